// Round 17
// baseline (229.843 us; speedup 1.0000x reference)
//
#include <hip/hip_runtime.h>

#define NN   65536
#define NE   1048576
#define CAP  48        // per-node edge capacity (Poisson(16): P(deg>=48)~5e-6)
#define NP   512       // partitions (128 nodes each), bin = dst >> 7
#define NODP 128       // nodes per partition
#define PCAP 2560      // partition capacity: mean 2048 + ~11 sd
#define FIN  128
#define HD   64
#define NOUT 32
#define EPSV 1e-5f

typedef unsigned short u16;
typedef unsigned int u32;

__device__ __forceinline__ float wsum(float v) {
#pragma unroll
  for (int o = 32; o > 0; o >>= 1) v += __shfl_xor(v, o, 64);
  return v;
}

__device__ __forceinline__ u16 f2bf(float f) {
  u32 x = __float_as_uint(f);
  u32 r = x + 0x7FFFu + ((x >> 16) & 1u);   // round-to-nearest-even
  return (u16)(r >> 16);
}
__device__ __forceinline__ float bf2f(u16 u) {
  return __uint_as_float((u32)u << 16);
}

__device__ __forceinline__ void fma4bf(float4& acc, uint2 g, float w) {
  acc.x += __uint_as_float(g.x << 16) * w;
  acc.y += __uint_as_float(g.x & 0xFFFF0000u) * w;
  acc.z += __uint_as_float(g.y << 16) * w;
  acc.w += __uint_as_float(g.y & 0xFFFF0000u) * w;
}

// ---------------- pass A: partition edges into 512 coarse bins (coalesced runs) --------
__global__ __launch_bounds__(1024) void passA_k(
    const int* __restrict__ src, const int* __restrict__ dst,
    const float* __restrict__ ew, int* __restrict__ pcnt,
    uint2* __restrict__ tmp) {
  __shared__ int hist[NP];
  __shared__ int base[NP];
  int t = threadIdx.x;
  if (t < NP) hist[t] = 0;
  __syncthreads();

  int d[4], s[4];
  float w[4];
  size_t e0 = (size_t)blockIdx.x * 4096;
#pragma unroll
  for (int r = 0; r < 4; ++r) {
    int i = e0 + r * 1024 + t;
    d[r] = dst[i]; s[r] = src[i]; w[r] = ew[i];
    atomicAdd(&hist[d[r] >> 7], 1);
  }
  __syncthreads();
  if (t < NP) {
    int c = hist[t];
    base[t] = c ? atomicAdd(&pcnt[t], c) : 0;
    hist[t] = 0;                 // reuse as cursor
  }
  __syncthreads();
#pragma unroll
  for (int r = 0; r < 4; ++r) {
    int bin = d[r] >> 7;
    int pos = base[bin] + atomicAdd(&hist[bin], 1);
    if (pos < PCAP)
      tmp[(size_t)bin * PCAP + pos] =
          make_uint2(((u32)d[r] << 16) | (u32)s[r], __float_as_uint(w[r]));
  }
}

// ---------------- pass B: per-partition CSR build + pad-to-4 zero-weight slots --------
__global__ __launch_bounds__(256) void passB_k(
    const uint2* __restrict__ tmp, const int* __restrict__ pcnt,
    u32* __restrict__ edgep, int* __restrict__ ecnt) {
  __shared__ int cur[NODP];
  int p = blockIdx.x, t = threadIdx.x;
  if (t < NODP) cur[t] = 0;
  __syncthreads();
  int cntp = min(pcnt[p], PCAP);
  const uint2* tp = tmp + (size_t)p * PCAP;
  for (int i = t; i < cntp; i += 256) {
    uint2 e = tp[i];
    int dd = e.x >> 16;
    int pos = atomicAdd(&cur[dd & (NODP - 1)], 1);
    if (pos < CAP)
      edgep[(size_t)dd * CAP + pos] =
          (e.x & 0xFFFFu) | ((u32)f2bf(__uint_as_float(e.y)) << 16);
  }
  __syncthreads();
  if (t < NODP) {
    int node = p * NODP + t;
    int c = min(cur[t], CAP);
    int padded = min((c + 3) & ~3, CAP);
    for (int s = c; s < padded; ++s)
      edgep[(size_t)node * CAP + s] = 0u;   // src 0, bf16 weight 0
    ecnt[node] = padded;
  }
}

// ---------------- fc_first: LN(128) -> [128x64] -> ELU -> LN(64), 4 lanes/node -------
__global__ __launch_bounds__(256, 4) void fc_first_k(
    const float* __restrict__ x, const float* __restrict__ ln1_g,
    const float* __restrict__ ln1_b, const float* __restrict__ w1,
    const float* __restrict__ b1, const float* __restrict__ ln_g,
    const float* __restrict__ ln_b, float* __restrict__ hA,
    u16* __restrict__ hAbf) {
  __shared__ __align__(16) float sW[FIN * HD];   // [k][j]
  __shared__ __align__(16) float sG[FIN], sB[FIN];
  __shared__ __align__(16) float sB1[HD], sLG[HD], sLB[HD];
  int tid = threadIdx.x;
  {
    const float4* w4 = (const float4*)w1;
    float4* s4 = (float4*)sW;
    for (int i = tid; i < FIN * HD / 4; i += 256) s4[i] = w4[i];
    if (tid < FIN) { sG[tid] = ln1_g[tid]; sB[tid] = ln1_b[tid]; }
    if (tid < HD) { sB1[tid] = b1[tid]; sLG[tid] = ln_g[tid]; sLB[tid] = ln_b[tid]; }
  }
  __syncthreads();

  int jq = tid & 3;                      // owns output features jq*16 .. jq*16+15
  int node = blockIdx.x * 64 + (tid >> 2);
  const float4* xp = (const float4*)(x + (size_t)node * FIN);

  float s = 0.f, s2 = 0.f;
  for (int i = 0; i < FIN / 4; ++i) {
    float4 v = xp[i];
    s += v.x + v.y + v.z + v.w;
    s2 += v.x * v.x + v.y * v.y + v.z * v.z + v.w * v.w;
  }
  float mean = s * (1.f / FIN);
  float var = s2 * (1.f / FIN) - mean * mean;
  float r = rsqrtf(var + EPSV);

  float acc[16];
#pragma unroll
  for (int jb = 0; jb < 4; ++jb) {
    float4 b = ((const float4*)sB1)[jq * 4 + jb];
    acc[jb * 4 + 0] = b.x; acc[jb * 4 + 1] = b.y;
    acc[jb * 4 + 2] = b.z; acc[jb * 4 + 3] = b.w;
  }
  const float4* sW4 = (const float4*)sW;   // 16 float4 per k-row
  for (int k4 = 0; k4 < FIN / 4; ++k4) {
    float4 xk = xp[k4];
    float4 g4 = ((const float4*)sG)[k4];
    float4 bb4 = ((const float4*)sB)[k4];
    float xn0 = (xk.x - mean) * r * g4.x + bb4.x;
    float xn1 = (xk.y - mean) * r * g4.y + bb4.y;
    float xn2 = (xk.z - mean) * r * g4.z + bb4.z;
    float xn3 = (xk.w - mean) * r * g4.w + bb4.w;
#pragma unroll
    for (int jb = 0; jb < 4; ++jb) {
      float4 w0 = sW4[(k4 * 4 + 0) * 16 + jq * 4 + jb];
      float4 w1v = sW4[(k4 * 4 + 1) * 16 + jq * 4 + jb];
      float4 w2 = sW4[(k4 * 4 + 2) * 16 + jq * 4 + jb];
      float4 w3v = sW4[(k4 * 4 + 3) * 16 + jq * 4 + jb];
      acc[jb * 4 + 0] += xn0 * w0.x + xn1 * w1v.x + xn2 * w2.x + xn3 * w3v.x;
      acc[jb * 4 + 1] += xn0 * w0.y + xn1 * w1v.y + xn2 * w2.y + xn3 * w3v.y;
      acc[jb * 4 + 2] += xn0 * w0.z + xn1 * w1v.z + xn2 * w2.z + xn3 * w3v.z;
      acc[jb * 4 + 3] += xn0 * w0.w + xn1 * w1v.w + xn2 * w2.w + xn3 * w3v.w;
    }
  }

  float s3 = 0.f;
#pragma unroll
  for (int j = 0; j < 16; ++j) {
    float y = acc[j];
    y = (y > 0.f) ? y : expm1f(y);
    acc[j] = y;
    s3 += y;
  }
  s3 += __shfl_xor(s3, 1, 64);
  s3 += __shfl_xor(s3, 2, 64);
  float m2 = s3 * (1.f / HD);
  float v2 = 0.f;
#pragma unroll
  for (int j = 0; j < 16; ++j) { float d = acc[j] - m2; v2 += d * d; }
  v2 += __shfl_xor(v2, 1, 64);
  v2 += __shfl_xor(v2, 2, 64);
  float r2 = rsqrtf(v2 * (1.f / HD) + EPSV);

  float4* hp = (float4*)(hA + (size_t)node * HD + jq * 16);
  short4* mp = (short4*)(hAbf + (size_t)node * HD + jq * 16);
#pragma unroll
  for (int jb = 0; jb < 4; ++jb) {
    float4 g4 = ((const float4*)sLG)[jq * 4 + jb];
    float4 b4 = ((const float4*)sLB)[jq * 4 + jb];
    float4 o;
    o.x = (acc[jb * 4 + 0] - m2) * r2 * g4.x + b4.x;
    o.y = (acc[jb * 4 + 1] - m2) * r2 * g4.y + b4.y;
    o.z = (acc[jb * 4 + 2] - m2) * r2 * g4.z + b4.z;
    o.w = (acc[jb * 4 + 3] - m2) * r2 * g4.w + b4.w;
    hp[jb] = o;
    short4 m4;
    m4.x = (short)f2bf(o.x); m4.y = (short)f2bf(o.y);
    m4.z = (short)f2bf(o.z); m4.w = (short)f2bf(o.w);
    mp[jb] = m4;
  }
}

// ---------------- conv: unpredicated gather -> LDS-W GEMM -> LN -> h += --------------
__global__ __launch_bounds__(512, 8) void conv_k(
    const float* __restrict__ h_in, const u16* __restrict__ hbf_in,
    float* __restrict__ h_out, u16* __restrict__ hbf_out,
    const int* __restrict__ ecnt, const u32* __restrict__ edgep,
    const float* __restrict__ W, const float* __restrict__ B,
    const float* __restrict__ ln_g, const float* __restrict__ ln_b) {
  __shared__ __align__(16) float sWt[HD * 68];   // [j][k], pad 68
  __shared__ __align__(16) float sagg[8][HD];    // per-wave
  int tid = threadIdx.x;
  for (int i = tid; i < HD * HD; i += 512) {
    int k = i >> 6, j = i & 63;
    sWt[j * 68 + k] = W[i];
  }
  __syncthreads();   // only barrier: W staging

  int wl = tid >> 6, lane = tid & 63;
  float bias = B[lane], lg = ln_g[lane], lb = ln_b[lane];
  int gw = blockIdx.x * 8 + wl;        // 32768 waves
  int q = lane >> 4;                   // quarter: edge within group of 4
  int fq = lane & 15;                  // feature-quad

  for (int rep = 0; rep < NN / 32768; ++rep) {
    int n = gw + rep * 32768;
    int cnt = ecnt[n];                 // padded to multiple of 4, all slots valid
    int beg = n * CAP;

    float4 acc = make_float4(0.f, 0.f, 0.f, 0.f);
    if (cnt > 0) {
      u32 H = edgep[beg + min(lane, CAP - 1)];
      int ng = cnt >> 2;               // groups of 4 edges, <= 12
      int g = 0;
      for (; g + 4 <= ng; g += 4) {    // 16 edges, 4 gathers in flight
        u32 h0 = __shfl(H, (g + 0) * 4 + q, 64);
        u32 h1 = __shfl(H, (g + 1) * 4 + q, 64);
        u32 h2 = __shfl(H, (g + 2) * 4 + q, 64);
        u32 h3 = __shfl(H, (g + 3) * 4 + q, 64);
        uint2 g0 = ((const uint2*)(hbf_in + ((size_t)(h0 & 0xFFFFu) << 6)))[fq];
        uint2 g1 = ((const uint2*)(hbf_in + ((size_t)(h1 & 0xFFFFu) << 6)))[fq];
        uint2 g2 = ((const uint2*)(hbf_in + ((size_t)(h2 & 0xFFFFu) << 6)))[fq];
        uint2 g3 = ((const uint2*)(hbf_in + ((size_t)(h3 & 0xFFFFu) << 6)))[fq];
        fma4bf(acc, g0, __uint_as_float(h0 & 0xFFFF0000u));
        fma4bf(acc, g1, __uint_as_float(h1 & 0xFFFF0000u));
        fma4bf(acc, g2, __uint_as_float(h2 & 0xFFFF0000u));
        fma4bf(acc, g3, __uint_as_float(h3 & 0xFFFF0000u));
      }
      for (; g < ng; ++g) {            // remaining groups (no predication)
        u32 hj = __shfl(H, g * 4 + q, 64);
        uint2 gg = ((const uint2*)(hbf_in + ((size_t)(hj & 0xFFFFu) << 6)))[fq];
        fma4bf(acc, gg, __uint_as_float(hj & 0xFFFF0000u));
      }
    }
#pragma unroll
    for (int off = 16; off < 64; off <<= 1) {
      acc.x += __shfl_xor(acc.x, off, 64);
      acc.y += __shfl_xor(acc.y, off, 64);
      acc.z += __shfl_xor(acc.z, off, 64);
      acc.w += __shfl_xor(acc.w, off, 64);
    }
    // per-wave staging: same-wave RAW, no barrier needed
    if (lane < 16) ((float4*)sagg[wl])[lane] = acc;

    float y = bias;
    const float4* ar = (const float4*)sagg[wl];
    const float4* wr = (const float4*)&sWt[lane * 68];
#pragma unroll
    for (int k4 = 0; k4 < HD / 4; ++k4) {
      float4 a4 = ar[k4];              // uniform broadcast
      float4 w4v = wr[k4];
      y += a4.x * w4v.x + a4.y * w4v.y + a4.z * w4v.z + a4.w * w4v.w;
    }

    float m = wsum(y) * (1.f / HD);
    float d = y - m;
    float v = wsum(d * d) * (1.f / HD);
    float ln = d * rsqrtf(v + EPSV) * lg + lb;
    float hv = h_in[(size_t)n * HD + lane] + ln;
    h_out[(size_t)n * HD + lane] = hv;
    if (hbf_out) hbf_out[(size_t)n * HD + lane] = f2bf(hv);
  }
}

// ---------------- fc_final: LN(64) -> [64x64]+b3 -> ELU -> [64x32]+b4, 4 lanes/node --
__global__ __launch_bounds__(256, 4) void fc_final_k(
    const float* __restrict__ h, const float* __restrict__ ln2_g,
    const float* __restrict__ ln2_b, const float* __restrict__ w3,
    const float* __restrict__ b3, const float* __restrict__ w4,
    const float* __restrict__ b4, float* __restrict__ out) {
  __shared__ __align__(16) float sW3[HD * HD];     // [k][j]
  __shared__ __align__(16) float sW4[HD * NOUT];   // [k][j]
  __shared__ __align__(16) float sG[HD], sB[HD], sB3[HD], sB4[NOUT];
  int tid = threadIdx.x;
  {
    const float4* a = (const float4*)w3;
    float4* d4 = (float4*)sW3;
    for (int i = tid; i < HD * HD / 4; i += 256) d4[i] = a[i];
    const float4* c = (const float4*)w4;
    float4* e4 = (float4*)sW4;
    for (int i = tid; i < HD * NOUT / 4; i += 256) e4[i] = c[i];
    if (tid < HD) { sG[tid] = ln2_g[tid]; sB[tid] = ln2_b[tid]; sB3[tid] = b3[tid]; }
    if (tid < NOUT) sB4[tid] = b4[tid];
  }
  __syncthreads();

  int jq = tid & 3;
  int node = blockIdx.x * 64 + (tid >> 2);
  const float4* hp = (const float4*)(h + (size_t)node * HD);

  float s = 0.f, s2 = 0.f;
  for (int i = 0; i < HD / 4; ++i) {
    float4 v = hp[i];
    s += v.x + v.y + v.z + v.w;
    s2 += v.x * v.x + v.y * v.y + v.z * v.z + v.w * v.w;
  }
  float mean = s * (1.f / HD);
  float var = s2 * (1.f / HD) - mean * mean;
  float r = rsqrtf(var + EPSV);

  float acc[16];                       // z features jq*16 .. jq*16+15
#pragma unroll
  for (int jb = 0; jb < 4; ++jb) {
    float4 b = ((const float4*)sB3)[jq * 4 + jb];
    acc[jb * 4 + 0] = b.x; acc[jb * 4 + 1] = b.y;
    acc[jb * 4 + 2] = b.z; acc[jb * 4 + 3] = b.w;
  }
  const float4* sW34 = (const float4*)sW3;
  for (int k4 = 0; k4 < HD / 4; ++k4) {
    float4 xk = hp[k4];
    float4 g4 = ((const float4*)sG)[k4];
    float4 bb4 = ((const float4*)sB)[k4];
    float xn0 = (xk.x - mean) * r * g4.x + bb4.x;
    float xn1 = (xk.y - mean) * r * g4.y + bb4.y;
    float xn2 = (xk.z - mean) * r * g4.z + bb4.z;
    float xn3 = (xk.w - mean) * r * g4.w + bb4.w;
#pragma unroll
    for (int jb = 0; jb < 4; ++jb) {
      float4 w0 = sW34[(k4 * 4 + 0) * 16 + jq * 4 + jb];
      float4 w1v = sW34[(k4 * 4 + 1) * 16 + jq * 4 + jb];
      float4 w2 = sW34[(k4 * 4 + 2) * 16 + jq * 4 + jb];
      float4 w3v = sW34[(k4 * 4 + 3) * 16 + jq * 4 + jb];
      acc[jb * 4 + 0] += xn0 * w0.x + xn1 * w1v.x + xn2 * w2.x + xn3 * w3v.x;
      acc[jb * 4 + 1] += xn0 * w0.y + xn1 * w1v.y + xn2 * w2.y + xn3 * w3v.y;
      acc[jb * 4 + 2] += xn0 * w0.z + xn1 * w1v.z + xn2 * w2.z + xn3 * w3v.z;
      acc[jb * 4 + 3] += xn0 * w0.w + xn1 * w1v.w + xn2 * w2.w + xn3 * w3v.w;
    }
  }

#pragma unroll
  for (int j = 0; j < 16; ++j) {
    float y = acc[j];
    acc[j] = (y > 0.f) ? y : expm1f(y);
  }

  // GEMM2: partial over this lane's 16 k, 2 output chunks of 16; 4-lane xor-reduce
  const float4* sW44 = (const float4*)sW4;   // 8 float4 per k-row
#pragma unroll
  for (int c = 0; c < 2; ++c) {
    float p[16];
#pragma unroll
    for (int i = 0; i < 16; ++i) p[i] = 0.f;
#pragma unroll
    for (int kk = 0; kk < 16; ++kk) {
      float zk = acc[kk];
      int krow = jq * 16 + kk;
#pragma unroll
      for (int qd = 0; qd < 4; ++qd) {
        float4 w = sW44[krow * 8 + c * 4 + qd];
        p[qd * 4 + 0] += zk * w.x;
        p[qd * 4 + 1] += zk * w.y;
        p[qd * 4 + 2] += zk * w.z;
        p[qd * 4 + 3] += zk * w.w;
      }
    }
#pragma unroll
    for (int i = 0; i < 16; ++i) {
      p[i] += __shfl_xor(p[i], 1, 64);
      p[i] += __shfl_xor(p[i], 2, 64);
    }
    if (jq == c) {
      float4* op = (float4*)(out + (size_t)node * NOUT + c * 16);
#pragma unroll
      for (int qd = 0; qd < 4; ++qd) {
        float4 b = ((const float4*)sB4)[c * 4 + qd];
        float4 o;
        o.x = p[qd * 4 + 0] + b.x; o.y = p[qd * 4 + 1] + b.y;
        o.z = p[qd * 4 + 2] + b.z; o.w = p[qd * 4 + 3] + b.w;
        op[qd] = o;
      }
    }
  }
}

extern "C" void kernel_launch(void* const* d_in, const int* in_sizes, int n_in,
                              void* d_out, int out_size, void* d_ws, size_t ws_size,
                              hipStream_t stream) {
  const float* x      = (const float*)d_in[0];
  const float* ew     = (const float*)d_in[1];
  const int*   src    = (const int*)d_in[2];
  const int*   dst    = (const int*)d_in[3];
  const float* ln1_g  = (const float*)d_in[4];
  const float* ln1_b  = (const float*)d_in[5];
  const float* w1     = (const float*)d_in[6];
  const float* b1     = (const float*)d_in[7];
  const float* ln_g   = (const float*)d_in[8];
  const float* ln_b   = (const float*)d_in[9];
  const float* conv_w = (const float*)d_in[10];
  const float* conv_b = (const float*)d_in[11];
  const float* ln2_g  = (const float*)d_in[12];
  const float* ln2_b  = (const float*)d_in[13];
  const float* w3     = (const float*)d_in[14];
  const float* b3     = (const float*)d_in[15];
  const float* w4     = (const float*)d_in[16];
  const float* b4     = (const float*)d_in[17];
  float* out = (float*)d_out;

  char* ws = (char*)d_ws;
  float* hA    = (float*)ws;                         // 16 MB (tmp aliases, pre-fc)
  float* hB    = hA + (size_t)NN * HD;               // 16 MB
  u16*   hAbf  = (u16*)(hB + (size_t)NN * HD);       // 8 MB
  u16*   hBbf  = hAbf + (size_t)NN * HD;             // 8 MB
  int*   ecnt  = (int*)(hBbf + (size_t)NN * HD);     // 256 KB (+pad)
  u32*   edgep = (u32*)(ecnt + NN + 64);             // NN*CAP*4B = 12.6 MB
  int*   pcnt  = (int*)(edgep + (size_t)NN * CAP);   // NP ints (+pad)
  uint2* tmp   = (uint2*)hA;                         // NP*PCAP*8B = 10.5 MB, CSR build only

  hipMemsetAsync(pcnt, 0, NP * sizeof(int), stream);
  passA_k<<<NE / 4096, 1024, 0, stream>>>(src, dst, ew, pcnt, tmp);
  passB_k<<<NP, 256, 0, stream>>>(tmp, pcnt, edgep, ecnt);

  fc_first_k<<<NN / 64, 256, 0, stream>>>(x, ln1_g, ln1_b, w1, b1, ln_g, ln_b,
                                          hA, hAbf);
  conv_k<<<4096, 512, 0, stream>>>(hA, hAbf, hB, hBbf, ecnt, edgep,
                                   conv_w,        conv_b,       ln_g, ln_b);
  conv_k<<<4096, 512, 0, stream>>>(hB, hBbf, hA, hAbf, ecnt, edgep,
                                   conv_w + 4096, conv_b + 64,  ln_g, ln_b);
  conv_k<<<4096, 512, 0, stream>>>(hA, hAbf, hB, (u16*)nullptr, ecnt, edgep,
                                   conv_w + 8192, conv_b + 128, ln_g, ln_b);
  fc_final_k<<<NN / 64, 256, 0, stream>>>(hB, ln2_g, ln2_b, w3, b3, w4, b4, out);
}

// Round 18
// 220.558 us; speedup vs baseline: 1.0421x; 1.0421x over previous
//
#include <hip/hip_runtime.h>

#define NN   65536
#define NE   1048576
#define CAP  48        // per-node edge capacity (Poisson(16): P(deg>=48)~5e-6)
#define NP   512       // partitions (128 nodes each), bin = dst >> 7
#define NODP 128       // nodes per partition
#define PCAP 2560      // partition capacity: mean 2048 + ~11 sd
#define FIN  128
#define HD   64
#define NOUT 32
#define EPSV 1e-5f
#define REPS 4         // nodes per wave (front-end pipelined)

typedef unsigned short u16;
typedef unsigned int u32;

__device__ __forceinline__ float wsum(float v) {
#pragma unroll
  for (int o = 32; o > 0; o >>= 1) v += __shfl_xor(v, o, 64);
  return v;
}

__device__ __forceinline__ u16 f2bf(float f) {
  u32 x = __float_as_uint(f);
  u32 r = x + 0x7FFFu + ((x >> 16) & 1u);   // round-to-nearest-even
  return (u16)(r >> 16);
}
__device__ __forceinline__ float bf2f(u16 u) {
  return __uint_as_float((u32)u << 16);
}

__device__ __forceinline__ void fma4bf(float4& acc, uint2 g, float w) {
  acc.x += __uint_as_float(g.x << 16) * w;
  acc.y += __uint_as_float(g.x & 0xFFFF0000u) * w;
  acc.z += __uint_as_float(g.y << 16) * w;
  acc.w += __uint_as_float(g.y & 0xFFFF0000u) * w;
}

// ---------------- pass A: partition edges into 512 coarse bins (coalesced runs) --------
__global__ __launch_bounds__(1024) void passA_k(
    const int* __restrict__ src, const int* __restrict__ dst,
    const float* __restrict__ ew, int* __restrict__ pcnt,
    uint2* __restrict__ tmp) {
  __shared__ int hist[NP];
  __shared__ int base[NP];
  int t = threadIdx.x;
  if (t < NP) hist[t] = 0;
  __syncthreads();

  int d[4], s[4];
  float w[4];
  size_t e0 = (size_t)blockIdx.x * 4096;
#pragma unroll
  for (int r = 0; r < 4; ++r) {
    int i = e0 + r * 1024 + t;
    d[r] = dst[i]; s[r] = src[i]; w[r] = ew[i];
    atomicAdd(&hist[d[r] >> 7], 1);
  }
  __syncthreads();
  if (t < NP) {
    int c = hist[t];
    base[t] = c ? atomicAdd(&pcnt[t], c) : 0;
    hist[t] = 0;                 // reuse as cursor
  }
  __syncthreads();
#pragma unroll
  for (int r = 0; r < 4; ++r) {
    int bin = d[r] >> 7;
    int pos = base[bin] + atomicAdd(&hist[bin], 1);
    if (pos < PCAP)
      tmp[(size_t)bin * PCAP + pos] =
          make_uint2(((u32)d[r] << 16) | (u32)s[r], __float_as_uint(w[r]));
  }
}

// ---------------- pass B: per-partition CSR build + pad-to-4 zero-weight slots --------
__global__ __launch_bounds__(256) void passB_k(
    const uint2* __restrict__ tmp, const int* __restrict__ pcnt,
    u32* __restrict__ edgep, int* __restrict__ ecnt) {
  __shared__ int cur[NODP];
  int p = blockIdx.x, t = threadIdx.x;
  if (t < NODP) cur[t] = 0;
  __syncthreads();
  int cntp = min(pcnt[p], PCAP);
  const uint2* tp = tmp + (size_t)p * PCAP;
  for (int i = t; i < cntp; i += 256) {
    uint2 e = tp[i];
    int dd = e.x >> 16;
    int pos = atomicAdd(&cur[dd & (NODP - 1)], 1);
    if (pos < CAP)
      edgep[(size_t)dd * CAP + pos] =
          (e.x & 0xFFFFu) | ((u32)f2bf(__uint_as_float(e.y)) << 16);
  }
  __syncthreads();
  if (t < NODP) {
    int node = p * NODP + t;
    int c = min(cur[t], CAP);
    int padded = min((c + 3) & ~3, CAP);
    for (int s = c; s < padded; ++s)
      edgep[(size_t)node * CAP + s] = 0u;   // src 0, bf16 weight 0
    ecnt[node] = padded;
  }
}

// ---------------- fc_first: LN(128) -> [128x64] -> ELU -> LN(64), 4 lanes/node -------
__global__ __launch_bounds__(256, 4) void fc_first_k(
    const float* __restrict__ x, const float* __restrict__ ln1_g,
    const float* __restrict__ ln1_b, const float* __restrict__ w1,
    const float* __restrict__ b1, const float* __restrict__ ln_g,
    const float* __restrict__ ln_b, float* __restrict__ hA,
    u16* __restrict__ hAbf) {
  __shared__ __align__(16) float sW[FIN * HD];   // [k][j]
  __shared__ __align__(16) float sG[FIN], sB[FIN];
  __shared__ __align__(16) float sB1[HD], sLG[HD], sLB[HD];
  int tid = threadIdx.x;
  {
    const float4* w4 = (const float4*)w1;
    float4* s4 = (float4*)sW;
    for (int i = tid; i < FIN * HD / 4; i += 256) s4[i] = w4[i];
    if (tid < FIN) { sG[tid] = ln1_g[tid]; sB[tid] = ln1_b[tid]; }
    if (tid < HD) { sB1[tid] = b1[tid]; sLG[tid] = ln_g[tid]; sLB[tid] = ln_b[tid]; }
  }
  __syncthreads();

  int jq = tid & 3;                      // owns output features jq*16 .. jq*16+15
  int node = blockIdx.x * 64 + (tid >> 2);
  const float4* xp = (const float4*)(x + (size_t)node * FIN);

  float s = 0.f, s2 = 0.f;
  for (int i = 0; i < FIN / 4; ++i) {
    float4 v = xp[i];
    s += v.x + v.y + v.z + v.w;
    s2 += v.x * v.x + v.y * v.y + v.z * v.z + v.w * v.w;
  }
  float mean = s * (1.f / FIN);
  float var = s2 * (1.f / FIN) - mean * mean;
  float r = rsqrtf(var + EPSV);

  float acc[16];
#pragma unroll
  for (int jb = 0; jb < 4; ++jb) {
    float4 b = ((const float4*)sB1)[jq * 4 + jb];
    acc[jb * 4 + 0] = b.x; acc[jb * 4 + 1] = b.y;
    acc[jb * 4 + 2] = b.z; acc[jb * 4 + 3] = b.w;
  }
  const float4* sW4 = (const float4*)sW;   // 16 float4 per k-row
  for (int k4 = 0; k4 < FIN / 4; ++k4) {
    float4 xk = xp[k4];
    float4 g4 = ((const float4*)sG)[k4];
    float4 bb4 = ((const float4*)sB)[k4];
    float xn0 = (xk.x - mean) * r * g4.x + bb4.x;
    float xn1 = (xk.y - mean) * r * g4.y + bb4.y;
    float xn2 = (xk.z - mean) * r * g4.z + bb4.z;
    float xn3 = (xk.w - mean) * r * g4.w + bb4.w;
#pragma unroll
    for (int jb = 0; jb < 4; ++jb) {
      float4 w0 = sW4[(k4 * 4 + 0) * 16 + jq * 4 + jb];
      float4 w1v = sW4[(k4 * 4 + 1) * 16 + jq * 4 + jb];
      float4 w2 = sW4[(k4 * 4 + 2) * 16 + jq * 4 + jb];
      float4 w3v = sW4[(k4 * 4 + 3) * 16 + jq * 4 + jb];
      acc[jb * 4 + 0] += xn0 * w0.x + xn1 * w1v.x + xn2 * w2.x + xn3 * w3v.x;
      acc[jb * 4 + 1] += xn0 * w0.y + xn1 * w1v.y + xn2 * w2.y + xn3 * w3v.y;
      acc[jb * 4 + 2] += xn0 * w0.z + xn1 * w1v.z + xn2 * w2.z + xn3 * w3v.z;
      acc[jb * 4 + 3] += xn0 * w0.w + xn1 * w1v.w + xn2 * w2.w + xn3 * w3v.w;
    }
  }

  float s3 = 0.f;
#pragma unroll
  for (int j = 0; j < 16; ++j) {
    float y = acc[j];
    y = (y > 0.f) ? y : expm1f(y);
    acc[j] = y;
    s3 += y;
  }
  s3 += __shfl_xor(s3, 1, 64);
  s3 += __shfl_xor(s3, 2, 64);
  float m2 = s3 * (1.f / HD);
  float v2 = 0.f;
#pragma unroll
  for (int j = 0; j < 16; ++j) { float d = acc[j] - m2; v2 += d * d; }
  v2 += __shfl_xor(v2, 1, 64);
  v2 += __shfl_xor(v2, 2, 64);
  float r2 = rsqrtf(v2 * (1.f / HD) + EPSV);

  float4* hp = (float4*)(hA + (size_t)node * HD + jq * 16);
  short4* mp = (short4*)(hAbf + (size_t)node * HD + jq * 16);
#pragma unroll
  for (int jb = 0; jb < 4; ++jb) {
    float4 g4 = ((const float4*)sLG)[jq * 4 + jb];
    float4 b4 = ((const float4*)sLB)[jq * 4 + jb];
    float4 o;
    o.x = (acc[jb * 4 + 0] - m2) * r2 * g4.x + b4.x;
    o.y = (acc[jb * 4 + 1] - m2) * r2 * g4.y + b4.y;
    o.z = (acc[jb * 4 + 2] - m2) * r2 * g4.z + b4.z;
    o.w = (acc[jb * 4 + 3] - m2) * r2 * g4.w + b4.w;
    hp[jb] = o;
    short4 m4;
    m4.x = (short)f2bf(o.x); m4.y = (short)f2bf(o.y);
    m4.z = (short)f2bf(o.z); m4.w = (short)f2bf(o.w);
    mp[jb] = m4;
  }
}

// ---------------- conv: 4-node front-end pipeline -> LDS-W GEMM -> LN -> h += --------
__global__ __launch_bounds__(512, 8) void conv_k(
    const float* __restrict__ h_in, const u16* __restrict__ hbf_in,
    float* __restrict__ h_out, u16* __restrict__ hbf_out,
    const int* __restrict__ ecnt, const u32* __restrict__ edgep,
    const float* __restrict__ W, const float* __restrict__ B,
    const float* __restrict__ ln_g, const float* __restrict__ ln_b) {
  __shared__ __align__(16) float sWt[HD * 68];   // [j][k], pad 68
  __shared__ __align__(16) float sagg[8][HD];    // per-wave
  int tid = threadIdx.x;
  for (int i = tid; i < HD * HD; i += 512) {
    int k = i >> 6, j = i & 63;
    sWt[j * 68 + k] = W[i];
  }
  __syncthreads();   // only barrier: W staging

  int wl = tid >> 6, lane = tid & 63;
  float bias = B[lane], lg = ln_g[lane], lb = ln_b[lane];
  int gw = blockIdx.x * 8 + wl;        // 16384 waves, REPS nodes each
  int q = lane >> 4;                   // quarter: edge within group of 4
  int fq = lane & 15;                  // feature-quad

  // ---- front-end preload: all REPS (cnt, header) pairs in flight together ----
  int cntR[REPS];
  u32 HR[REPS];
#pragma unroll
  for (int rp = 0; rp < REPS; ++rp) {
    int n = gw + rp * 16384;
    cntR[rp] = ecnt[n];
    HR[rp] = edgep[(size_t)n * CAP + min(lane, CAP - 1)];
  }

#pragma unroll
  for (int rp = 0; rp < REPS; ++rp) {
    int n = gw + rp * 16384;
    int cnt = cntR[rp];
    u32 H = HR[rp];

    float4 acc = make_float4(0.f, 0.f, 0.f, 0.f);
    if (cnt > 0) {
      int ng = cnt >> 2;               // groups of 4 edges, <= 12
      int g = 0;
      for (; g + 4 <= ng; g += 4) {    // 16 edges, 4 gathers in flight
        u32 h0 = __shfl(H, (g + 0) * 4 + q, 64);
        u32 h1 = __shfl(H, (g + 1) * 4 + q, 64);
        u32 h2 = __shfl(H, (g + 2) * 4 + q, 64);
        u32 h3 = __shfl(H, (g + 3) * 4 + q, 64);
        uint2 g0 = ((const uint2*)(hbf_in + ((size_t)(h0 & 0xFFFFu) << 6)))[fq];
        uint2 g1 = ((const uint2*)(hbf_in + ((size_t)(h1 & 0xFFFFu) << 6)))[fq];
        uint2 g2 = ((const uint2*)(hbf_in + ((size_t)(h2 & 0xFFFFu) << 6)))[fq];
        uint2 g3 = ((const uint2*)(hbf_in + ((size_t)(h3 & 0xFFFFu) << 6)))[fq];
        fma4bf(acc, g0, __uint_as_float(h0 & 0xFFFF0000u));
        fma4bf(acc, g1, __uint_as_float(h1 & 0xFFFF0000u));
        fma4bf(acc, g2, __uint_as_float(h2 & 0xFFFF0000u));
        fma4bf(acc, g3, __uint_as_float(h3 & 0xFFFF0000u));
      }
      for (; g < ng; ++g) {            // remaining groups (no predication)
        u32 hj = __shfl(H, g * 4 + q, 64);
        uint2 gg = ((const uint2*)(hbf_in + ((size_t)(hj & 0xFFFFu) << 6)))[fq];
        fma4bf(acc, gg, __uint_as_float(hj & 0xFFFF0000u));
      }
    }
#pragma unroll
    for (int off = 16; off < 64; off <<= 1) {
      acc.x += __shfl_xor(acc.x, off, 64);
      acc.y += __shfl_xor(acc.y, off, 64);
      acc.z += __shfl_xor(acc.z, off, 64);
      acc.w += __shfl_xor(acc.w, off, 64);
    }
    // per-wave staging: same-wave RAW, no barrier needed
    if (lane < 16) ((float4*)sagg[wl])[lane] = acc;

    float y = bias;
    const float4* ar = (const float4*)sagg[wl];
    const float4* wr = (const float4*)&sWt[lane * 68];
#pragma unroll
    for (int k4 = 0; k4 < HD / 4; ++k4) {
      float4 a4 = ar[k4];              // uniform broadcast
      float4 w4v = wr[k4];
      y += a4.x * w4v.x + a4.y * w4v.y + a4.z * w4v.z + a4.w * w4v.w;
    }

    float m = wsum(y) * (1.f / HD);
    float d = y - m;
    float v = wsum(d * d) * (1.f / HD);
    float ln = d * rsqrtf(v + EPSV) * lg + lb;
    float hv = h_in[(size_t)n * HD + lane] + ln;
    h_out[(size_t)n * HD + lane] = hv;
    if (hbf_out) hbf_out[(size_t)n * HD + lane] = f2bf(hv);
  }
}

// ---------------- fc_final: LN(64) -> [64x64]+b3 -> ELU -> [64x32]+b4, 4 lanes/node --
__global__ __launch_bounds__(256, 4) void fc_final_k(
    const float* __restrict__ h, const float* __restrict__ ln2_g,
    const float* __restrict__ ln2_b, const float* __restrict__ w3,
    const float* __restrict__ b3, const float* __restrict__ w4,
    const float* __restrict__ b4, float* __restrict__ out) {
  __shared__ __align__(16) float sW3[HD * HD];     // [k][j]
  __shared__ __align__(16) float sW4[HD * NOUT];   // [k][j]
  __shared__ __align__(16) float sG[HD], sB[HD], sB3[HD], sB4[NOUT];
  int tid = threadIdx.x;
  {
    const float4* a = (const float4*)w3;
    float4* d4 = (float4*)sW3;
    for (int i = tid; i < HD * HD / 4; i += 256) d4[i] = a[i];
    const float4* c = (const float4*)w4;
    float4* e4 = (float4*)sW4;
    for (int i = tid; i < HD * NOUT / 4; i += 256) e4[i] = c[i];
    if (tid < HD) { sG[tid] = ln2_g[tid]; sB[tid] = ln2_b[tid]; sB3[tid] = b3[tid]; }
    if (tid < NOUT) sB4[tid] = b4[tid];
  }
  __syncthreads();

  int jq = tid & 3;
  int node = blockIdx.x * 64 + (tid >> 2);
  const float4* hp = (const float4*)(h + (size_t)node * HD);

  float s = 0.f, s2 = 0.f;
  for (int i = 0; i < HD / 4; ++i) {
    float4 v = hp[i];
    s += v.x + v.y + v.z + v.w;
    s2 += v.x * v.x + v.y * v.y + v.z * v.z + v.w * v.w;
  }
  float mean = s * (1.f / HD);
  float var = s2 * (1.f / HD) - mean * mean;
  float r = rsqrtf(var + EPSV);

  float acc[16];                       // z features jq*16 .. jq*16+15
#pragma unroll
  for (int jb = 0; jb < 4; ++jb) {
    float4 b = ((const float4*)sB3)[jq * 4 + jb];
    acc[jb * 4 + 0] = b.x; acc[jb * 4 + 1] = b.y;
    acc[jb * 4 + 2] = b.z; acc[jb * 4 + 3] = b.w;
  }
  const float4* sW34 = (const float4*)sW3;
  for (int k4 = 0; k4 < HD / 4; ++k4) {
    float4 xk = hp[k4];
    float4 g4 = ((const float4*)sG)[k4];
    float4 bb4 = ((const float4*)sB)[k4];
    float xn0 = (xk.x - mean) * r * g4.x + bb4.x;
    float xn1 = (xk.y - mean) * r * g4.y + bb4.y;
    float xn2 = (xk.z - mean) * r * g4.z + bb4.z;
    float xn3 = (xk.w - mean) * r * g4.w + bb4.w;
#pragma unroll
    for (int jb = 0; jb < 4; ++jb) {
      float4 w0 = sW34[(k4 * 4 + 0) * 16 + jq * 4 + jb];
      float4 w1v = sW34[(k4 * 4 + 1) * 16 + jq * 4 + jb];
      float4 w2 = sW34[(k4 * 4 + 2) * 16 + jq * 4 + jb];
      float4 w3v = sW34[(k4 * 4 + 3) * 16 + jq * 4 + jb];
      acc[jb * 4 + 0] += xn0 * w0.x + xn1 * w1v.x + xn2 * w2.x + xn3 * w3v.x;
      acc[jb * 4 + 1] += xn0 * w0.y + xn1 * w1v.y + xn2 * w2.y + xn3 * w3v.y;
      acc[jb * 4 + 2] += xn0 * w0.z + xn1 * w1v.z + xn2 * w2.z + xn3 * w3v.z;
      acc[jb * 4 + 3] += xn0 * w0.w + xn1 * w1v.w + xn2 * w2.w + xn3 * w3v.w;
    }
  }

#pragma unroll
  for (int j = 0; j < 16; ++j) {
    float y = acc[j];
    acc[j] = (y > 0.f) ? y : expm1f(y);
  }

  // GEMM2: partial over this lane's 16 k, 2 output chunks of 16; 4-lane xor-reduce
  const float4* sW44 = (const float4*)sW4;   // 8 float4 per k-row
#pragma unroll
  for (int c = 0; c < 2; ++c) {
    float p[16];
#pragma unroll
    for (int i = 0; i < 16; ++i) p[i] = 0.f;
#pragma unroll
    for (int kk = 0; kk < 16; ++kk) {
      float zk = acc[kk];
      int krow = jq * 16 + kk;
#pragma unroll
      for (int qd = 0; qd < 4; ++qd) {
        float4 w = sW44[krow * 8 + c * 4 + qd];
        p[qd * 4 + 0] += zk * w.x;
        p[qd * 4 + 1] += zk * w.y;
        p[qd * 4 + 2] += zk * w.z;
        p[qd * 4 + 3] += zk * w.w;
      }
    }
#pragma unroll
    for (int i = 0; i < 16; ++i) {
      p[i] += __shfl_xor(p[i], 1, 64);
      p[i] += __shfl_xor(p[i], 2, 64);
    }
    if (jq == c) {
      float4* op = (float4*)(out + (size_t)node * NOUT + c * 16);
#pragma unroll
      for (int qd = 0; qd < 4; ++qd) {
        float4 b = ((const float4*)sB4)[c * 4 + qd];
        float4 o;
        o.x = p[qd * 4 + 0] + b.x; o.y = p[qd * 4 + 1] + b.y;
        o.z = p[qd * 4 + 2] + b.z; o.w = p[qd * 4 + 3] + b.w;
        op[qd] = o;
      }
    }
  }
}

extern "C" void kernel_launch(void* const* d_in, const int* in_sizes, int n_in,
                              void* d_out, int out_size, void* d_ws, size_t ws_size,
                              hipStream_t stream) {
  const float* x      = (const float*)d_in[0];
  const float* ew     = (const float*)d_in[1];
  const int*   src    = (const int*)d_in[2];
  const int*   dst    = (const int*)d_in[3];
  const float* ln1_g  = (const float*)d_in[4];
  const float* ln1_b  = (const float*)d_in[5];
  const float* w1     = (const float*)d_in[6];
  const float* b1     = (const float*)d_in[7];
  const float* ln_g   = (const float*)d_in[8];
  const float* ln_b   = (const float*)d_in[9];
  const float* conv_w = (const float*)d_in[10];
  const float* conv_b = (const float*)d_in[11];
  const float* ln2_g  = (const float*)d_in[12];
  const float* ln2_b  = (const float*)d_in[13];
  const float* w3     = (const float*)d_in[14];
  const float* b3     = (const float*)d_in[15];
  const float* w4     = (const float*)d_in[16];
  const float* b4     = (const float*)d_in[17];
  float* out = (float*)d_out;

  char* ws = (char*)d_ws;
  float* hA    = (float*)ws;                         // 16 MB (tmp aliases, pre-fc)
  float* hB    = hA + (size_t)NN * HD;               // 16 MB
  u16*   hAbf  = (u16*)(hB + (size_t)NN * HD);       // 8 MB
  u16*   hBbf  = hAbf + (size_t)NN * HD;             // 8 MB
  int*   ecnt  = (int*)(hBbf + (size_t)NN * HD);     // 256 KB (+pad)
  u32*   edgep = (u32*)(ecnt + NN + 64);             // NN*CAP*4B = 12.6 MB
  int*   pcnt  = (int*)(edgep + (size_t)NN * CAP);   // NP ints (+pad)
  uint2* tmp   = (uint2*)hA;                         // NP*PCAP*8B = 10.5 MB, CSR build only

  hipMemsetAsync(pcnt, 0, NP * sizeof(int), stream);
  passA_k<<<NE / 4096, 1024, 0, stream>>>(src, dst, ew, pcnt, tmp);
  passB_k<<<NP, 256, 0, stream>>>(tmp, pcnt, edgep, ecnt);

  fc_first_k<<<NN / 64, 256, 0, stream>>>(x, ln1_g, ln1_b, w1, b1, ln_g, ln_b,
                                          hA, hAbf);
  conv_k<<<2048, 512, 0, stream>>>(hA, hAbf, hB, hBbf, ecnt, edgep,
                                   conv_w,        conv_b,       ln_g, ln_b);
  conv_k<<<2048, 512, 0, stream>>>(hB, hBbf, hA, hAbf, ecnt, edgep,
                                   conv_w + 4096, conv_b + 64,  ln_g, ln_b);
  conv_k<<<2048, 512, 0, stream>>>(hA, hAbf, hB, (u16*)nullptr, ecnt, edgep,
                                   conv_w + 8192, conv_b + 128, ln_g, ln_b);
  fc_final_k<<<NN / 64, 256, 0, stream>>>(hB, ln2_g, ln2_b, w3, b3, w4, b4, out);
}

// Round 19
// 216.800 us; speedup vs baseline: 1.0602x; 1.0173x over previous
//
#include <hip/hip_runtime.h>

#define NN   65536
#define NE   1048576
#define CAP  48        // per-node edge capacity (Poisson(16): P(deg>=48)~5e-6)
#define NP   512       // partitions (128 nodes each), bin = dst >> 7
#define NODP 128       // nodes per partition
#define PCAP 2560      // partition capacity: mean 2048 + ~11 sd
#define FIN  128
#define HD   64
#define NOUT 32
#define EPSV 1e-5f
#define REPS 4         // nodes per wave (front-end pipelined)

typedef unsigned short u16;
typedef unsigned int u32;

__device__ __forceinline__ float wsum(float v) {
#pragma unroll
  for (int o = 32; o > 0; o >>= 1) v += __shfl_xor(v, o, 64);
  return v;
}

__device__ __forceinline__ u16 f2bf(float f) {
  u32 x = __float_as_uint(f);
  u32 r = x + 0x7FFFu + ((x >> 16) & 1u);   // round-to-nearest-even
  return (u16)(r >> 16);
}
__device__ __forceinline__ float bf2f(u16 u) {
  return __uint_as_float((u32)u << 16);
}

__device__ __forceinline__ void fma4bf(float4& acc, uint2 g, float w) {
  acc.x += __uint_as_float(g.x << 16) * w;
  acc.y += __uint_as_float(g.x & 0xFFFF0000u) * w;
  acc.z += __uint_as_float(g.y << 16) * w;
  acc.w += __uint_as_float(g.y & 0xFFFF0000u) * w;
}

// ---------------- pass A: partition edges into 512 coarse bins (coalesced runs) --------
__global__ __launch_bounds__(1024) void passA_k(
    const int* __restrict__ src, const int* __restrict__ dst,
    const float* __restrict__ ew, int* __restrict__ pcnt,
    uint2* __restrict__ tmp) {
  __shared__ int hist[NP];
  __shared__ int base[NP];
  int t = threadIdx.x;
  if (t < NP) hist[t] = 0;
  __syncthreads();

  int d[4], s[4];
  float w[4];
  size_t e0 = (size_t)blockIdx.x * 4096;
#pragma unroll
  for (int r = 0; r < 4; ++r) {
    int i = e0 + r * 1024 + t;
    d[r] = dst[i]; s[r] = src[i]; w[r] = ew[i];
    atomicAdd(&hist[d[r] >> 7], 1);
  }
  __syncthreads();
  if (t < NP) {
    int c = hist[t];
    base[t] = c ? atomicAdd(&pcnt[t], c) : 0;
    hist[t] = 0;                 // reuse as cursor
  }
  __syncthreads();
#pragma unroll
  for (int r = 0; r < 4; ++r) {
    int bin = d[r] >> 7;
    int pos = base[bin] + atomicAdd(&hist[bin], 1);
    if (pos < PCAP)
      tmp[(size_t)bin * PCAP + pos] =
          make_uint2(((u32)d[r] << 16) | (u32)s[r], __float_as_uint(w[r]));
  }
}

// ---------------- pass B: per-partition CSR build + pad-to-4 zero-weight slots --------
__global__ __launch_bounds__(256) void passB_k(
    const uint2* __restrict__ tmp, const int* __restrict__ pcnt,
    u32* __restrict__ edgep, int* __restrict__ ecnt) {
  __shared__ int cur[NODP];
  int p = blockIdx.x, t = threadIdx.x;
  if (t < NODP) cur[t] = 0;
  __syncthreads();
  int cntp = min(pcnt[p], PCAP);
  const uint2* tp = tmp + (size_t)p * PCAP;
  for (int i = t; i < cntp; i += 256) {
    uint2 e = tp[i];
    int dd = e.x >> 16;
    int pos = atomicAdd(&cur[dd & (NODP - 1)], 1);
    if (pos < CAP)
      edgep[(size_t)dd * CAP + pos] =
          (e.x & 0xFFFFu) | ((u32)f2bf(__uint_as_float(e.y)) << 16);
  }
  __syncthreads();
  if (t < NODP) {
    int node = p * NODP + t;
    int c = min(cur[t], CAP);
    int padded = min((c + 3) & ~3, CAP);
    for (int s = c; s < padded; ++s)
      edgep[(size_t)node * CAP + s] = 0u;   // src 0, bf16 weight 0
    ecnt[node] = padded;
  }
}

// ---------------- fc_first: LN(128) -> [128x64] -> ELU -> LN(64), 4 lanes/node -------
// Output: bf16 mirror only (h lives in bf16 from here on).
__global__ __launch_bounds__(256, 4) void fc_first_k(
    const float* __restrict__ x, const float* __restrict__ ln1_g,
    const float* __restrict__ ln1_b, const float* __restrict__ w1,
    const float* __restrict__ b1, const float* __restrict__ ln_g,
    const float* __restrict__ ln_b, u16* __restrict__ hAbf) {
  __shared__ __align__(16) float sW[FIN * HD];   // [k][j]
  __shared__ __align__(16) float sG[FIN], sB[FIN];
  __shared__ __align__(16) float sB1[HD], sLG[HD], sLB[HD];
  int tid = threadIdx.x;
  {
    const float4* w4 = (const float4*)w1;
    float4* s4 = (float4*)sW;
    for (int i = tid; i < FIN * HD / 4; i += 256) s4[i] = w4[i];
    if (tid < FIN) { sG[tid] = ln1_g[tid]; sB[tid] = ln1_b[tid]; }
    if (tid < HD) { sB1[tid] = b1[tid]; sLG[tid] = ln_g[tid]; sLB[tid] = ln_b[tid]; }
  }
  __syncthreads();

  int jq = tid & 3;                      // owns output features jq*16 .. jq*16+15
  int node = blockIdx.x * 64 + (tid >> 2);
  const float4* xp = (const float4*)(x + (size_t)node * FIN);

  float s = 0.f, s2 = 0.f;
  for (int i = 0; i < FIN / 4; ++i) {
    float4 v = xp[i];
    s += v.x + v.y + v.z + v.w;
    s2 += v.x * v.x + v.y * v.y + v.z * v.z + v.w * v.w;
  }
  float mean = s * (1.f / FIN);
  float var = s2 * (1.f / FIN) - mean * mean;
  float r = rsqrtf(var + EPSV);

  float acc[16];
#pragma unroll
  for (int jb = 0; jb < 4; ++jb) {
    float4 b = ((const float4*)sB1)[jq * 4 + jb];
    acc[jb * 4 + 0] = b.x; acc[jb * 4 + 1] = b.y;
    acc[jb * 4 + 2] = b.z; acc[jb * 4 + 3] = b.w;
  }
  const float4* sW4 = (const float4*)sW;   // 16 float4 per k-row
  for (int k4 = 0; k4 < FIN / 4; ++k4) {
    float4 xk = xp[k4];
    float4 g4 = ((const float4*)sG)[k4];
    float4 bb4 = ((const float4*)sB)[k4];
    float xn0 = (xk.x - mean) * r * g4.x + bb4.x;
    float xn1 = (xk.y - mean) * r * g4.y + bb4.y;
    float xn2 = (xk.z - mean) * r * g4.z + bb4.z;
    float xn3 = (xk.w - mean) * r * g4.w + bb4.w;
#pragma unroll
    for (int jb = 0; jb < 4; ++jb) {
      float4 w0 = sW4[(k4 * 4 + 0) * 16 + jq * 4 + jb];
      float4 w1v = sW4[(k4 * 4 + 1) * 16 + jq * 4 + jb];
      float4 w2 = sW4[(k4 * 4 + 2) * 16 + jq * 4 + jb];
      float4 w3v = sW4[(k4 * 4 + 3) * 16 + jq * 4 + jb];
      acc[jb * 4 + 0] += xn0 * w0.x + xn1 * w1v.x + xn2 * w2.x + xn3 * w3v.x;
      acc[jb * 4 + 1] += xn0 * w0.y + xn1 * w1v.y + xn2 * w2.y + xn3 * w3v.y;
      acc[jb * 4 + 2] += xn0 * w0.z + xn1 * w1v.z + xn2 * w2.z + xn3 * w3v.z;
      acc[jb * 4 + 3] += xn0 * w0.w + xn1 * w1v.w + xn2 * w2.w + xn3 * w3v.w;
    }
  }

  float s3 = 0.f;
#pragma unroll
  for (int j = 0; j < 16; ++j) {
    float y = acc[j];
    y = (y > 0.f) ? y : expm1f(y);
    acc[j] = y;
    s3 += y;
  }
  s3 += __shfl_xor(s3, 1, 64);
  s3 += __shfl_xor(s3, 2, 64);
  float m2 = s3 * (1.f / HD);
  float v2 = 0.f;
#pragma unroll
  for (int j = 0; j < 16; ++j) { float d = acc[j] - m2; v2 += d * d; }
  v2 += __shfl_xor(v2, 1, 64);
  v2 += __shfl_xor(v2, 2, 64);
  float r2 = rsqrtf(v2 * (1.f / HD) + EPSV);

  short4* mp = (short4*)(hAbf + (size_t)node * HD + jq * 16);
#pragma unroll
  for (int jb = 0; jb < 4; ++jb) {
    float4 g4 = ((const float4*)sLG)[jq * 4 + jb];
    float4 b4 = ((const float4*)sLB)[jq * 4 + jb];
    short4 m4;
    m4.x = (short)f2bf((acc[jb * 4 + 0] - m2) * r2 * g4.x + b4.x);
    m4.y = (short)f2bf((acc[jb * 4 + 1] - m2) * r2 * g4.y + b4.y);
    m4.z = (short)f2bf((acc[jb * 4 + 2] - m2) * r2 * g4.z + b4.z);
    m4.w = (short)f2bf((acc[jb * 4 + 3] - m2) * r2 * g4.w + b4.w);
    mp[jb] = m4;
  }
}

// ---------------- conv: bf16 residual, clamp-31 headers, pipelined front-end ---------
__global__ __launch_bounds__(512, 8) void conv_k(
    const u16* __restrict__ hbf_in, u16* __restrict__ hbf_out,
    const int* __restrict__ ecnt, const u32* __restrict__ edgep,
    const float* __restrict__ W, const float* __restrict__ B,
    const float* __restrict__ ln_g, const float* __restrict__ ln_b) {
  __shared__ __align__(16) float sWt[HD * 68];   // [j][k], pad 68
  __shared__ __align__(16) float sagg[8][HD];    // per-wave
  int tid = threadIdx.x;
  for (int i = tid; i < HD * HD; i += 512) {
    int k = i >> 6, j = i & 63;
    sWt[j * 68 + k] = W[i];
  }
  __syncthreads();   // only barrier: W staging

  int wl = tid >> 6, lane = tid & 63;
  float bias = B[lane], lg = ln_g[lane], lb = ln_b[lane];
  int gw = blockIdx.x * 8 + wl;        // 16384 waves, REPS nodes each
  int q = lane >> 4;                   // quarter: edge within group of 4
  int fq = lane & 15;                  // feature-quad

  // ---- front-end preload: all REPS (cnt, header) pairs in flight together ----
  // header clamp 31: 2 cache lines/node; deg>32 handled by direct-load tail.
  int cntR[REPS];
  u32 HR[REPS];
#pragma unroll
  for (int rp = 0; rp < REPS; ++rp) {
    int n = gw + rp * 16384;
    cntR[rp] = ecnt[n];
    HR[rp] = edgep[(size_t)n * CAP + min(lane, 31)];
  }

#pragma unroll
  for (int rp = 0; rp < REPS; ++rp) {
    int n = gw + rp * 16384;
    int cnt = cntR[rp];
    u32 H = HR[rp];

    float4 acc = make_float4(0.f, 0.f, 0.f, 0.f);
    if (cnt > 0) {
      int ng = cnt >> 2;               // groups of 4 edges, <= 12
      int ngs = min(ng, 8);            // groups with headers in H (j < 32)
      int g = 0;
      for (; g + 4 <= ngs; g += 4) {   // 16 edges, 4 gathers in flight
        u32 h0 = __shfl(H, (g + 0) * 4 + q, 64);
        u32 h1 = __shfl(H, (g + 1) * 4 + q, 64);
        u32 h2 = __shfl(H, (g + 2) * 4 + q, 64);
        u32 h3 = __shfl(H, (g + 3) * 4 + q, 64);
        uint2 g0 = ((const uint2*)(hbf_in + ((size_t)(h0 & 0xFFFFu) << 6)))[fq];
        uint2 g1 = ((const uint2*)(hbf_in + ((size_t)(h1 & 0xFFFFu) << 6)))[fq];
        uint2 g2 = ((const uint2*)(hbf_in + ((size_t)(h2 & 0xFFFFu) << 6)))[fq];
        uint2 g3 = ((const uint2*)(hbf_in + ((size_t)(h3 & 0xFFFFu) << 6)))[fq];
        fma4bf(acc, g0, __uint_as_float(h0 & 0xFFFF0000u));
        fma4bf(acc, g1, __uint_as_float(h1 & 0xFFFF0000u));
        fma4bf(acc, g2, __uint_as_float(h2 & 0xFFFF0000u));
        fma4bf(acc, g3, __uint_as_float(h3 & 0xFFFF0000u));
      }
      for (; g < ngs; ++g) {           // remaining in-header groups
        u32 hj = __shfl(H, g * 4 + q, 64);
        uint2 gg = ((const uint2*)(hbf_in + ((size_t)(hj & 0xFFFFu) << 6)))[fq];
        fma4bf(acc, gg, __uint_as_float(hj & 0xFFFF0000u));
      }
      for (; g < ng; ++g) {            // rare deg>32 tail: direct header load
        u32 hj = edgep[(size_t)n * CAP + g * 4 + q];
        uint2 gg = ((const uint2*)(hbf_in + ((size_t)(hj & 0xFFFFu) << 6)))[fq];
        fma4bf(acc, gg, __uint_as_float(hj & 0xFFFF0000u));
      }
    }
#pragma unroll
    for (int off = 16; off < 64; off <<= 1) {
      acc.x += __shfl_xor(acc.x, off, 64);
      acc.y += __shfl_xor(acc.y, off, 64);
      acc.z += __shfl_xor(acc.z, off, 64);
      acc.w += __shfl_xor(acc.w, off, 64);
    }
    // per-wave staging: same-wave RAW, no barrier needed
    if (lane < 16) ((float4*)sagg[wl])[lane] = acc;

    float y = bias;
    const float4* ar = (const float4*)sagg[wl];
    const float4* wr = (const float4*)&sWt[lane * 68];
#pragma unroll
    for (int k4 = 0; k4 < HD / 4; ++k4) {
      float4 a4 = ar[k4];              // uniform broadcast
      float4 w4v = wr[k4];
      y += a4.x * w4v.x + a4.y * w4v.y + a4.z * w4v.z + a4.w * w4v.w;
    }

    float m = wsum(y) * (1.f / HD);
    float d = y - m;
    float v = wsum(d * d) * (1.f / HD);
    float ln = d * rsqrtf(v + EPSV) * lg + lb;
    float hv = bf2f(hbf_in[(size_t)n * HD + lane]) + ln;   // bf16 residual
    hbf_out[(size_t)n * HD + lane] = f2bf(hv);
  }
}

// ---------------- fc_final: LN(64) -> [64x64]+b3 -> ELU -> [64x32]+b4, 4 lanes/node --
// Input: bf16 h.
__global__ __launch_bounds__(256, 4) void fc_final_k(
    const u16* __restrict__ hbf, const float* __restrict__ ln2_g,
    const float* __restrict__ ln2_b, const float* __restrict__ w3,
    const float* __restrict__ b3, const float* __restrict__ w4,
    const float* __restrict__ b4, float* __restrict__ out) {
  __shared__ __align__(16) float sW3[HD * HD];     // [k][j]
  __shared__ __align__(16) float sW4[HD * NOUT];   // [k][j]
  __shared__ __align__(16) float sG[HD], sB[HD], sB3[HD], sB4[NOUT];
  int tid = threadIdx.x;
  {
    const float4* a = (const float4*)w3;
    float4* d4 = (float4*)sW3;
    for (int i = tid; i < HD * HD / 4; i += 256) d4[i] = a[i];
    const float4* c = (const float4*)w4;
    float4* e4 = (float4*)sW4;
    for (int i = tid; i < HD * NOUT / 4; i += 256) e4[i] = c[i];
    if (tid < HD) { sG[tid] = ln2_g[tid]; sB[tid] = ln2_b[tid]; sB3[tid] = b3[tid]; }
    if (tid < NOUT) sB4[tid] = b4[tid];
  }
  __syncthreads();

  int jq = tid & 3;
  int node = blockIdx.x * 64 + (tid >> 2);
  const u32* hr = (const u32*)(hbf + (size_t)node * HD);   // 32 u32 = 64 bf16

  float s = 0.f, s2 = 0.f;
  for (int i = 0; i < 8; ++i) {
    uint4 v = ((const uint4*)hr)[i];
    float f0 = __uint_as_float(v.x << 16), f1 = __uint_as_float(v.x & 0xFFFF0000u);
    float f2 = __uint_as_float(v.y << 16), f3 = __uint_as_float(v.y & 0xFFFF0000u);
    float f4 = __uint_as_float(v.z << 16), f5 = __uint_as_float(v.z & 0xFFFF0000u);
    float f6 = __uint_as_float(v.w << 16), f7 = __uint_as_float(v.w & 0xFFFF0000u);
    s += f0 + f1 + f2 + f3 + f4 + f5 + f6 + f7;
    s2 += f0 * f0 + f1 * f1 + f2 * f2 + f3 * f3
        + f4 * f4 + f5 * f5 + f6 * f6 + f7 * f7;
  }
  float mean = s * (1.f / HD);
  float var = s2 * (1.f / HD) - mean * mean;
  float r = rsqrtf(var + EPSV);

  float acc[16];                       // z features jq*16 .. jq*16+15
#pragma unroll
  for (int jb = 0; jb < 4; ++jb) {
    float4 b = ((const float4*)sB3)[jq * 4 + jb];
    acc[jb * 4 + 0] = b.x; acc[jb * 4 + 1] = b.y;
    acc[jb * 4 + 2] = b.z; acc[jb * 4 + 3] = b.w;
  }
  const float4* sW34 = (const float4*)sW3;
  for (int k4 = 0; k4 < HD / 4; ++k4) {
    uint2 rw = ((const uint2*)hr)[k4];
    float xk0 = __uint_as_float(rw.x << 16);
    float xk1 = __uint_as_float(rw.x & 0xFFFF0000u);
    float xk2 = __uint_as_float(rw.y << 16);
    float xk3 = __uint_as_float(rw.y & 0xFFFF0000u);
    float4 g4 = ((const float4*)sG)[k4];
    float4 bb4 = ((const float4*)sB)[k4];
    float xn0 = (xk0 - mean) * r * g4.x + bb4.x;
    float xn1 = (xk1 - mean) * r * g4.y + bb4.y;
    float xn2 = (xk2 - mean) * r * g4.z + bb4.z;
    float xn3 = (xk3 - mean) * r * g4.w + bb4.w;
#pragma unroll
    for (int jb = 0; jb < 4; ++jb) {
      float4 w0 = sW34[(k4 * 4 + 0) * 16 + jq * 4 + jb];
      float4 w1v = sW34[(k4 * 4 + 1) * 16 + jq * 4 + jb];
      float4 w2 = sW34[(k4 * 4 + 2) * 16 + jq * 4 + jb];
      float4 w3v = sW34[(k4 * 4 + 3) * 16 + jq * 4 + jb];
      acc[jb * 4 + 0] += xn0 * w0.x + xn1 * w1v.x + xn2 * w2.x + xn3 * w3v.x;
      acc[jb * 4 + 1] += xn0 * w0.y + xn1 * w1v.y + xn2 * w2.y + xn3 * w3v.y;
      acc[jb * 4 + 2] += xn0 * w0.z + xn1 * w1v.z + xn2 * w2.z + xn3 * w3v.z;
      acc[jb * 4 + 3] += xn0 * w0.w + xn1 * w1v.w + xn2 * w2.w + xn3 * w3v.w;
    }
  }

#pragma unroll
  for (int j = 0; j < 16; ++j) {
    float y = acc[j];
    acc[j] = (y > 0.f) ? y : expm1f(y);
  }

  // GEMM2: partial over this lane's 16 k, 2 output chunks of 16; 4-lane xor-reduce
  const float4* sW44 = (const float4*)sW4;   // 8 float4 per k-row
#pragma unroll
  for (int c = 0; c < 2; ++c) {
    float p[16];
#pragma unroll
    for (int i = 0; i < 16; ++i) p[i] = 0.f;
#pragma unroll
    for (int kk = 0; kk < 16; ++kk) {
      float zk = acc[kk];
      int krow = jq * 16 + kk;
#pragma unroll
      for (int qd = 0; qd < 4; ++qd) {
        float4 w = sW44[krow * 8 + c * 4 + qd];
        p[qd * 4 + 0] += zk * w.x;
        p[qd * 4 + 1] += zk * w.y;
        p[qd * 4 + 2] += zk * w.z;
        p[qd * 4 + 3] += zk * w.w;
      }
    }
#pragma unroll
    for (int i = 0; i < 16; ++i) {
      p[i] += __shfl_xor(p[i], 1, 64);
      p[i] += __shfl_xor(p[i], 2, 64);
    }
    if (jq == c) {
      float4* op = (float4*)(out + (size_t)node * NOUT + c * 16);
#pragma unroll
      for (int qd = 0; qd < 4; ++qd) {
        float4 b = ((const float4*)sB4)[c * 4 + qd];
        float4 o;
        o.x = p[qd * 4 + 0] + b.x; o.y = p[qd * 4 + 1] + b.y;
        o.z = p[qd * 4 + 2] + b.z; o.w = p[qd * 4 + 3] + b.w;
        op[qd] = o;
      }
    }
  }
}

extern "C" void kernel_launch(void* const* d_in, const int* in_sizes, int n_in,
                              void* d_out, int out_size, void* d_ws, size_t ws_size,
                              hipStream_t stream) {
  const float* x      = (const float*)d_in[0];
  const float* ew     = (const float*)d_in[1];
  const int*   src    = (const int*)d_in[2];
  const int*   dst    = (const int*)d_in[3];
  const float* ln1_g  = (const float*)d_in[4];
  const float* ln1_b  = (const float*)d_in[5];
  const float* w1     = (const float*)d_in[6];
  const float* b1     = (const float*)d_in[7];
  const float* ln_g   = (const float*)d_in[8];
  const float* ln_b   = (const float*)d_in[9];
  const float* conv_w = (const float*)d_in[10];
  const float* conv_b = (const float*)d_in[11];
  const float* ln2_g  = (const float*)d_in[12];
  const float* ln2_b  = (const float*)d_in[13];
  const float* w3     = (const float*)d_in[14];
  const float* b3     = (const float*)d_in[15];
  const float* w4     = (const float*)d_in[16];
  const float* b4     = (const float*)d_in[17];
  float* out = (float*)d_out;

  char* ws = (char*)d_ws;
  u16*   hAbf  = (u16*)ws;                           // 8 MB
  u16*   hBbf  = hAbf + (size_t)NN * HD;             // 8 MB
  int*   ecnt  = (int*)(hBbf + (size_t)NN * HD);     // 256 KB (+pad)
  u32*   edgep = (u32*)(ecnt + NN + 64);             // NN*CAP*4B = 12.6 MB
  int*   pcnt  = (int*)(edgep + (size_t)NN * CAP);   // NP ints (+pad)
  uint2* tmp   = (uint2*)(pcnt + NP + 64);           // NP*PCAP*8B = 10.5 MB

  hipMemsetAsync(pcnt, 0, NP * sizeof(int), stream);
  passA_k<<<NE / 4096, 1024, 0, stream>>>(src, dst, ew, pcnt, tmp);
  passB_k<<<NP, 256, 0, stream>>>(tmp, pcnt, edgep, ecnt);

  fc_first_k<<<NN / 64, 256, 0, stream>>>(x, ln1_g, ln1_b, w1, b1, ln_g, ln_b,
                                          hAbf);
  conv_k<<<2048, 512, 0, stream>>>(hAbf, hBbf, ecnt, edgep,
                                   conv_w,        conv_b,       ln_g, ln_b);
  conv_k<<<2048, 512, 0, stream>>>(hBbf, hAbf, ecnt, edgep,
                                   conv_w + 4096, conv_b + 64,  ln_g, ln_b);
  conv_k<<<2048, 512, 0, stream>>>(hAbf, hBbf, ecnt, edgep,
                                   conv_w + 8192, conv_b + 128, ln_g, ln_b);
  fc_final_k<<<NN / 64, 256, 0, stream>>>(hBbf, ln2_g, ln2_b, w3, b3, w4, b4, out);
}

// Round 20
// 187.888 us; speedup vs baseline: 1.2233x; 1.1539x over previous
//
#include <hip/hip_runtime.h>

#define NN   65536
#define NE   1048576
#define CAP  48        // per-node edge capacity (Poisson(16): P(deg>=48)~5e-6)
#define NP   512       // partitions (128 nodes each), bin = dst >> 7
#define NODP 128       // nodes per partition
#define PCAP 2560      // partition capacity: mean 2048 + ~11 sd
#define FIN  128
#define HD   64
#define NOUT 32
#define EPSV 1e-5f

typedef unsigned short u16;
typedef unsigned int u32;
typedef __attribute__((ext_vector_type(8))) short short8v;   // 8 bf16
typedef __attribute__((ext_vector_type(4))) float f32x4;

__device__ __forceinline__ u16 f2bf(float f) {
  u32 x = __float_as_uint(f);
  u32 r = x + 0x7FFFu + ((x >> 16) & 1u);   // round-to-nearest-even
  return (u16)(r >> 16);
}
__device__ __forceinline__ float bf2f(u16 u) {
  return __uint_as_float((u32)u << 16);
}

__device__ __forceinline__ void fma4bf(float4& acc, uint2 g, float w) {
  acc.x += __uint_as_float(g.x << 16) * w;
  acc.y += __uint_as_float(g.x & 0xFFFF0000u) * w;
  acc.z += __uint_as_float(g.y << 16) * w;
  acc.w += __uint_as_float(g.y & 0xFFFF0000u) * w;
}

// ---------------- pass A: partition edges into 512 coarse bins (coalesced runs) --------
__global__ __launch_bounds__(1024) void passA_k(
    const int* __restrict__ src, const int* __restrict__ dst,
    const float* __restrict__ ew, int* __restrict__ pcnt,
    uint2* __restrict__ tmp) {
  __shared__ int hist[NP];
  __shared__ int base[NP];
  int t = threadIdx.x;
  if (t < NP) hist[t] = 0;
  __syncthreads();

  int d[4], s[4];
  float w[4];
  size_t e0 = (size_t)blockIdx.x * 4096;
#pragma unroll
  for (int r = 0; r < 4; ++r) {
    int i = e0 + r * 1024 + t;
    d[r] = dst[i]; s[r] = src[i]; w[r] = ew[i];
    atomicAdd(&hist[d[r] >> 7], 1);
  }
  __syncthreads();
  if (t < NP) {
    int c = hist[t];
    base[t] = c ? atomicAdd(&pcnt[t], c) : 0;
    hist[t] = 0;                 // reuse as cursor
  }
  __syncthreads();
#pragma unroll
  for (int r = 0; r < 4; ++r) {
    int bin = d[r] >> 7;
    int pos = base[bin] + atomicAdd(&hist[bin], 1);
    if (pos < PCAP)
      tmp[(size_t)bin * PCAP + pos] =
          make_uint2(((u32)d[r] << 16) | (u32)s[r], __float_as_uint(w[r]));
  }
}

// ---------------- pass B: per-partition CSR build + pad-to-4 zero-weight slots --------
__global__ __launch_bounds__(256) void passB_k(
    const uint2* __restrict__ tmp, const int* __restrict__ pcnt,
    u32* __restrict__ edgep, int* __restrict__ ecnt) {
  __shared__ int cur[NODP];
  int p = blockIdx.x, t = threadIdx.x;
  if (t < NODP) cur[t] = 0;
  __syncthreads();
  int cntp = min(pcnt[p], PCAP);
  const uint2* tp = tmp + (size_t)p * PCAP;
  for (int i = t; i < cntp; i += 256) {
    uint2 e = tp[i];
    int dd = e.x >> 16;
    int pos = atomicAdd(&cur[dd & (NODP - 1)], 1);
    if (pos < CAP)
      edgep[(size_t)dd * CAP + pos] =
          (e.x & 0xFFFFu) | ((u32)f2bf(__uint_as_float(e.y)) << 16);
  }
  __syncthreads();
  if (t < NODP) {
    int node = p * NODP + t;
    int c = min(cur[t], CAP);
    int padded = min((c + 3) & ~3, CAP);
    for (int s = c; s < padded; ++s)
      edgep[(size_t)node * CAP + s] = 0u;   // src 0, bf16 weight 0
    ecnt[node] = padded;
  }
}

// ---------------- fc_first: LN(128) -> [128x64] -> ELU -> LN(64), 4 lanes/node -------
__global__ __launch_bounds__(256, 4) void fc_first_k(
    const float* __restrict__ x, const float* __restrict__ ln1_g,
    const float* __restrict__ ln1_b, const float* __restrict__ w1,
    const float* __restrict__ b1, const float* __restrict__ ln_g,
    const float* __restrict__ ln_b, u16* __restrict__ hAbf) {
  __shared__ __align__(16) float sW[FIN * HD];   // [k][j]
  __shared__ __align__(16) float sG[FIN], sB[FIN];
  __shared__ __align__(16) float sB1[HD], sLG[HD], sLB[HD];
  int tid = threadIdx.x;
  {
    const float4* w4 = (const float4*)w1;
    float4* s4 = (float4*)sW;
    for (int i = tid; i < FIN * HD / 4; i += 256) s4[i] = w4[i];
    if (tid < FIN) { sG[tid] = ln1_g[tid]; sB[tid] = ln1_b[tid]; }
    if (tid < HD) { sB1[tid] = b1[tid]; sLG[tid] = ln_g[tid]; sLB[tid] = ln_b[tid]; }
  }
  __syncthreads();

  int jq = tid & 3;
  int node = blockIdx.x * 64 + (tid >> 2);
  const float4* xp = (const float4*)(x + (size_t)node * FIN);

  float s = 0.f, s2 = 0.f;
  for (int i = 0; i < FIN / 4; ++i) {
    float4 v = xp[i];
    s += v.x + v.y + v.z + v.w;
    s2 += v.x * v.x + v.y * v.y + v.z * v.z + v.w * v.w;
  }
  float mean = s * (1.f / FIN);
  float var = s2 * (1.f / FIN) - mean * mean;
  float r = rsqrtf(var + EPSV);

  float acc[16];
#pragma unroll
  for (int jb = 0; jb < 4; ++jb) {
    float4 b = ((const float4*)sB1)[jq * 4 + jb];
    acc[jb * 4 + 0] = b.x; acc[jb * 4 + 1] = b.y;
    acc[jb * 4 + 2] = b.z; acc[jb * 4 + 3] = b.w;
  }
  const float4* sW4 = (const float4*)sW;   // 16 float4 per k-row
  for (int k4 = 0; k4 < FIN / 4; ++k4) {
    float4 xk = xp[k4];
    float4 g4 = ((const float4*)sG)[k4];
    float4 bb4 = ((const float4*)sB)[k4];
    float xn0 = (xk.x - mean) * r * g4.x + bb4.x;
    float xn1 = (xk.y - mean) * r * g4.y + bb4.y;
    float xn2 = (xk.z - mean) * r * g4.z + bb4.z;
    float xn3 = (xk.w - mean) * r * g4.w + bb4.w;
#pragma unroll
    for (int jb = 0; jb < 4; ++jb) {
      float4 w0 = sW4[(k4 * 4 + 0) * 16 + jq * 4 + jb];
      float4 w1v = sW4[(k4 * 4 + 1) * 16 + jq * 4 + jb];
      float4 w2 = sW4[(k4 * 4 + 2) * 16 + jq * 4 + jb];
      float4 w3v = sW4[(k4 * 4 + 3) * 16 + jq * 4 + jb];
      acc[jb * 4 + 0] += xn0 * w0.x + xn1 * w1v.x + xn2 * w2.x + xn3 * w3v.x;
      acc[jb * 4 + 1] += xn0 * w0.y + xn1 * w1v.y + xn2 * w2.y + xn3 * w3v.y;
      acc[jb * 4 + 2] += xn0 * w0.z + xn1 * w1v.z + xn2 * w2.z + xn3 * w3v.z;
      acc[jb * 4 + 3] += xn0 * w0.w + xn1 * w1v.w + xn2 * w2.w + xn3 * w3v.w;
    }
  }

  float s3 = 0.f;
#pragma unroll
  for (int j = 0; j < 16; ++j) {
    float y = acc[j];
    y = (y > 0.f) ? y : expm1f(y);
    acc[j] = y;
    s3 += y;
  }
  s3 += __shfl_xor(s3, 1, 64);
  s3 += __shfl_xor(s3, 2, 64);
  float m2 = s3 * (1.f / HD);
  float v2 = 0.f;
#pragma unroll
  for (int j = 0; j < 16; ++j) { float d = acc[j] - m2; v2 += d * d; }
  v2 += __shfl_xor(v2, 1, 64);
  v2 += __shfl_xor(v2, 2, 64);
  float r2 = rsqrtf(v2 * (1.f / HD) + EPSV);

  short4* mp = (short4*)(hAbf + (size_t)node * HD + jq * 16);
#pragma unroll
  for (int jb = 0; jb < 4; ++jb) {
    float4 g4 = ((const float4*)sLG)[jq * 4 + jb];
    float4 b4 = ((const float4*)sLB)[jq * 4 + jb];
    short4 m4;
    m4.x = (short)f2bf((acc[jb * 4 + 0] - m2) * r2 * g4.x + b4.x);
    m4.y = (short)f2bf((acc[jb * 4 + 1] - m2) * r2 * g4.y + b4.y);
    m4.z = (short)f2bf((acc[jb * 4 + 2] - m2) * r2 * g4.z + b4.z);
    m4.w = (short)f2bf((acc[jb * 4 + 3] - m2) * r2 * g4.w + b4.w);
    mp[jb] = m4;
  }
}

// ---------------- conv: gather -> MFMA GEMM (bf16) -> LN -> bf16 residual ------------
// 32 nodes/block. Phase1: gather agg rows (bf16 LDS). Phase2: 8 waves x
// (16-node x 16-j) tiles via mfma_f32_16x16x32_bf16. Phase3: LN + residual.
__global__ __launch_bounds__(512, 8) void conv_k(
    const u16* __restrict__ hbf_in, u16* __restrict__ hbf_out,
    const int* __restrict__ ecnt, const u32* __restrict__ edgep,
    const float* __restrict__ W, const float* __restrict__ B,
    const float* __restrict__ ln_g, const float* __restrict__ ln_b) {
  __shared__ __align__(16) u16 sWt[HD * 72];      // [j][k] bf16, row pad 72
  __shared__ __align__(16) u16 sAgg[32 * 72];     // [node][k] bf16, row pad 72
  __shared__ __align__(16) float sOut[32 * 68];   // [node][j] f32, row pad 68
  int tid = threadIdx.x;
  for (int i = tid; i < HD * HD; i += 512) {
    int k = i >> 6, j = i & 63;          // W[k][j]
    sWt[j * 72 + k] = f2bf(W[i]);
  }

  int wl = tid >> 6, lane = tid & 63;
  int q = lane >> 4;                   // quarter
  int fq = lane & 15;
  int nbase = blockIdx.x * 32;

  // front-end preload: this wave's 4 nodes
  int cntR[4];
  u32 HR[4];
#pragma unroll
  for (int rp = 0; rp < 4; ++rp) {
    int n = nbase + wl * 4 + rp;
    cntR[rp] = ecnt[n];
    HR[rp] = edgep[(size_t)n * CAP + min(lane, 31)];
  }

  // ---- phase 1: gather 4 nodes, write bf16 agg rows ----
#pragma unroll
  for (int rp = 0; rp < 4; ++rp) {
    int n = nbase + wl * 4 + rp;
    int cnt = cntR[rp];
    u32 H = HR[rp];

    float4 acc = make_float4(0.f, 0.f, 0.f, 0.f);
    if (cnt > 0) {
      int ng = cnt >> 2;
      int ngs = min(ng, 8);            // groups with headers in H
      int g = 0;
      for (; g + 4 <= ngs; g += 4) {
        u32 h0 = __shfl(H, (g + 0) * 4 + q, 64);
        u32 h1 = __shfl(H, (g + 1) * 4 + q, 64);
        u32 h2 = __shfl(H, (g + 2) * 4 + q, 64);
        u32 h3 = __shfl(H, (g + 3) * 4 + q, 64);
        uint2 g0 = ((const uint2*)(hbf_in + ((size_t)(h0 & 0xFFFFu) << 6)))[fq];
        uint2 g1 = ((const uint2*)(hbf_in + ((size_t)(h1 & 0xFFFFu) << 6)))[fq];
        uint2 g2 = ((const uint2*)(hbf_in + ((size_t)(h2 & 0xFFFFu) << 6)))[fq];
        uint2 g3 = ((const uint2*)(hbf_in + ((size_t)(h3 & 0xFFFFu) << 6)))[fq];
        fma4bf(acc, g0, __uint_as_float(h0 & 0xFFFF0000u));
        fma4bf(acc, g1, __uint_as_float(h1 & 0xFFFF0000u));
        fma4bf(acc, g2, __uint_as_float(h2 & 0xFFFF0000u));
        fma4bf(acc, g3, __uint_as_float(h3 & 0xFFFF0000u));
      }
      for (; g < ngs; ++g) {
        u32 hj = __shfl(H, g * 4 + q, 64);
        uint2 gg = ((const uint2*)(hbf_in + ((size_t)(hj & 0xFFFFu) << 6)))[fq];
        fma4bf(acc, gg, __uint_as_float(hj & 0xFFFF0000u));
      }
      for (; g < ng; ++g) {            // rare deg>32 tail
        u32 hj = edgep[(size_t)n * CAP + g * 4 + q];
        uint2 gg = ((const uint2*)(hbf_in + ((size_t)(hj & 0xFFFFu) << 6)))[fq];
        fma4bf(acc, gg, __uint_as_float(hj & 0xFFFF0000u));
      }
    }
#pragma unroll
    for (int off = 16; off < 64; off <<= 1) {
      acc.x += __shfl_xor(acc.x, off, 64);
      acc.y += __shfl_xor(acc.y, off, 64);
      acc.z += __shfl_xor(acc.z, off, 64);
      acc.w += __shfl_xor(acc.w, off, 64);
    }
    if (lane < 16) {
      u32 p0 = (u32)f2bf(acc.x) | ((u32)f2bf(acc.y) << 16);
      u32 p1 = (u32)f2bf(acc.z) | ((u32)f2bf(acc.w) << 16);
      u32* dp = (u32*)&sAgg[(wl * 4 + rp) * 72 + fq * 4];
      dp[0] = p0; dp[1] = p1;
    }
  }
  __syncthreads();

  // ---- phase 2: MFMA. wave -> node-group g=wl>>2 (16 nodes), j-tile t=wl&3 ----
  {
    int g = wl >> 2, t = wl & 3;
    f32x4 d = {0.f, 0.f, 0.f, 0.f};
#pragma unroll
    for (int s = 0; s < 2; ++s) {
      short8v av = *(const short8v*)&sAgg[(g * 16 + fq) * 72 + s * 32 + q * 8];
      short8v bv = *(const short8v*)&sWt[(t * 16 + fq) * 72 + s * 32 + q * 8];
      d = __builtin_amdgcn_mfma_f32_16x16x32_bf16(av, bv, d, 0, 0, 0);
    }
#pragma unroll
    for (int reg = 0; reg < 4; ++reg) {
      int row = q * 4 + reg;           // node within group (D: row=(lane>>4)*4+reg)
      sOut[(g * 16 + row) * 68 + t * 16 + fq] = d[reg];
    }
  }
  __syncthreads();

  // ---- phase 3: bias + LN (single-pass moments) + bf16 residual ----
  float bias = B[lane], lg = ln_g[lane], lb = ln_b[lane];
#pragma unroll
  for (int rp = 0; rp < 4; ++rp) {
    int nl = wl * 4 + rp;
    int n = nbase + nl;
    float y = sOut[nl * 68 + lane] + bias;
    float a = y, b2 = y * y;
#pragma unroll
    for (int o = 32; o > 0; o >>= 1) {
      a += __shfl_xor(a, o, 64);
      b2 += __shfl_xor(b2, o, 64);
    }
    float m = a * (1.f / HD);
    float v = b2 * (1.f / HD) - m * m;
    float ln = (y - m) * rsqrtf(v + EPSV) * lg + lb;
    float hv = bf2f(hbf_in[(size_t)n * HD + lane]) + ln;
    hbf_out[(size_t)n * HD + lane] = f2bf(hv);
  }
}

// ---------------- fc_final: LN(64) -> [64x64]+b3 -> ELU -> [64x32]+b4, 4 lanes/node --
__global__ __launch_bounds__(256, 4) void fc_final_k(
    const u16* __restrict__ hbf, const float* __restrict__ ln2_g,
    const float* __restrict__ ln2_b, const float* __restrict__ w3,
    const float* __restrict__ b3, const float* __restrict__ w4,
    const float* __restrict__ b4, float* __restrict__ out) {
  __shared__ __align__(16) float sW3[HD * HD];     // [k][j]
  __shared__ __align__(16) float sW4[HD * NOUT];   // [k][j]
  __shared__ __align__(16) float sG[HD], sB[HD], sB3[HD], sB4[NOUT];
  int tid = threadIdx.x;
  {
    const float4* a = (const float4*)w3;
    float4* d4 = (float4*)sW3;
    for (int i = tid; i < HD * HD / 4; i += 256) d4[i] = a[i];
    const float4* c = (const float4*)w4;
    float4* e4 = (float4*)sW4;
    for (int i = tid; i < HD * NOUT / 4; i += 256) e4[i] = c[i];
    if (tid < HD) { sG[tid] = ln2_g[tid]; sB[tid] = ln2_b[tid]; sB3[tid] = b3[tid]; }
    if (tid < NOUT) sB4[tid] = b4[tid];
  }
  __syncthreads();

  int jq = tid & 3;
  int node = blockIdx.x * 64 + (tid >> 2);
  const u32* hr = (const u32*)(hbf + (size_t)node * HD);   // 32 u32 = 64 bf16

  float s = 0.f, s2 = 0.f;
  for (int i = 0; i < 8; ++i) {
    uint4 v = ((const uint4*)hr)[i];
    float f0 = __uint_as_float(v.x << 16), f1 = __uint_as_float(v.x & 0xFFFF0000u);
    float f2 = __uint_as_float(v.y << 16), f3 = __uint_as_float(v.y & 0xFFFF0000u);
    float f4 = __uint_as_float(v.z << 16), f5 = __uint_as_float(v.z & 0xFFFF0000u);
    float f6 = __uint_as_float(v.w << 16), f7 = __uint_as_float(v.w & 0xFFFF0000u);
    s += f0 + f1 + f2 + f3 + f4 + f5 + f6 + f7;
    s2 += f0 * f0 + f1 * f1 + f2 * f2 + f3 * f3
        + f4 * f4 + f5 * f5 + f6 * f6 + f7 * f7;
  }
  float mean = s * (1.f / HD);
  float var = s2 * (1.f / HD) - mean * mean;
  float r = rsqrtf(var + EPSV);

  float acc[16];
#pragma unroll
  for (int jb = 0; jb < 4; ++jb) {
    float4 b = ((const float4*)sB3)[jq * 4 + jb];
    acc[jb * 4 + 0] = b.x; acc[jb * 4 + 1] = b.y;
    acc[jb * 4 + 2] = b.z; acc[jb * 4 + 3] = b.w;
  }
  const float4* sW34 = (const float4*)sW3;
  for (int k4 = 0; k4 < HD / 4; ++k4) {
    uint2 rw = ((const uint2*)hr)[k4];
    float xk0 = __uint_as_float(rw.x << 16);
    float xk1 = __uint_as_float(rw.x & 0xFFFF0000u);
    float xk2 = __uint_as_float(rw.y << 16);
    float xk3 = __uint_as_float(rw.y & 0xFFFF0000u);
    float4 g4 = ((const float4*)sG)[k4];
    float4 bb4 = ((const float4*)sB)[k4];
    float xn0 = (xk0 - mean) * r * g4.x + bb4.x;
    float xn1 = (xk1 - mean) * r * g4.y + bb4.y;
    float xn2 = (xk2 - mean) * r * g4.z + bb4.z;
    float xn3 = (xk3 - mean) * r * g4.w + bb4.w;
#pragma unroll
    for (int jb = 0; jb < 4; ++jb) {
      float4 w0 = sW34[(k4 * 4 + 0) * 16 + jq * 4 + jb];
      float4 w1v = sW34[(k4 * 4 + 1) * 16 + jq * 4 + jb];
      float4 w2 = sW34[(k4 * 4 + 2) * 16 + jq * 4 + jb];
      float4 w3v = sW34[(k4 * 4 + 3) * 16 + jq * 4 + jb];
      acc[jb * 4 + 0] += xn0 * w0.x + xn1 * w1v.x + xn2 * w2.x + xn3 * w3v.x;
      acc[jb * 4 + 1] += xn0 * w0.y + xn1 * w1v.y + xn2 * w2.y + xn3 * w3v.y;
      acc[jb * 4 + 2] += xn0 * w0.z + xn1 * w1v.z + xn2 * w2.z + xn3 * w3v.z;
      acc[jb * 4 + 3] += xn0 * w0.w + xn1 * w1v.w + xn2 * w2.w + xn3 * w3v.w;
    }
  }

#pragma unroll
  for (int j = 0; j < 16; ++j) {
    float y = acc[j];
    acc[j] = (y > 0.f) ? y : expm1f(y);
  }

  const float4* sW44 = (const float4*)sW4;   // 8 float4 per k-row
#pragma unroll
  for (int c = 0; c < 2; ++c) {
    float p[16];
#pragma unroll
    for (int i = 0; i < 16; ++i) p[i] = 0.f;
#pragma unroll
    for (int kk = 0; kk < 16; ++kk) {
      float zk = acc[kk];
      int krow = jq * 16 + kk;
#pragma unroll
      for (int qd = 0; qd < 4; ++qd) {
        float4 w = sW44[krow * 8 + c * 4 + qd];
        p[qd * 4 + 0] += zk * w.x;
        p[qd * 4 + 1] += zk * w.y;
        p[qd * 4 + 2] += zk * w.z;
        p[qd * 4 + 3] += zk * w.w;
      }
    }
#pragma unroll
    for (int i = 0; i < 16; ++i) {
      p[i] += __shfl_xor(p[i], 1, 64);
      p[i] += __shfl_xor(p[i], 2, 64);
    }
    if (jq == c) {
      float4* op = (float4*)(out + (size_t)node * NOUT + c * 16);
#pragma unroll
      for (int qd = 0; qd < 4; ++qd) {
        float4 b = ((const float4*)sB4)[c * 4 + qd];
        float4 o;
        o.x = p[qd * 4 + 0] + b.x; o.y = p[qd * 4 + 1] + b.y;
        o.z = p[qd * 4 + 2] + b.z; o.w = p[qd * 4 + 3] + b.w;
        op[qd] = o;
      }
    }
  }
}

extern "C" void kernel_launch(void* const* d_in, const int* in_sizes, int n_in,
                              void* d_out, int out_size, void* d_ws, size_t ws_size,
                              hipStream_t stream) {
  const float* x      = (const float*)d_in[0];
  const float* ew     = (const float*)d_in[1];
  const int*   src    = (const int*)d_in[2];
  const int*   dst    = (const int*)d_in[3];
  const float* ln1_g  = (const float*)d_in[4];
  const float* ln1_b  = (const float*)d_in[5];
  const float* w1     = (const float*)d_in[6];
  const float* b1     = (const float*)d_in[7];
  const float* ln_g   = (const float*)d_in[8];
  const float* ln_b   = (const float*)d_in[9];
  const float* conv_w = (const float*)d_in[10];
  const float* conv_b = (const float*)d_in[11];
  const float* ln2_g  = (const float*)d_in[12];
  const float* ln2_b  = (const float*)d_in[13];
  const float* w3     = (const float*)d_in[14];
  const float* b3     = (const float*)d_in[15];
  const float* w4     = (const float*)d_in[16];
  const float* b4     = (const float*)d_in[17];
  float* out = (float*)d_out;

  char* ws = (char*)d_ws;
  u16*   hAbf  = (u16*)ws;                           // 8 MB
  u16*   hBbf  = hAbf + (size_t)NN * HD;             // 8 MB
  int*   ecnt  = (int*)(hBbf + (size_t)NN * HD);     // 256 KB (+pad)
  u32*   edgep = (u32*)(ecnt + NN + 64);             // NN*CAP*4B = 12.6 MB
  int*   pcnt  = (int*)(edgep + (size_t)NN * CAP);   // NP ints (+pad)
  uint2* tmp   = (uint2*)(pcnt + NP + 64);           // NP*PCAP*8B = 10.5 MB

  hipMemsetAsync(pcnt, 0, NP * sizeof(int), stream);
  passA_k<<<NE / 4096, 1024, 0, stream>>>(src, dst, ew, pcnt, tmp);
  passB_k<<<NP, 256, 0, stream>>>(tmp, pcnt, edgep, ecnt);

  fc_first_k<<<NN / 64, 256, 0, stream>>>(x, ln1_g, ln1_b, w1, b1, ln_g, ln_b,
                                          hAbf);
  conv_k<<<NN / 32, 512, 0, stream>>>(hAbf, hBbf, ecnt, edgep,
                                      conv_w,        conv_b,       ln_g, ln_b);
  conv_k<<<NN / 32, 512, 0, stream>>>(hBbf, hAbf, ecnt, edgep,
                                      conv_w + 4096, conv_b + 64,  ln_g, ln_b);
  conv_k<<<NN / 32, 512, 0, stream>>>(hAbf, hBbf, ecnt, edgep,
                                      conv_w + 8192, conv_b + 128, ln_g, ln_b);
  fc_final_k<<<NN / 64, 256, 0, stream>>>(hBbf, ln2_g, ln2_b, w3, b3, w4, b4, out);
}

// Round 21
// 171.171 us; speedup vs baseline: 1.3428x; 1.0977x over previous
//
#include <hip/hip_runtime.h>

#define NN   65536
#define NE   1048576
#define CAP  48        // per-node edge capacity (Poisson(16): P(deg>=48)~5e-6)
#define NP   512       // partitions (128 nodes each), bin = dst >> 7
#define NODP 128       // nodes per partition
#define PCAP 2560      // partition capacity: mean 2048 + ~11 sd
#define FIN  128
#define HD   64
#define NOUT 32
#define EPSV 1e-5f

typedef unsigned short u16;
typedef unsigned int u32;
typedef __attribute__((ext_vector_type(8))) short short8v;   // 8 bf16
typedef __attribute__((ext_vector_type(4))) float f32x4;

__device__ __forceinline__ u16 f2bf(float f) {
  u32 x = __float_as_uint(f);
  u32 r = x + 0x7FFFu + ((x >> 16) & 1u);   // round-to-nearest-even
  return (u16)(r >> 16);
}
__device__ __forceinline__ float bf2f(u16 u) {
  return __uint_as_float((u32)u << 16);
}

__device__ __forceinline__ void fma4bf(float4& acc, uint2 g, float w) {
  acc.x += __uint_as_float(g.x << 16) * w;
  acc.y += __uint_as_float(g.x & 0xFFFF0000u) * w;
  acc.z += __uint_as_float(g.y << 16) * w;
  acc.w += __uint_as_float(g.y & 0xFFFF0000u) * w;
}

// ---------------- pass A: partition edges into 512 coarse bins (coalesced runs) --------
__global__ __launch_bounds__(1024) void passA_k(
    const int* __restrict__ src, const int* __restrict__ dst,
    const float* __restrict__ ew, int* __restrict__ pcnt,
    uint2* __restrict__ tmp) {
  __shared__ int hist[NP];
  __shared__ int base[NP];
  int t = threadIdx.x;
  if (t < NP) hist[t] = 0;
  __syncthreads();

  int d[4], s[4];
  float w[4];
  size_t e0 = (size_t)blockIdx.x * 4096;
#pragma unroll
  for (int r = 0; r < 4; ++r) {
    int i = e0 + r * 1024 + t;
    d[r] = dst[i]; s[r] = src[i]; w[r] = ew[i];
    atomicAdd(&hist[d[r] >> 7], 1);
  }
  __syncthreads();
  if (t < NP) {
    int c = hist[t];
    base[t] = c ? atomicAdd(&pcnt[t], c) : 0;
    hist[t] = 0;                 // reuse as cursor
  }
  __syncthreads();
#pragma unroll
  for (int r = 0; r < 4; ++r) {
    int bin = d[r] >> 7;
    int pos = base[bin] + atomicAdd(&hist[bin], 1);
    if (pos < PCAP)
      tmp[(size_t)bin * PCAP + pos] =
          make_uint2(((u32)d[r] << 16) | (u32)s[r], __float_as_uint(w[r]));
  }
}

// ---------------- pass B: per-partition CSR build + pad-to-4 zero-weight slots --------
__global__ __launch_bounds__(256) void passB_k(
    const uint2* __restrict__ tmp, const int* __restrict__ pcnt,
    u32* __restrict__ edgep, int* __restrict__ ecnt) {
  __shared__ int cur[NODP];
  int p = blockIdx.x, t = threadIdx.x;
  if (t < NODP) cur[t] = 0;
  __syncthreads();
  int cntp = min(pcnt[p], PCAP);
  const uint2* tp = tmp + (size_t)p * PCAP;
  for (int i = t; i < cntp; i += 256) {
    uint2 e = tp[i];
    int dd = e.x >> 16;
    int pos = atomicAdd(&cur[dd & (NODP - 1)], 1);
    if (pos < CAP)
      edgep[(size_t)dd * CAP + pos] =
          (e.x & 0xFFFFu) | ((u32)f2bf(__uint_as_float(e.y)) << 16);
  }
  __syncthreads();
  if (t < NODP) {
    int node = p * NODP + t;
    int c = min(cur[t], CAP);
    int padded = min((c + 3) & ~3, CAP);
    for (int s = c; s < padded; ++s)
      edgep[(size_t)node * CAP + s] = 0u;   // src 0, bf16 weight 0
    ecnt[node] = padded;
  }
}

// ---------------- fc_first: LN(128) -> MFMA [128x64] -> ELU -> LN(64) ----------------
// 64 nodes/block, 4 waves. Phase1: LN(x) -> bf16 LDS. Phase2: wave = 16 nodes,
// 4 j-tiles x 4 k-steps of mfma_f32_16x16x32_bf16. Phase3: ELU+LN(64)+store.
__global__ __launch_bounds__(256, 4) void fc_first_k(
    const float* __restrict__ x, const float* __restrict__ ln1_g,
    const float* __restrict__ ln1_b, const float* __restrict__ w1,
    const float* __restrict__ b1, const float* __restrict__ ln_g,
    const float* __restrict__ ln_b, u16* __restrict__ hAbf) {
  __shared__ __align__(16) u16 sXn[64 * 136];   // [node][k] bf16, pad 136
  __shared__ __align__(16) u16 sWb[64 * 136];   // [j][k] bf16 (W^T), pad 136
  __shared__ __align__(16) float sG[FIN], sB[FIN];
  int tid = threadIdx.x;
  for (int i = tid; i < FIN * HD; i += 256) {
    int k = i >> 6, j = i & 63;          // w1[k][j]
    sWb[j * 136 + k] = f2bf(w1[i]);
  }
  if (tid < FIN) { sG[tid] = ln1_g[tid]; sB[tid] = ln1_b[tid]; }
  __syncthreads();

  // ---- phase 1: LN(128), 4 lanes/node, x read once ----
  {
    int jq = tid & 3;                  // k-slice jq*32..jq*32+31
    int nl = tid >> 2;                 // local node 0..63
    int node = blockIdx.x * 64 + nl;
    const float4* xp = (const float4*)(x + (size_t)node * FIN + jq * 32);
    float xv[32];
    float s = 0.f, s2 = 0.f;
#pragma unroll
    for (int i = 0; i < 8; ++i) {
      float4 v = xp[i];
      xv[i * 4 + 0] = v.x; xv[i * 4 + 1] = v.y;
      xv[i * 4 + 2] = v.z; xv[i * 4 + 3] = v.w;
      s += v.x + v.y + v.z + v.w;
      s2 += v.x * v.x + v.y * v.y + v.z * v.z + v.w * v.w;
    }
    s += __shfl_xor(s, 1, 64);  s += __shfl_xor(s, 2, 64);
    s2 += __shfl_xor(s2, 1, 64); s2 += __shfl_xor(s2, 2, 64);
    float mean = s * (1.f / FIN);
    float var = s2 * (1.f / FIN) - mean * mean;
    float r = rsqrtf(var + EPSV);
    u32* dp = (u32*)&sXn[nl * 136 + jq * 32];
#pragma unroll
    for (int i = 0; i < 16; ++i) {
      int k = jq * 32 + i * 2;
      float a0 = (xv[i * 2 + 0] - mean) * r * sG[k + 0] + sB[k + 0];
      float a1 = (xv[i * 2 + 1] - mean) * r * sG[k + 1] + sB[k + 1];
      dp[i] = (u32)f2bf(a0) | ((u32)f2bf(a1) << 16);
    }
  }
  __syncthreads();

  // ---- phase 2: MFMA. wave wl -> nodes wl*16..+15; 4 j-tiles ----
  int wl = tid >> 6, lane = tid & 63;
  int q = lane >> 4, fq = lane & 15;
  f32x4 d0 = {0.f, 0.f, 0.f, 0.f}, d1 = d0, d2 = d0, d3 = d0;
#pragma unroll
  for (int st = 0; st < 4; ++st) {
    short8v av = *(const short8v*)&sXn[(wl * 16 + fq) * 136 + st * 32 + q * 8];
    short8v b0 = *(const short8v*)&sWb[(0 * 16 + fq) * 136 + st * 32 + q * 8];
    short8v b1v = *(const short8v*)&sWb[(1 * 16 + fq) * 136 + st * 32 + q * 8];
    short8v b2 = *(const short8v*)&sWb[(2 * 16 + fq) * 136 + st * 32 + q * 8];
    short8v b3v = *(const short8v*)&sWb[(3 * 16 + fq) * 136 + st * 32 + q * 8];
    d0 = __builtin_amdgcn_mfma_f32_16x16x32_bf16(av, b0, d0, 0, 0, 0);
    d1 = __builtin_amdgcn_mfma_f32_16x16x32_bf16(av, b1v, d1, 0, 0, 0);
    d2 = __builtin_amdgcn_mfma_f32_16x16x32_bf16(av, b2, d2, 0, 0, 0);
    d3 = __builtin_amdgcn_mfma_f32_16x16x32_bf16(av, b3v, d3, 0, 0, 0);
  }

  // ---- phase 3: bias+ELU (in regs), LN(64) via 16-lane butterflies, store ----
  float b1r[4], lgr[4], lbr[4];
#pragma unroll
  for (int t = 0; t < 4; ++t) {
    b1r[t] = b1[t * 16 + fq];
    lgr[t] = ln_g[t * 16 + fq];
    lbr[t] = ln_b[t * 16 + fq];
  }
  float y0[4], y1[4], y2[4], y3[4];    // [reg] for j-tiles 0..3
  float ps[4], ps2[4];
#pragma unroll
  for (int reg = 0; reg < 4; ++reg) {
    float v0 = d0[reg] + b1r[0]; v0 = (v0 > 0.f) ? v0 : expm1f(v0);
    float v1 = d1[reg] + b1r[1]; v1 = (v1 > 0.f) ? v1 : expm1f(v1);
    float v2 = d2[reg] + b1r[2]; v2 = (v2 > 0.f) ? v2 : expm1f(v2);
    float v3 = d3[reg] + b1r[3]; v3 = (v3 > 0.f) ? v3 : expm1f(v3);
    y0[reg] = v0; y1[reg] = v1; y2[reg] = v2; y3[reg] = v3;
    ps[reg] = v0 + v1 + v2 + v3;
    ps2[reg] = v0 * v0 + v1 * v1 + v2 * v2 + v3 * v3;
  }
#pragma unroll
  for (int o = 1; o <= 8; o <<= 1) {
#pragma unroll
    for (int reg = 0; reg < 4; ++reg) {
      ps[reg] += __shfl_xor(ps[reg], o, 64);
      ps2[reg] += __shfl_xor(ps2[reg], o, 64);
    }
  }
#pragma unroll
  for (int reg = 0; reg < 4; ++reg) {
    int n = blockIdx.x * 64 + wl * 16 + q * 4 + reg;   // D: row=(lane>>4)*4+reg
    float m2 = ps[reg] * (1.f / HD);
    float vv = ps2[reg] * (1.f / HD) - m2 * m2;
    float r2 = rsqrtf(vv + EPSV);
    hAbf[(size_t)n * HD + 0 * 16 + fq] = f2bf((y0[reg] - m2) * r2 * lgr[0] + lbr[0]);
    hAbf[(size_t)n * HD + 1 * 16 + fq] = f2bf((y1[reg] - m2) * r2 * lgr[1] + lbr[1]);
    hAbf[(size_t)n * HD + 2 * 16 + fq] = f2bf((y2[reg] - m2) * r2 * lgr[2] + lbr[2]);
    hAbf[(size_t)n * HD + 3 * 16 + fq] = f2bf((y3[reg] - m2) * r2 * lgr[3] + lbr[3]);
  }
}

// ---------------- conv: gather -> MFMA GEMM (bf16) -> LN -> bf16 residual ------------
__global__ __launch_bounds__(512, 8) void conv_k(
    const u16* __restrict__ hbf_in, u16* __restrict__ hbf_out,
    const int* __restrict__ ecnt, const u32* __restrict__ edgep,
    const float* __restrict__ W, const float* __restrict__ B,
    const float* __restrict__ ln_g, const float* __restrict__ ln_b) {
  __shared__ __align__(16) u16 sWt[HD * 72];      // [j][k] bf16, row pad 72
  __shared__ __align__(16) u16 sAgg[32 * 72];     // [node][k] bf16, row pad 72
  __shared__ __align__(16) float sOut[32 * 68];   // [node][j] f32, row pad 68
  int tid = threadIdx.x;
  for (int i = tid; i < HD * HD; i += 512) {
    int k = i >> 6, j = i & 63;          // W[k][j]
    sWt[j * 72 + k] = f2bf(W[i]);
  }

  int wl = tid >> 6, lane = tid & 63;
  int q = lane >> 4;
  int fq = lane & 15;
  int nbase = blockIdx.x * 32;

  int cntR[4];
  u32 HR[4];
#pragma unroll
  for (int rp = 0; rp < 4; ++rp) {
    int n = nbase + wl * 4 + rp;
    cntR[rp] = ecnt[n];
    HR[rp] = edgep[(size_t)n * CAP + min(lane, 31)];
  }

#pragma unroll
  for (int rp = 0; rp < 4; ++rp) {
    int n = nbase + wl * 4 + rp;
    int cnt = cntR[rp];
    u32 H = HR[rp];

    float4 acc = make_float4(0.f, 0.f, 0.f, 0.f);
    if (cnt > 0) {
      int ng = cnt >> 2;
      int ngs = min(ng, 8);
      int g = 0;
      for (; g + 4 <= ngs; g += 4) {
        u32 h0 = __shfl(H, (g + 0) * 4 + q, 64);
        u32 h1 = __shfl(H, (g + 1) * 4 + q, 64);
        u32 h2 = __shfl(H, (g + 2) * 4 + q, 64);
        u32 h3 = __shfl(H, (g + 3) * 4 + q, 64);
        uint2 g0 = ((const uint2*)(hbf_in + ((size_t)(h0 & 0xFFFFu) << 6)))[fq];
        uint2 g1 = ((const uint2*)(hbf_in + ((size_t)(h1 & 0xFFFFu) << 6)))[fq];
        uint2 g2 = ((const uint2*)(hbf_in + ((size_t)(h2 & 0xFFFFu) << 6)))[fq];
        uint2 g3 = ((const uint2*)(hbf_in + ((size_t)(h3 & 0xFFFFu) << 6)))[fq];
        fma4bf(acc, g0, __uint_as_float(h0 & 0xFFFF0000u));
        fma4bf(acc, g1, __uint_as_float(h1 & 0xFFFF0000u));
        fma4bf(acc, g2, __uint_as_float(h2 & 0xFFFF0000u));
        fma4bf(acc, g3, __uint_as_float(h3 & 0xFFFF0000u));
      }
      for (; g < ngs; ++g) {
        u32 hj = __shfl(H, g * 4 + q, 64);
        uint2 gg = ((const uint2*)(hbf_in + ((size_t)(hj & 0xFFFFu) << 6)))[fq];
        fma4bf(acc, gg, __uint_as_float(hj & 0xFFFF0000u));
      }
      for (; g < ng; ++g) {
        u32 hj = edgep[(size_t)n * CAP + g * 4 + q];
        uint2 gg = ((const uint2*)(hbf_in + ((size_t)(hj & 0xFFFFu) << 6)))[fq];
        fma4bf(acc, gg, __uint_as_float(hj & 0xFFFF0000u));
      }
    }
#pragma unroll
    for (int off = 16; off < 64; off <<= 1) {
      acc.x += __shfl_xor(acc.x, off, 64);
      acc.y += __shfl_xor(acc.y, off, 64);
      acc.z += __shfl_xor(acc.z, off, 64);
      acc.w += __shfl_xor(acc.w, off, 64);
    }
    if (lane < 16) {
      u32 p0 = (u32)f2bf(acc.x) | ((u32)f2bf(acc.y) << 16);
      u32 p1 = (u32)f2bf(acc.z) | ((u32)f2bf(acc.w) << 16);
      u32* dp = (u32*)&sAgg[(wl * 4 + rp) * 72 + fq * 4];
      dp[0] = p0; dp[1] = p1;
    }
  }
  __syncthreads();

  {
    int g = wl >> 2, t = wl & 3;
    f32x4 d = {0.f, 0.f, 0.f, 0.f};
#pragma unroll
    for (int s = 0; s < 2; ++s) {
      short8v av = *(const short8v*)&sAgg[(g * 16 + fq) * 72 + s * 32 + q * 8];
      short8v bv = *(const short8v*)&sWt[(t * 16 + fq) * 72 + s * 32 + q * 8];
      d = __builtin_amdgcn_mfma_f32_16x16x32_bf16(av, bv, d, 0, 0, 0);
    }
#pragma unroll
    for (int reg = 0; reg < 4; ++reg) {
      int row = q * 4 + reg;
      sOut[(g * 16 + row) * 68 + t * 16 + fq] = d[reg];
    }
  }
  __syncthreads();

  float bias = B[lane], lg = ln_g[lane], lb = ln_b[lane];
#pragma unroll
  for (int rp = 0; rp < 4; ++rp) {
    int nl = wl * 4 + rp;
    int n = nbase + nl;
    float y = sOut[nl * 68 + lane] + bias;
    float a = y, b2 = y * y;
#pragma unroll
    for (int o = 32; o > 0; o >>= 1) {
      a += __shfl_xor(a, o, 64);
      b2 += __shfl_xor(b2, o, 64);
    }
    float m = a * (1.f / HD);
    float v = b2 * (1.f / HD) - m * m;
    float ln = (y - m) * rsqrtf(v + EPSV) * lg + lb;
    float hv = bf2f(hbf_in[(size_t)n * HD + lane]) + ln;
    hbf_out[(size_t)n * HD + lane] = f2bf(hv);
  }
}

// ---------------- fc_final: LN(64) -> [64x64]+b3 -> ELU -> [64x32]+b4, 4 lanes/node --
__global__ __launch_bounds__(256, 4) void fc_final_k(
    const u16* __restrict__ hbf, const float* __restrict__ ln2_g,
    const float* __restrict__ ln2_b, const float* __restrict__ w3,
    const float* __restrict__ b3, const float* __restrict__ w4,
    const float* __restrict__ b4, float* __restrict__ out) {
  __shared__ __align__(16) float sW3[HD * HD];     // [k][j]
  __shared__ __align__(16) float sW4[HD * NOUT];   // [k][j]
  __shared__ __align__(16) float sG[HD], sB[HD], sB3[HD], sB4[NOUT];
  int tid = threadIdx.x;
  {
    const float4* a = (const float4*)w3;
    float4* d4 = (float4*)sW3;
    for (int i = tid; i < HD * HD / 4; i += 256) d4[i] = a[i];
    const float4* c = (const float4*)w4;
    float4* e4 = (float4*)sW4;
    for (int i = tid; i < HD * NOUT / 4; i += 256) e4[i] = c[i];
    if (tid < HD) { sG[tid] = ln2_g[tid]; sB[tid] = ln2_b[tid]; sB3[tid] = b3[tid]; }
    if (tid < NOUT) sB4[tid] = b4[tid];
  }
  __syncthreads();

  int jq = tid & 3;
  int node = blockIdx.x * 64 + (tid >> 2);
  const u32* hr = (const u32*)(hbf + (size_t)node * HD);

  float s = 0.f, s2 = 0.f;
  for (int i = 0; i < 8; ++i) {
    uint4 v = ((const uint4*)hr)[i];
    float f0 = __uint_as_float(v.x << 16), f1 = __uint_as_float(v.x & 0xFFFF0000u);
    float f2 = __uint_as_float(v.y << 16), f3 = __uint_as_float(v.y & 0xFFFF0000u);
    float f4 = __uint_as_float(v.z << 16), f5 = __uint_as_float(v.z & 0xFFFF0000u);
    float f6 = __uint_as_float(v.w << 16), f7 = __uint_as_float(v.w & 0xFFFF0000u);
    s += f0 + f1 + f2 + f3 + f4 + f5 + f6 + f7;
    s2 += f0 * f0 + f1 * f1 + f2 * f2 + f3 * f3
        + f4 * f4 + f5 * f5 + f6 * f6 + f7 * f7;
  }
  float mean = s * (1.f / HD);
  float var = s2 * (1.f / HD) - mean * mean;
  float r = rsqrtf(var + EPSV);

  float acc[16];
#pragma unroll
  for (int jb = 0; jb < 4; ++jb) {
    float4 b = ((const float4*)sB3)[jq * 4 + jb];
    acc[jb * 4 + 0] = b.x; acc[jb * 4 + 1] = b.y;
    acc[jb * 4 + 2] = b.z; acc[jb * 4 + 3] = b.w;
  }
  const float4* sW34 = (const float4*)sW3;
  for (int k4 = 0; k4 < HD / 4; ++k4) {
    uint2 rw = ((const uint2*)hr)[k4];
    float xk0 = __uint_as_float(rw.x << 16);
    float xk1 = __uint_as_float(rw.x & 0xFFFF0000u);
    float xk2 = __uint_as_float(rw.y << 16);
    float xk3 = __uint_as_float(rw.y & 0xFFFF0000u);
    float4 g4 = ((const float4*)sG)[k4];
    float4 bb4 = ((const float4*)sB)[k4];
    float xn0 = (xk0 - mean) * r * g4.x + bb4.x;
    float xn1 = (xk1 - mean) * r * g4.y + bb4.y;
    float xn2 = (xk2 - mean) * r * g4.z + bb4.z;
    float xn3 = (xk3 - mean) * r * g4.w + bb4.w;
#pragma unroll
    for (int jb = 0; jb < 4; ++jb) {
      float4 w0 = sW34[(k4 * 4 + 0) * 16 + jq * 4 + jb];
      float4 w1v = sW34[(k4 * 4 + 1) * 16 + jq * 4 + jb];
      float4 w2 = sW34[(k4 * 4 + 2) * 16 + jq * 4 + jb];
      float4 w3v = sW34[(k4 * 4 + 3) * 16 + jq * 4 + jb];
      acc[jb * 4 + 0] += xn0 * w0.x + xn1 * w1v.x + xn2 * w2.x + xn3 * w3v.x;
      acc[jb * 4 + 1] += xn0 * w0.y + xn1 * w1v.y + xn2 * w2.y + xn3 * w3v.y;
      acc[jb * 4 + 2] += xn0 * w0.z + xn1 * w1v.z + xn2 * w2.z + xn3 * w3v.z;
      acc[jb * 4 + 3] += xn0 * w0.w + xn1 * w1v.w + xn2 * w2.w + xn3 * w3v.w;
    }
  }

#pragma unroll
  for (int j = 0; j < 16; ++j) {
    float y = acc[j];
    acc[j] = (y > 0.f) ? y : expm1f(y);
  }

  const float4* sW44 = (const float4*)sW4;
#pragma unroll
  for (int c = 0; c < 2; ++c) {
    float p[16];
#pragma unroll
    for (int i = 0; i < 16; ++i) p[i] = 0.f;
#pragma unroll
    for (int kk = 0; kk < 16; ++kk) {
      float zk = acc[kk];
      int krow = jq * 16 + kk;
#pragma unroll
      for (int qd = 0; qd < 4; ++qd) {
        float4 w = sW44[krow * 8 + c * 4 + qd];
        p[qd * 4 + 0] += zk * w.x;
        p[qd * 4 + 1] += zk * w.y;
        p[qd * 4 + 2] += zk * w.z;
        p[qd * 4 + 3] += zk * w.w;
      }
    }
#pragma unroll
    for (int i = 0; i < 16; ++i) {
      p[i] += __shfl_xor(p[i], 1, 64);
      p[i] += __shfl_xor(p[i], 2, 64);
    }
    if (jq == c) {
      float4* op = (float4*)(out + (size_t)node * NOUT + c * 16);
#pragma unroll
      for (int qd = 0; qd < 4; ++qd) {
        float4 b = ((const float4*)sB4)[c * 4 + qd];
        float4 o;
        o.x = p[qd * 4 + 0] + b.x; o.y = p[qd * 4 + 1] + b.y;
        o.z = p[qd * 4 + 2] + b.z; o.w = p[qd * 4 + 3] + b.w;
        op[qd] = o;
      }
    }
  }
}

extern "C" void kernel_launch(void* const* d_in, const int* in_sizes, int n_in,
                              void* d_out, int out_size, void* d_ws, size_t ws_size,
                              hipStream_t stream) {
  const float* x      = (const float*)d_in[0];
  const float* ew     = (const float*)d_in[1];
  const int*   src    = (const int*)d_in[2];
  const int*   dst    = (const int*)d_in[3];
  const float* ln1_g  = (const float*)d_in[4];
  const float* ln1_b  = (const float*)d_in[5];
  const float* w1     = (const float*)d_in[6];
  const float* b1     = (const float*)d_in[7];
  const float* ln_g   = (const float*)d_in[8];
  const float* ln_b   = (const float*)d_in[9];
  const float* conv_w = (const float*)d_in[10];
  const float* conv_b = (const float*)d_in[11];
  const float* ln2_g  = (const float*)d_in[12];
  const float* ln2_b  = (const float*)d_in[13];
  const float* w3     = (const float*)d_in[14];
  const float* b3     = (const float*)d_in[15];
  const float* w4     = (const float*)d_in[16];
  const float* b4     = (const float*)d_in[17];
  float* out = (float*)d_out;

  char* ws = (char*)d_ws;
  u16*   hAbf  = (u16*)ws;                           // 8 MB
  u16*   hBbf  = hAbf + (size_t)NN * HD;             // 8 MB
  int*   ecnt  = (int*)(hBbf + (size_t)NN * HD);     // 256 KB (+pad)
  u32*   edgep = (u32*)(ecnt + NN + 64);             // NN*CAP*4B = 12.6 MB
  int*   pcnt  = (int*)(edgep + (size_t)NN * CAP);   // NP ints (+pad)
  uint2* tmp   = (uint2*)(pcnt + NP + 64);           // NP*PCAP*8B = 10.5 MB

  hipMemsetAsync(pcnt, 0, NP * sizeof(int), stream);
  passA_k<<<NE / 4096, 1024, 0, stream>>>(src, dst, ew, pcnt, tmp);
  passB_k<<<NP, 256, 0, stream>>>(tmp, pcnt, edgep, ecnt);

  fc_first_k<<<NN / 64, 256, 0, stream>>>(x, ln1_g, ln1_b, w1, b1, ln_g, ln_b,
                                          hAbf);
  conv_k<<<NN / 32, 512, 0, stream>>>(hAbf, hBbf, ecnt, edgep,
                                      conv_w,        conv_b,       ln_g, ln_b);
  conv_k<<<NN / 32, 512, 0, stream>>>(hBbf, hAbf, ecnt, edgep,
                                      conv_w + 4096, conv_b + 64,  ln_g, ln_b);
  conv_k<<<NN / 32, 512, 0, stream>>>(hAbf, hBbf, ecnt, edgep,
                                      conv_w + 8192, conv_b + 128, ln_g, ln_b);
  fc_final_k<<<NN / 64, 256, 0, stream>>>(hBbf, ln2_g, ln2_b, w3, b3, w4, b4, out);
}

// Round 22
// 170.636 us; speedup vs baseline: 1.3470x; 1.0031x over previous
//
#include <hip/hip_runtime.h>

#define NN   65536
#define NE   1048576
#define CAP  48        // per-node edge capacity (Poisson(16): P(deg>=48)~5e-6)
#define NP   512       // partitions (128 nodes each), bin = dst >> 7
#define NODP 128       // nodes per partition
#define PCAP 2560      // partition capacity: mean 2048 + ~11 sd
#define FIN  128
#define HD   64
#define NOUT 32
#define EPSV 1e-5f

typedef unsigned short u16;
typedef unsigned int u32;
typedef __attribute__((ext_vector_type(8))) short short8v;   // 8 bf16
typedef __attribute__((ext_vector_type(4))) float f32x4;

__device__ __forceinline__ u16 f2bf(float f) {
  u32 x = __float_as_uint(f);
  u32 r = x + 0x7FFFu + ((x >> 16) & 1u);   // round-to-nearest-even
  return (u16)(r >> 16);
}
__device__ __forceinline__ float bf2f(u16 u) {
  return __uint_as_float((u32)u << 16);
}

__device__ __forceinline__ void fma4bf(float4& acc, uint2 g, float w) {
  acc.x += __uint_as_float(g.x << 16) * w;
  acc.y += __uint_as_float(g.x & 0xFFFF0000u) * w;
  acc.z += __uint_as_float(g.y << 16) * w;
  acc.w += __uint_as_float(g.y & 0xFFFF0000u) * w;
}

// ---------------- zero pcnt (replaces hipMemsetAsync: runtime fill cost ~41us) -------
__global__ __launch_bounds__(512) void zero_k(int* __restrict__ pcnt) {
  pcnt[threadIdx.x] = 0;
}

// ---------------- pass A: partition edges into 512 coarse bins (coalesced runs) --------
__global__ __launch_bounds__(1024) void passA_k(
    const int* __restrict__ src, const int* __restrict__ dst,
    const float* __restrict__ ew, int* __restrict__ pcnt,
    uint2* __restrict__ tmp) {
  __shared__ int hist[NP];
  __shared__ int base[NP];
  int t = threadIdx.x;
  if (t < NP) hist[t] = 0;
  __syncthreads();

  int d[4], s[4];
  float w[4];
  size_t e0 = (size_t)blockIdx.x * 4096;
#pragma unroll
  for (int r = 0; r < 4; ++r) {
    int i = e0 + r * 1024 + t;
    d[r] = dst[i]; s[r] = src[i]; w[r] = ew[i];
    atomicAdd(&hist[d[r] >> 7], 1);
  }
  __syncthreads();
  if (t < NP) {
    int c = hist[t];
    base[t] = c ? atomicAdd(&pcnt[t], c) : 0;
    hist[t] = 0;                 // reuse as cursor
  }
  __syncthreads();
#pragma unroll
  for (int r = 0; r < 4; ++r) {
    int bin = d[r] >> 7;
    int pos = base[bin] + atomicAdd(&hist[bin], 1);
    if (pos < PCAP)
      tmp[(size_t)bin * PCAP + pos] =
          make_uint2(((u32)d[r] << 16) | (u32)s[r], __float_as_uint(w[r]));
  }
}

// ---------------- pass B: per-partition CSR build + pad-to-4 zero-weight slots --------
__global__ __launch_bounds__(256) void passB_k(
    const uint2* __restrict__ tmp, const int* __restrict__ pcnt,
    u32* __restrict__ edgep, int* __restrict__ ecnt) {
  __shared__ int cur[NODP];
  int p = blockIdx.x, t = threadIdx.x;
  if (t < NODP) cur[t] = 0;
  __syncthreads();
  int cntp = min(pcnt[p], PCAP);
  const uint2* tp = tmp + (size_t)p * PCAP;
  for (int i = t; i < cntp; i += 256) {
    uint2 e = tp[i];
    int dd = e.x >> 16;
    int pos = atomicAdd(&cur[dd & (NODP - 1)], 1);
    if (pos < CAP)
      edgep[(size_t)dd * CAP + pos] =
          (e.x & 0xFFFFu) | ((u32)f2bf(__uint_as_float(e.y)) << 16);
  }
  __syncthreads();
  if (t < NODP) {
    int node = p * NODP + t;
    int c = min(cur[t], CAP);
    int padded = min((c + 3) & ~3, CAP);
    for (int s = c; s < padded; ++s)
      edgep[(size_t)node * CAP + s] = 0u;   // src 0, bf16 weight 0
    ecnt[node] = padded;
  }
}

// ---------------- fc_first: LN(128) -> MFMA [128x64] -> ELU -> LN(64) ----------------
__global__ __launch_bounds__(256, 4) void fc_first_k(
    const float* __restrict__ x, const float* __restrict__ ln1_g,
    const float* __restrict__ ln1_b, const float* __restrict__ w1,
    const float* __restrict__ b1, const float* __restrict__ ln_g,
    const float* __restrict__ ln_b, u16* __restrict__ hAbf) {
  __shared__ __align__(16) u16 sXn[64 * 136];   // [node][k] bf16, pad 136
  __shared__ __align__(16) u16 sWb[64 * 136];   // [j][k] bf16 (W^T), pad 136
  __shared__ __align__(16) float sG[FIN], sB[FIN];
  int tid = threadIdx.x;
  for (int i = tid; i < FIN * HD; i += 256) {
    int k = i >> 6, j = i & 63;          // w1[k][j]
    sWb[j * 136 + k] = f2bf(w1[i]);
  }
  if (tid < FIN) { sG[tid] = ln1_g[tid]; sB[tid] = ln1_b[tid]; }
  __syncthreads();

  // ---- phase 1: LN(128), 4 lanes/node, x read once ----
  {
    int jq = tid & 3;                  // k-slice jq*32..jq*32+31
    int nl = tid >> 2;                 // local node 0..63
    int node = blockIdx.x * 64 + nl;
    const float4* xp = (const float4*)(x + (size_t)node * FIN + jq * 32);
    float xv[32];
    float s = 0.f, s2 = 0.f;
#pragma unroll
    for (int i = 0; i < 8; ++i) {
      float4 v = xp[i];
      xv[i * 4 + 0] = v.x; xv[i * 4 + 1] = v.y;
      xv[i * 4 + 2] = v.z; xv[i * 4 + 3] = v.w;
      s += v.x + v.y + v.z + v.w;
      s2 += v.x * v.x + v.y * v.y + v.z * v.z + v.w * v.w;
    }
    s += __shfl_xor(s, 1, 64);  s += __shfl_xor(s, 2, 64);
    s2 += __shfl_xor(s2, 1, 64); s2 += __shfl_xor(s2, 2, 64);
    float mean = s * (1.f / FIN);
    float var = s2 * (1.f / FIN) - mean * mean;
    float r = rsqrtf(var + EPSV);
    u32* dp = (u32*)&sXn[nl * 136 + jq * 32];
#pragma unroll
    for (int i = 0; i < 16; ++i) {
      int k = jq * 32 + i * 2;
      float a0 = (xv[i * 2 + 0] - mean) * r * sG[k + 0] + sB[k + 0];
      float a1 = (xv[i * 2 + 1] - mean) * r * sG[k + 1] + sB[k + 1];
      dp[i] = (u32)f2bf(a0) | ((u32)f2bf(a1) << 16);
    }
  }
  __syncthreads();

  // ---- phase 2: MFMA. wave wl -> nodes wl*16..+15; 4 j-tiles ----
  int wl = tid >> 6, lane = tid & 63;
  int q = lane >> 4, fq = lane & 15;
  f32x4 d0 = {0.f, 0.f, 0.f, 0.f}, d1 = d0, d2 = d0, d3 = d0;
#pragma unroll
  for (int st = 0; st < 4; ++st) {
    short8v av = *(const short8v*)&sXn[(wl * 16 + fq) * 136 + st * 32 + q * 8];
    short8v b0 = *(const short8v*)&sWb[(0 * 16 + fq) * 136 + st * 32 + q * 8];
    short8v b1v = *(const short8v*)&sWb[(1 * 16 + fq) * 136 + st * 32 + q * 8];
    short8v b2 = *(const short8v*)&sWb[(2 * 16 + fq) * 136 + st * 32 + q * 8];
    short8v b3v = *(const short8v*)&sWb[(3 * 16 + fq) * 136 + st * 32 + q * 8];
    d0 = __builtin_amdgcn_mfma_f32_16x16x32_bf16(av, b0, d0, 0, 0, 0);
    d1 = __builtin_amdgcn_mfma_f32_16x16x32_bf16(av, b1v, d1, 0, 0, 0);
    d2 = __builtin_amdgcn_mfma_f32_16x16x32_bf16(av, b2, d2, 0, 0, 0);
    d3 = __builtin_amdgcn_mfma_f32_16x16x32_bf16(av, b3v, d3, 0, 0, 0);
  }

  // ---- phase 3: bias+ELU (in regs), LN(64) via 16-lane butterflies, store ----
  float b1r[4], lgr[4], lbr[4];
#pragma unroll
  for (int t = 0; t < 4; ++t) {
    b1r[t] = b1[t * 16 + fq];
    lgr[t] = ln_g[t * 16 + fq];
    lbr[t] = ln_b[t * 16 + fq];
  }
  float y0[4], y1[4], y2[4], y3[4];
  float ps[4], ps2[4];
#pragma unroll
  for (int reg = 0; reg < 4; ++reg) {
    float v0 = d0[reg] + b1r[0]; v0 = (v0 > 0.f) ? v0 : expm1f(v0);
    float v1 = d1[reg] + b1r[1]; v1 = (v1 > 0.f) ? v1 : expm1f(v1);
    float v2 = d2[reg] + b1r[2]; v2 = (v2 > 0.f) ? v2 : expm1f(v2);
    float v3 = d3[reg] + b1r[3]; v3 = (v3 > 0.f) ? v3 : expm1f(v3);
    y0[reg] = v0; y1[reg] = v1; y2[reg] = v2; y3[reg] = v3;
    ps[reg] = v0 + v1 + v2 + v3;
    ps2[reg] = v0 * v0 + v1 * v1 + v2 * v2 + v3 * v3;
  }
#pragma unroll
  for (int o = 1; o <= 8; o <<= 1) {
#pragma unroll
    for (int reg = 0; reg < 4; ++reg) {
      ps[reg] += __shfl_xor(ps[reg], o, 64);
      ps2[reg] += __shfl_xor(ps2[reg], o, 64);
    }
  }
#pragma unroll
  for (int reg = 0; reg < 4; ++reg) {
    int n = blockIdx.x * 64 + wl * 16 + q * 4 + reg;   // D: row=(lane>>4)*4+reg
    float m2 = ps[reg] * (1.f / HD);
    float vv = ps2[reg] * (1.f / HD) - m2 * m2;
    float r2 = rsqrtf(vv + EPSV);
    hAbf[(size_t)n * HD + 0 * 16 + fq] = f2bf((y0[reg] - m2) * r2 * lgr[0] + lbr[0]);
    hAbf[(size_t)n * HD + 1 * 16 + fq] = f2bf((y1[reg] - m2) * r2 * lgr[1] + lbr[1]);
    hAbf[(size_t)n * HD + 2 * 16 + fq] = f2bf((y2[reg] - m2) * r2 * lgr[2] + lbr[2]);
    hAbf[(size_t)n * HD + 3 * 16 + fq] = f2bf((y3[reg] - m2) * r2 * lgr[3] + lbr[3]);
  }
}

// ---------------- conv: gather -> MFMA GEMM (bf16) -> LN -> bf16 residual ------------
__global__ __launch_bounds__(512, 8) void conv_k(
    const u16* __restrict__ hbf_in, u16* __restrict__ hbf_out,
    const int* __restrict__ ecnt, const u32* __restrict__ edgep,
    const float* __restrict__ W, const float* __restrict__ B,
    const float* __restrict__ ln_g, const float* __restrict__ ln_b) {
  __shared__ __align__(16) u16 sWt[HD * 72];      // [j][k] bf16, row pad 72
  __shared__ __align__(16) u16 sAgg[32 * 72];     // [node][k] bf16, row pad 72
  __shared__ __align__(16) float sOut[32 * 68];   // [node][j] f32, row pad 68
  int tid = threadIdx.x;
  for (int i = tid; i < HD * HD; i += 512) {
    int k = i >> 6, j = i & 63;          // W[k][j]
    sWt[j * 72 + k] = f2bf(W[i]);
  }

  int wl = tid >> 6, lane = tid & 63;
  int q = lane >> 4;
  int fq = lane & 15;
  int nbase = blockIdx.x * 32;

  int cntR[4];
  u32 HR[4];
#pragma unroll
  for (int rp = 0; rp < 4; ++rp) {
    int n = nbase + wl * 4 + rp;
    cntR[rp] = ecnt[n];
    HR[rp] = edgep[(size_t)n * CAP + min(lane, 31)];
  }

#pragma unroll
  for (int rp = 0; rp < 4; ++rp) {
    int n = nbase + wl * 4 + rp;
    int cnt = cntR[rp];
    u32 H = HR[rp];

    float4 acc = make_float4(0.f, 0.f, 0.f, 0.f);
    if (cnt > 0) {
      int ng = cnt >> 2;
      int ngs = min(ng, 8);
      int g = 0;
      for (; g + 4 <= ngs; g += 4) {
        u32 h0 = __shfl(H, (g + 0) * 4 + q, 64);
        u32 h1 = __shfl(H, (g + 1) * 4 + q, 64);
        u32 h2 = __shfl(H, (g + 2) * 4 + q, 64);
        u32 h3 = __shfl(H, (g + 3) * 4 + q, 64);
        uint2 g0 = ((const uint2*)(hbf_in + ((size_t)(h0 & 0xFFFFu) << 6)))[fq];
        uint2 g1 = ((const uint2*)(hbf_in + ((size_t)(h1 & 0xFFFFu) << 6)))[fq];
        uint2 g2 = ((const uint2*)(hbf_in + ((size_t)(h2 & 0xFFFFu) << 6)))[fq];
        uint2 g3 = ((const uint2*)(hbf_in + ((size_t)(h3 & 0xFFFFu) << 6)))[fq];
        fma4bf(acc, g0, __uint_as_float(h0 & 0xFFFF0000u));
        fma4bf(acc, g1, __uint_as_float(h1 & 0xFFFF0000u));
        fma4bf(acc, g2, __uint_as_float(h2 & 0xFFFF0000u));
        fma4bf(acc, g3, __uint_as_float(h3 & 0xFFFF0000u));
      }
      for (; g < ngs; ++g) {
        u32 hj = __shfl(H, g * 4 + q, 64);
        uint2 gg = ((const uint2*)(hbf_in + ((size_t)(hj & 0xFFFFu) << 6)))[fq];
        fma4bf(acc, gg, __uint_as_float(hj & 0xFFFF0000u));
      }
      for (; g < ng; ++g) {
        u32 hj = edgep[(size_t)n * CAP + g * 4 + q];
        uint2 gg = ((const uint2*)(hbf_in + ((size_t)(hj & 0xFFFFu) << 6)))[fq];
        fma4bf(acc, gg, __uint_as_float(hj & 0xFFFF0000u));
      }
    }
#pragma unroll
    for (int off = 16; off < 64; off <<= 1) {
      acc.x += __shfl_xor(acc.x, off, 64);
      acc.y += __shfl_xor(acc.y, off, 64);
      acc.z += __shfl_xor(acc.z, off, 64);
      acc.w += __shfl_xor(acc.w, off, 64);
    }
    if (lane < 16) {
      u32 p0 = (u32)f2bf(acc.x) | ((u32)f2bf(acc.y) << 16);
      u32 p1 = (u32)f2bf(acc.z) | ((u32)f2bf(acc.w) << 16);
      u32* dp = (u32*)&sAgg[(wl * 4 + rp) * 72 + fq * 4];
      dp[0] = p0; dp[1] = p1;
    }
  }
  __syncthreads();

  {
    int g = wl >> 2, t = wl & 3;
    f32x4 d = {0.f, 0.f, 0.f, 0.f};
#pragma unroll
    for (int s = 0; s < 2; ++s) {
      short8v av = *(const short8v*)&sAgg[(g * 16 + fq) * 72 + s * 32 + q * 8];
      short8v bv = *(const short8v*)&sWt[(t * 16 + fq) * 72 + s * 32 + q * 8];
      d = __builtin_amdgcn_mfma_f32_16x16x32_bf16(av, bv, d, 0, 0, 0);
    }
#pragma unroll
    for (int reg = 0; reg < 4; ++reg) {
      int row = q * 4 + reg;
      sOut[(g * 16 + row) * 68 + t * 16 + fq] = d[reg];
    }
  }
  __syncthreads();

  float bias = B[lane], lg = ln_g[lane], lb = ln_b[lane];
#pragma unroll
  for (int rp = 0; rp < 4; ++rp) {
    int nl = wl * 4 + rp;
    int n = nbase + nl;
    float y = sOut[nl * 68 + lane] + bias;
    float a = y, b2 = y * y;
#pragma unroll
    for (int o = 32; o > 0; o >>= 1) {
      a += __shfl_xor(a, o, 64);
      b2 += __shfl_xor(b2, o, 64);
    }
    float m = a * (1.f / HD);
    float v = b2 * (1.f / HD) - m * m;
    float ln = (y - m) * rsqrtf(v + EPSV) * lg + lb;
    float hv = bf2f(hbf_in[(size_t)n * HD + lane]) + ln;
    hbf_out[(size_t)n * HD + lane] = f2bf(hv);
  }
}

// ---------------- fc_final: LN(64) -> [64x64]+b3 -> ELU -> [64x32]+b4, 4 lanes/node --
__global__ __launch_bounds__(256, 4) void fc_final_k(
    const u16* __restrict__ hbf, const float* __restrict__ ln2_g,
    const float* __restrict__ ln2_b, const float* __restrict__ w3,
    const float* __restrict__ b3, const float* __restrict__ w4,
    const float* __restrict__ b4, float* __restrict__ out) {
  __shared__ __align__(16) float sW3[HD * HD];     // [k][j]
  __shared__ __align__(16) float sW4[HD * NOUT];   // [k][j]
  __shared__ __align__(16) float sG[HD], sB[HD], sB3[HD], sB4[NOUT];
  int tid = threadIdx.x;
  {
    const float4* a = (const float4*)w3;
    float4* d4 = (float4*)sW3;
    for (int i = tid; i < HD * HD / 4; i += 256) d4[i] = a[i];
    const float4* c = (const float4*)w4;
    float4* e4 = (float4*)sW4;
    for (int i = tid; i < HD * NOUT / 4; i += 256) e4[i] = c[i];
    if (tid < HD) { sG[tid] = ln2_g[tid]; sB[tid] = ln2_b[tid]; sB3[tid] = b3[tid]; }
    if (tid < NOUT) sB4[tid] = b4[tid];
  }
  __syncthreads();

  int jq = tid & 3;
  int node = blockIdx.x * 64 + (tid >> 2);
  const u32* hr = (const u32*)(hbf + (size_t)node * HD);

  float s = 0.f, s2 = 0.f;
  for (int i = 0; i < 8; ++i) {
    uint4 v = ((const uint4*)hr)[i];
    float f0 = __uint_as_float(v.x << 16), f1 = __uint_as_float(v.x & 0xFFFF0000u);
    float f2 = __uint_as_float(v.y << 16), f3 = __uint_as_float(v.y & 0xFFFF0000u);
    float f4 = __uint_as_float(v.z << 16), f5 = __uint_as_float(v.z & 0xFFFF0000u);
    float f6 = __uint_as_float(v.w << 16), f7 = __uint_as_float(v.w & 0xFFFF0000u);
    s += f0 + f1 + f2 + f3 + f4 + f5 + f6 + f7;
    s2 += f0 * f0 + f1 * f1 + f2 * f2 + f3 * f3
        + f4 * f4 + f5 * f5 + f6 * f6 + f7 * f7;
  }
  float mean = s * (1.f / HD);
  float var = s2 * (1.f / HD) - mean * mean;
  float r = rsqrtf(var + EPSV);

  float acc[16];
#pragma unroll
  for (int jb = 0; jb < 4; ++jb) {
    float4 b = ((const float4*)sB3)[jq * 4 + jb];
    acc[jb * 4 + 0] = b.x; acc[jb * 4 + 1] = b.y;
    acc[jb * 4 + 2] = b.z; acc[jb * 4 + 3] = b.w;
  }
  const float4* sW34 = (const float4*)sW3;
  for (int k4 = 0; k4 < HD / 4; ++k4) {
    uint2 rw = ((const uint2*)hr)[k4];
    float xk0 = __uint_as_float(rw.x << 16);
    float xk1 = __uint_as_float(rw.x & 0xFFFF0000u);
    float xk2 = __uint_as_float(rw.y << 16);
    float xk3 = __uint_as_float(rw.y & 0xFFFF0000u);
    float4 g4 = ((const float4*)sG)[k4];
    float4 bb4 = ((const float4*)sB)[k4];
    float xn0 = (xk0 - mean) * r * g4.x + bb4.x;
    float xn1 = (xk1 - mean) * r * g4.y + bb4.y;
    float xn2 = (xk2 - mean) * r * g4.z + bb4.z;
    float xn3 = (xk3 - mean) * r * g4.w + bb4.w;
#pragma unroll
    for (int jb = 0; jb < 4; ++jb) {
      float4 w0 = sW34[(k4 * 4 + 0) * 16 + jq * 4 + jb];
      float4 w1v = sW34[(k4 * 4 + 1) * 16 + jq * 4 + jb];
      float4 w2 = sW34[(k4 * 4 + 2) * 16 + jq * 4 + jb];
      float4 w3v = sW34[(k4 * 4 + 3) * 16 + jq * 4 + jb];
      acc[jb * 4 + 0] += xn0 * w0.x + xn1 * w1v.x + xn2 * w2.x + xn3 * w3v.x;
      acc[jb * 4 + 1] += xn0 * w0.y + xn1 * w1v.y + xn2 * w2.y + xn3 * w3v.y;
      acc[jb * 4 + 2] += xn0 * w0.z + xn1 * w1v.z + xn2 * w2.z + xn3 * w3v.z;
      acc[jb * 4 + 3] += xn0 * w0.w + xn1 * w1v.w + xn2 * w2.w + xn3 * w3v.w;
    }
  }

#pragma unroll
  for (int j = 0; j < 16; ++j) {
    float y = acc[j];
    acc[j] = (y > 0.f) ? y : expm1f(y);
  }

  const float4* sW44 = (const float4*)sW4;
#pragma unroll
  for (int c = 0; c < 2; ++c) {
    float p[16];
#pragma unroll
    for (int i = 0; i < 16; ++i) p[i] = 0.f;
#pragma unroll
    for (int kk = 0; kk < 16; ++kk) {
      float zk = acc[kk];
      int krow = jq * 16 + kk;
#pragma unroll
      for (int qd = 0; qd < 4; ++qd) {
        float4 w = sW44[krow * 8 + c * 4 + qd];
        p[qd * 4 + 0] += zk * w.x;
        p[qd * 4 + 1] += zk * w.y;
        p[qd * 4 + 2] += zk * w.z;
        p[qd * 4 + 3] += zk * w.w;
      }
    }
#pragma unroll
    for (int i = 0; i < 16; ++i) {
      p[i] += __shfl_xor(p[i], 1, 64);
      p[i] += __shfl_xor(p[i], 2, 64);
    }
    if (jq == c) {
      float4* op = (float4*)(out + (size_t)node * NOUT + c * 16);
#pragma unroll
      for (int qd = 0; qd < 4; ++qd) {
        float4 b = ((const float4*)sB4)[c * 4 + qd];
        float4 o;
        o.x = p[qd * 4 + 0] + b.x; o.y = p[qd * 4 + 1] + b.y;
        o.z = p[qd * 4 + 2] + b.z; o.w = p[qd * 4 + 3] + b.w;
        op[qd] = o;
      }
    }
  }
}

extern "C" void kernel_launch(void* const* d_in, const int* in_sizes, int n_in,
                              void* d_out, int out_size, void* d_ws, size_t ws_size,
                              hipStream_t stream) {
  const float* x      = (const float*)d_in[0];
  const float* ew     = (const float*)d_in[1];
  const int*   src    = (const int*)d_in[2];
  const int*   dst    = (const int*)d_in[3];
  const float* ln1_g  = (const float*)d_in[4];
  const float* ln1_b  = (const float*)d_in[5];
  const float* w1     = (const float*)d_in[6];
  const float* b1     = (const float*)d_in[7];
  const float* ln_g   = (const float*)d_in[8];
  const float* ln_b   = (const float*)d_in[9];
  const float* conv_w = (const float*)d_in[10];
  const float* conv_b = (const float*)d_in[11];
  const float* ln2_g  = (const float*)d_in[12];
  const float* ln2_b  = (const float*)d_in[13];
  const float* w3     = (const float*)d_in[14];
  const float* b3     = (const float*)d_in[15];
  const float* w4     = (const float*)d_in[16];
  const float* b4     = (const float*)d_in[17];
  float* out = (float*)d_out;

  char* ws = (char*)d_ws;
  u16*   hAbf  = (u16*)ws;                           // 8 MB
  u16*   hBbf  = hAbf + (size_t)NN * HD;             // 8 MB
  int*   ecnt  = (int*)(hBbf + (size_t)NN * HD);     // 256 KB (+pad)
  u32*   edgep = (u32*)(ecnt + NN + 64);             // NN*CAP*4B = 12.6 MB
  int*   pcnt  = (int*)(edgep + (size_t)NN * CAP);   // NP ints (+pad)
  uint2* tmp   = (uint2*)(pcnt + NP + 64);           // NP*PCAP*8B = 10.5 MB

  zero_k<<<1, NP, 0, stream>>>(pcnt);
  passA_k<<<NE / 4096, 1024, 0, stream>>>(src, dst, ew, pcnt, tmp);
  passB_k<<<NP, 256, 0, stream>>>(tmp, pcnt, edgep, ecnt);

  fc_first_k<<<NN / 64, 256, 0, stream>>>(x, ln1_g, ln1_b, w1, b1, ln_g, ln_b,
                                          hAbf);
  conv_k<<<NN / 32, 512, 0, stream>>>(hAbf, hBbf, ecnt, edgep,
                                      conv_w,        conv_b,       ln_g, ln_b);
  conv_k<<<NN / 32, 512, 0, stream>>>(hBbf, hAbf, ecnt, edgep,
                                      conv_w + 4096, conv_b + 64,  ln_g, ln_b);
  conv_k<<<NN / 32, 512, 0, stream>>>(hAbf, hBbf, ecnt, edgep,
                                      conv_w + 8192, conv_b + 128, ln_g, ln_b);
  fc_final_k<<<NN / 64, 256, 0, stream>>>(hBbf, ln2_g, ln2_b, w3, b3, w4, b4, out);
}

// Round 23
// 147.554 us; speedup vs baseline: 1.5577x; 1.1564x over previous
//
#include <hip/hip_runtime.h>

#define NN   65536
#define NE   1048576
#define CAP  48        // per-node edge capacity (Poisson(16): P(deg>=48)~5e-6)
#define NP   512       // partitions (128 nodes each), bin = dst >> 7
#define NODP 128       // nodes per partition
#define PCAP 2560      // partition capacity: mean 2048 + ~11 sd
#define FIN  128
#define HD   64
#define NOUT 32
#define EPSV 1e-5f

typedef unsigned short u16;
typedef unsigned int u32;
typedef __attribute__((ext_vector_type(8))) short short8v;   // 8 bf16
typedef __attribute__((ext_vector_type(4))) float f32x4;

__device__ __forceinline__ u16 f2bf(float f) {
  u32 x = __float_as_uint(f);
  u32 r = x + 0x7FFFu + ((x >> 16) & 1u);   // round-to-nearest-even
  return (u16)(r >> 16);
}
__device__ __forceinline__ float bf2f(u16 u) {
  return __uint_as_float((u32)u << 16);
}

__device__ __forceinline__ void fma4bf(float4& acc, uint2 g, float w) {
  acc.x += __uint_as_float(g.x << 16) * w;
  acc.y += __uint_as_float(g.x & 0xFFFF0000u) * w;
  acc.z += __uint_as_float(g.y << 16) * w;
  acc.w += __uint_as_float(g.y & 0xFFFF0000u) * w;
}

// ---------------- zero pcnt ----------------
__global__ __launch_bounds__(512) void zero_k(int* __restrict__ pcnt) {
  pcnt[threadIdx.x] = 0;
}

// ---------------- pass A: partition edges into 512 coarse bins --------
__global__ __launch_bounds__(1024) void passA_k(
    const int* __restrict__ src, const int* __restrict__ dst,
    const float* __restrict__ ew, int* __restrict__ pcnt,
    uint2* __restrict__ tmp) {
  __shared__ int hist[NP];
  __shared__ int base[NP];
  int t = threadIdx.x;
  if (t < NP) hist[t] = 0;
  __syncthreads();

  int d[4], s[4];
  float w[4];
  size_t e0 = (size_t)blockIdx.x * 4096;
#pragma unroll
  for (int r = 0; r < 4; ++r) {
    int i = e0 + r * 1024 + t;
    d[r] = dst[i]; s[r] = src[i]; w[r] = ew[i];
    atomicAdd(&hist[d[r] >> 7], 1);
  }
  __syncthreads();
  if (t < NP) {
    int c = hist[t];
    base[t] = c ? atomicAdd(&pcnt[t], c) : 0;
    hist[t] = 0;                 // reuse as cursor
  }
  __syncthreads();
#pragma unroll
  for (int r = 0; r < 4; ++r) {
    int bin = d[r] >> 7;
    int pos = base[bin] + atomicAdd(&hist[bin], 1);
    if (pos < PCAP)
      tmp[(size_t)bin * PCAP + pos] =
          make_uint2(((u32)d[r] << 16) | (u32)s[r], __float_as_uint(w[r]));
  }
}

// ---------------- pass B: per-partition CSR build + pad-to-4 --------
__global__ __launch_bounds__(256) void passB_k(
    const uint2* __restrict__ tmp, const int* __restrict__ pcnt,
    u32* __restrict__ edgep, int* __restrict__ ecnt) {
  __shared__ int cur[NODP];
  int p = blockIdx.x, t = threadIdx.x;
  if (t < NODP) cur[t] = 0;
  __syncthreads();
  int cntp = min(pcnt[p], PCAP);
  const uint2* tp = tmp + (size_t)p * PCAP;
  for (int i = t; i < cntp; i += 256) {
    uint2 e = tp[i];
    int dd = e.x >> 16;
    int pos = atomicAdd(&cur[dd & (NODP - 1)], 1);
    if (pos < CAP)
      edgep[(size_t)dd * CAP + pos] =
          (e.x & 0xFFFFu) | ((u32)f2bf(__uint_as_float(e.y)) << 16);
  }
  __syncthreads();
  if (t < NODP) {
    int node = p * NODP + t;
    int c = min(cur[t], CAP);
    int padded = min((c + 3) & ~3, CAP);
    for (int s = c; s < padded; ++s)
      edgep[(size_t)node * CAP + s] = 0u;   // src 0, bf16 weight 0
    ecnt[node] = padded;
  }
}

// ---------------- fc_first: LN(128) -> MFMA [128x64] -> ELU -> LN(64) ----------------
__global__ __launch_bounds__(256, 4) void fc_first_k(
    const float* __restrict__ x, const float* __restrict__ ln1_g,
    const float* __restrict__ ln1_b, const float* __restrict__ w1,
    const float* __restrict__ b1, const float* __restrict__ ln_g,
    const float* __restrict__ ln_b, u16* __restrict__ hAbf) {
  __shared__ __align__(16) u16 sXn[64 * 136];   // [node][k] bf16, pad 136
  __shared__ __align__(16) u16 sWb[64 * 136];   // [j][k] bf16 (W^T), pad 136
  __shared__ __align__(16) float sG[FIN], sB[FIN];
  int tid = threadIdx.x;
  for (int i = tid; i < FIN * HD; i += 256) {
    int k = i >> 6, j = i & 63;          // w1[k][j]
    sWb[j * 136 + k] = f2bf(w1[i]);
  }
  if (tid < FIN) { sG[tid] = ln1_g[tid]; sB[tid] = ln1_b[tid]; }
  __syncthreads();

  // ---- phase 1: LN(128), 4 lanes/node, x read once ----
  {
    int jq = tid & 3;                  // k-slice jq*32..jq*32+31
    int nl = tid >> 2;                 // local node 0..63
    int node = blockIdx.x * 64 + nl;
    const float4* xp = (const float4*)(x + (size_t)node * FIN + jq * 32);
    float xv[32];
    float s = 0.f, s2 = 0.f;
#pragma unroll
    for (int i = 0; i < 8; ++i) {
      float4 v = xp[i];
      xv[i * 4 + 0] = v.x; xv[i * 4 + 1] = v.y;
      xv[i * 4 + 2] = v.z; xv[i * 4 + 3] = v.w;
      s += v.x + v.y + v.z + v.w;
      s2 += v.x * v.x + v.y * v.y + v.z * v.z + v.w * v.w;
    }
    s += __shfl_xor(s, 1, 64);  s += __shfl_xor(s, 2, 64);
    s2 += __shfl_xor(s2, 1, 64); s2 += __shfl_xor(s2, 2, 64);
    float mean = s * (1.f / FIN);
    float var = s2 * (1.f / FIN) - mean * mean;
    float r = rsqrtf(var + EPSV);
    u32* dp = (u32*)&sXn[nl * 136 + jq * 32];
#pragma unroll
    for (int i = 0; i < 16; ++i) {
      int k = jq * 32 + i * 2;
      float a0 = (xv[i * 2 + 0] - mean) * r * sG[k + 0] + sB[k + 0];
      float a1 = (xv[i * 2 + 1] - mean) * r * sG[k + 1] + sB[k + 1];
      dp[i] = (u32)f2bf(a0) | ((u32)f2bf(a1) << 16);
    }
  }
  __syncthreads();

  // ---- phase 2: MFMA. wave wl -> nodes wl*16..+15; 4 j-tiles ----
  int wl = tid >> 6, lane = tid & 63;
  int q = lane >> 4, fq = lane & 15;
  f32x4 d0 = {0.f, 0.f, 0.f, 0.f}, d1 = d0, d2 = d0, d3 = d0;
#pragma unroll
  for (int st = 0; st < 4; ++st) {
    short8v av = *(const short8v*)&sXn[(wl * 16 + fq) * 136 + st * 32 + q * 8];
    short8v b0 = *(const short8v*)&sWb[(0 * 16 + fq) * 136 + st * 32 + q * 8];
    short8v b1v = *(const short8v*)&sWb[(1 * 16 + fq) * 136 + st * 32 + q * 8];
    short8v b2 = *(const short8v*)&sWb[(2 * 16 + fq) * 136 + st * 32 + q * 8];
    short8v b3v = *(const short8v*)&sWb[(3 * 16 + fq) * 136 + st * 32 + q * 8];
    d0 = __builtin_amdgcn_mfma_f32_16x16x32_bf16(av, b0, d0, 0, 0, 0);
    d1 = __builtin_amdgcn_mfma_f32_16x16x32_bf16(av, b1v, d1, 0, 0, 0);
    d2 = __builtin_amdgcn_mfma_f32_16x16x32_bf16(av, b2, d2, 0, 0, 0);
    d3 = __builtin_amdgcn_mfma_f32_16x16x32_bf16(av, b3v, d3, 0, 0, 0);
  }

  // ---- phase 3: bias+ELU (in regs), LN(64) via 16-lane butterflies, store ----
  float b1r[4], lgr[4], lbr[4];
#pragma unroll
  for (int t = 0; t < 4; ++t) {
    b1r[t] = b1[t * 16 + fq];
    lgr[t] = ln_g[t * 16 + fq];
    lbr[t] = ln_b[t * 16 + fq];
  }
  float y0[4], y1[4], y2[4], y3[4];
  float ps[4], ps2[4];
#pragma unroll
  for (int reg = 0; reg < 4; ++reg) {
    float v0 = d0[reg] + b1r[0]; v0 = (v0 > 0.f) ? v0 : expm1f(v0);
    float v1 = d1[reg] + b1r[1]; v1 = (v1 > 0.f) ? v1 : expm1f(v1);
    float v2 = d2[reg] + b1r[2]; v2 = (v2 > 0.f) ? v2 : expm1f(v2);
    float v3 = d3[reg] + b1r[3]; v3 = (v3 > 0.f) ? v3 : expm1f(v3);
    y0[reg] = v0; y1[reg] = v1; y2[reg] = v2; y3[reg] = v3;
    ps[reg] = v0 + v1 + v2 + v3;
    ps2[reg] = v0 * v0 + v1 * v1 + v2 * v2 + v3 * v3;
  }
#pragma unroll
  for (int o = 1; o <= 8; o <<= 1) {
#pragma unroll
    for (int reg = 0; reg < 4; ++reg) {
      ps[reg] += __shfl_xor(ps[reg], o, 64);
      ps2[reg] += __shfl_xor(ps2[reg], o, 64);
    }
  }
#pragma unroll
  for (int reg = 0; reg < 4; ++reg) {
    int n = blockIdx.x * 64 + wl * 16 + q * 4 + reg;   // D: row=(lane>>4)*4+reg
    float m2 = ps[reg] * (1.f / HD);
    float vv = ps2[reg] * (1.f / HD) - m2 * m2;
    float r2 = rsqrtf(vv + EPSV);
    hAbf[(size_t)n * HD + 0 * 16 + fq] = f2bf((y0[reg] - m2) * r2 * lgr[0] + lbr[0]);
    hAbf[(size_t)n * HD + 1 * 16 + fq] = f2bf((y1[reg] - m2) * r2 * lgr[1] + lbr[1]);
    hAbf[(size_t)n * HD + 2 * 16 + fq] = f2bf((y2[reg] - m2) * r2 * lgr[2] + lbr[2]);
    hAbf[(size_t)n * HD + 3 * 16 + fq] = f2bf((y3[reg] - m2) * r2 * lgr[3] + lbr[3]);
  }
}

// ---------------- conv: gather -> MFMA GEMM (bf16) -> LN -> bf16 residual ------------
__global__ __launch_bounds__(512, 8) void conv_k(
    const u16* __restrict__ hbf_in, u16* __restrict__ hbf_out,
    const int* __restrict__ ecnt, const u32* __restrict__ edgep,
    const float* __restrict__ W, const float* __restrict__ B,
    const float* __restrict__ ln_g, const float* __restrict__ ln_b) {
  __shared__ __align__(16) u16 sWt[HD * 72];      // [j][k] bf16, row pad 72
  __shared__ __align__(16) u16 sAgg[32 * 72];     // [node][k] bf16, row pad 72
  __shared__ __align__(16) float sOut[32 * 68];   // [node][j] f32, row pad 68
  int tid = threadIdx.x;
  for (int i = tid; i < HD * HD; i += 512) {
    int k = i >> 6, j = i & 63;          // W[k][j]
    sWt[j * 72 + k] = f2bf(W[i]);
  }

  int wl = tid >> 6, lane = tid & 63;
  int q = lane >> 4;
  int fq = lane & 15;
  int nbase = blockIdx.x * 32;

  int cntR[4];
  u32 HR[4];
#pragma unroll
  for (int rp = 0; rp < 4; ++rp) {
    int n = nbase + wl * 4 + rp;
    cntR[rp] = ecnt[n];
    HR[rp] = edgep[(size_t)n * CAP + min(lane, 31)];
  }

#pragma unroll
  for (int rp = 0; rp < 4; ++rp) {
    int n = nbase + wl * 4 + rp;
    int cnt = cntR[rp];
    u32 H = HR[rp];

    float4 acc = make_float4(0.f, 0.f, 0.f, 0.f);
    if (cnt > 0) {
      int ng = cnt >> 2;
      int ngs = min(ng, 8);
      int g = 0;
      for (; g + 4 <= ngs; g += 4) {
        u32 h0 = __shfl(H, (g + 0) * 4 + q, 64);
        u32 h1 = __shfl(H, (g + 1) * 4 + q, 64);
        u32 h2 = __shfl(H, (g + 2) * 4 + q, 64);
        u32 h3 = __shfl(H, (g + 3) * 4 + q, 64);
        uint2 g0 = ((const uint2*)(hbf_in + ((size_t)(h0 & 0xFFFFu) << 6)))[fq];
        uint2 g1 = ((const uint2*)(hbf_in + ((size_t)(h1 & 0xFFFFu) << 6)))[fq];
        uint2 g2 = ((const uint2*)(hbf_in + ((size_t)(h2 & 0xFFFFu) << 6)))[fq];
        uint2 g3 = ((const uint2*)(hbf_in + ((size_t)(h3 & 0xFFFFu) << 6)))[fq];
        fma4bf(acc, g0, __uint_as_float(h0 & 0xFFFF0000u));
        fma4bf(acc, g1, __uint_as_float(h1 & 0xFFFF0000u));
        fma4bf(acc, g2, __uint_as_float(h2 & 0xFFFF0000u));
        fma4bf(acc, g3, __uint_as_float(h3 & 0xFFFF0000u));
      }
      for (; g < ngs; ++g) {
        u32 hj = __shfl(H, g * 4 + q, 64);
        uint2 gg = ((const uint2*)(hbf_in + ((size_t)(hj & 0xFFFFu) << 6)))[fq];
        fma4bf(acc, gg, __uint_as_float(hj & 0xFFFF0000u));
      }
      for (; g < ng; ++g) {
        u32 hj = edgep[(size_t)n * CAP + g * 4 + q];
        uint2 gg = ((const uint2*)(hbf_in + ((size_t)(hj & 0xFFFFu) << 6)))[fq];
        fma4bf(acc, gg, __uint_as_float(hj & 0xFFFF0000u));
      }
    }
#pragma unroll
    for (int off = 16; off < 64; off <<= 1) {
      acc.x += __shfl_xor(acc.x, off, 64);
      acc.y += __shfl_xor(acc.y, off, 64);
      acc.z += __shfl_xor(acc.z, off, 64);
      acc.w += __shfl_xor(acc.w, off, 64);
    }
    if (lane < 16) {
      u32 p0 = (u32)f2bf(acc.x) | ((u32)f2bf(acc.y) << 16);
      u32 p1 = (u32)f2bf(acc.z) | ((u32)f2bf(acc.w) << 16);
      u32* dp = (u32*)&sAgg[(wl * 4 + rp) * 72 + fq * 4];
      dp[0] = p0; dp[1] = p1;
    }
  }
  __syncthreads();

  {
    int g = wl >> 2, t = wl & 3;
    f32x4 d = {0.f, 0.f, 0.f, 0.f};
#pragma unroll
    for (int s = 0; s < 2; ++s) {
      short8v av = *(const short8v*)&sAgg[(g * 16 + fq) * 72 + s * 32 + q * 8];
      short8v bv = *(const short8v*)&sWt[(t * 16 + fq) * 72 + s * 32 + q * 8];
      d = __builtin_amdgcn_mfma_f32_16x16x32_bf16(av, bv, d, 0, 0, 0);
    }
#pragma unroll
    for (int reg = 0; reg < 4; ++reg) {
      int row = q * 4 + reg;
      sOut[(g * 16 + row) * 68 + t * 16 + fq] = d[reg];
    }
  }
  __syncthreads();

  float bias = B[lane], lg = ln_g[lane], lb = ln_b[lane];
#pragma unroll
  for (int rp = 0; rp < 4; ++rp) {
    int nl = wl * 4 + rp;
    int n = nbase + nl;
    float y = sOut[nl * 68 + lane] + bias;
    float a = y, b2 = y * y;
#pragma unroll
    for (int o = 32; o > 0; o >>= 1) {
      a += __shfl_xor(a, o, 64);
      b2 += __shfl_xor(b2, o, 64);
    }
    float m = a * (1.f / HD);
    float v = b2 * (1.f / HD) - m * m;
    float ln = (y - m) * rsqrtf(v + EPSV) * lg + lb;
    float hv = bf2f(hbf_in[(size_t)n * HD + lane]) + ln;
    hbf_out[(size_t)n * HD + lane] = f2bf(hv);
  }
}

// ---------------- fc_final: LN(64) -> MFMA [64x64] -> ELU -> MFMA [64x32] ------------
// 64 nodes/block, 4 waves. One barrier (after W staging + phase1).
__global__ __launch_bounds__(256, 4) void fc_final_k(
    const u16* __restrict__ hbf, const float* __restrict__ ln2_g,
    const float* __restrict__ ln2_b, const float* __restrict__ w3,
    const float* __restrict__ b3, const float* __restrict__ w4,
    const float* __restrict__ b4, float* __restrict__ out) {
  __shared__ __align__(16) u16 sHn[64 * 72];    // [node][k] LN(h) bf16
  __shared__ __align__(16) u16 sW3b[64 * 72];   // [j][k] W3^T bf16
  __shared__ __align__(16) u16 sW4b[32 * 72];   // [j][k] W4^T bf16
  __shared__ __align__(16) u16 sZ[64 * 72];     // [node][k] z bf16
  int tid = threadIdx.x;
  for (int i = tid; i < HD * HD; i += 256) {
    int k = i >> 6, j = i & 63;          // w3[k][j]
    sW3b[j * 72 + k] = f2bf(w3[i]);
  }
  for (int i = tid; i < HD * NOUT; i += 256) {
    int k = i >> 5, j = i & 31;          // w4[k][j]
    sW4b[j * 72 + k] = f2bf(w4[i]);
  }

  // ---- phase 1: LN(64), 4 lanes/node ----
  {
    int jq = tid & 3;                  // k-slice jq*16..jq*16+15
    int nl = tid >> 2;
    int node = blockIdx.x * 64 + nl;
    const uint4* hp = (const uint4*)(hbf + (size_t)node * HD + jq * 16);
    float hv[16];
    float s = 0.f, s2 = 0.f;
#pragma unroll
    for (int i = 0; i < 2; ++i) {
      uint4 v = hp[i];
      float f0 = __uint_as_float(v.x << 16), f1 = __uint_as_float(v.x & 0xFFFF0000u);
      float f2 = __uint_as_float(v.y << 16), f3 = __uint_as_float(v.y & 0xFFFF0000u);
      float f4 = __uint_as_float(v.z << 16), f5 = __uint_as_float(v.z & 0xFFFF0000u);
      float f6 = __uint_as_float(v.w << 16), f7 = __uint_as_float(v.w & 0xFFFF0000u);
      hv[i * 8 + 0] = f0; hv[i * 8 + 1] = f1; hv[i * 8 + 2] = f2; hv[i * 8 + 3] = f3;
      hv[i * 8 + 4] = f4; hv[i * 8 + 5] = f5; hv[i * 8 + 6] = f6; hv[i * 8 + 7] = f7;
      s += f0 + f1 + f2 + f3 + f4 + f5 + f6 + f7;
      s2 += f0 * f0 + f1 * f1 + f2 * f2 + f3 * f3
          + f4 * f4 + f5 * f5 + f6 * f6 + f7 * f7;
    }
    s += __shfl_xor(s, 1, 64);  s += __shfl_xor(s, 2, 64);
    s2 += __shfl_xor(s2, 1, 64); s2 += __shfl_xor(s2, 2, 64);
    float mean = s * (1.f / HD);
    float var = s2 * (1.f / HD) - mean * mean;
    float r = rsqrtf(var + EPSV);
    u32* dp = (u32*)&sHn[nl * 72 + jq * 16];
#pragma unroll
    for (int i = 0; i < 8; ++i) {
      int k = jq * 16 + i * 2;
      float a0 = (hv[i * 2 + 0] - mean) * r * ln2_g[k + 0] + ln2_b[k + 0];
      float a1 = (hv[i * 2 + 1] - mean) * r * ln2_g[k + 1] + ln2_b[k + 1];
      dp[i] = (u32)f2bf(a0) | ((u32)f2bf(a1) << 16);
    }
  }
  __syncthreads();   // W3/W4 staged + sHn complete

  // ---- phase 2: GEMM1 MFMA, wave wl -> nodes wl*16..+15, 4 j-tiles ----
  int wl = tid >> 6, lane = tid & 63;
  int q = lane >> 4, fq = lane & 15;
  f32x4 d0 = {0.f, 0.f, 0.f, 0.f}, d1 = d0, d2 = d0, d3 = d0;
#pragma unroll
  for (int st = 0; st < 2; ++st) {
    short8v av = *(const short8v*)&sHn[(wl * 16 + fq) * 72 + st * 32 + q * 8];
    short8v b0 = *(const short8v*)&sW3b[(0 * 16 + fq) * 72 + st * 32 + q * 8];
    short8v b1v = *(const short8v*)&sW3b[(1 * 16 + fq) * 72 + st * 32 + q * 8];
    short8v b2 = *(const short8v*)&sW3b[(2 * 16 + fq) * 72 + st * 32 + q * 8];
    short8v b3v = *(const short8v*)&sW3b[(3 * 16 + fq) * 72 + st * 32 + q * 8];
    d0 = __builtin_amdgcn_mfma_f32_16x16x32_bf16(av, b0, d0, 0, 0, 0);
    d1 = __builtin_amdgcn_mfma_f32_16x16x32_bf16(av, b1v, d1, 0, 0, 0);
    d2 = __builtin_amdgcn_mfma_f32_16x16x32_bf16(av, b2, d2, 0, 0, 0);
    d3 = __builtin_amdgcn_mfma_f32_16x16x32_bf16(av, b3v, d3, 0, 0, 0);
  }
  // bias + ELU, z -> bf16 LDS (same-wave rows: no barrier needed)
  {
    float b3r[4];
#pragma unroll
    for (int t = 0; t < 4; ++t) b3r[t] = b3[t * 16 + fq];
#pragma unroll
    for (int reg = 0; reg < 4; ++reg) {
      int row = wl * 16 + q * 4 + reg;
      float v0 = d0[reg] + b3r[0]; v0 = (v0 > 0.f) ? v0 : expm1f(v0);
      float v1 = d1[reg] + b3r[1]; v1 = (v1 > 0.f) ? v1 : expm1f(v1);
      float v2 = d2[reg] + b3r[2]; v2 = (v2 > 0.f) ? v2 : expm1f(v2);
      float v3 = d3[reg] + b3r[3]; v3 = (v3 > 0.f) ? v3 : expm1f(v3);
      sZ[row * 72 + 0 * 16 + fq] = f2bf(v0);
      sZ[row * 72 + 1 * 16 + fq] = f2bf(v1);
      sZ[row * 72 + 2 * 16 + fq] = f2bf(v2);
      sZ[row * 72 + 3 * 16 + fq] = f2bf(v3);
    }
  }

  // ---- phase 3: GEMM2 MFMA (64 -> 32), 2 j-tiles, direct f32 store ----
  {
    f32x4 e0 = {0.f, 0.f, 0.f, 0.f}, e1 = e0;
#pragma unroll
    for (int st = 0; st < 2; ++st) {
      short8v av = *(const short8v*)&sZ[(wl * 16 + fq) * 72 + st * 32 + q * 8];
      short8v b0 = *(const short8v*)&sW4b[(0 * 16 + fq) * 72 + st * 32 + q * 8];
      short8v b1v = *(const short8v*)&sW4b[(1 * 16 + fq) * 72 + st * 32 + q * 8];
      e0 = __builtin_amdgcn_mfma_f32_16x16x32_bf16(av, b0, e0, 0, 0, 0);
      e1 = __builtin_amdgcn_mfma_f32_16x16x32_bf16(av, b1v, e1, 0, 0, 0);
    }
    float b4r0 = b4[0 * 16 + fq], b4r1 = b4[1 * 16 + fq];
#pragma unroll
    for (int reg = 0; reg < 4; ++reg) {
      int n = blockIdx.x * 64 + wl * 16 + q * 4 + reg;
      out[(size_t)n * NOUT + 0 * 16 + fq] = e0[reg] + b4r0;
      out[(size_t)n * NOUT + 1 * 16 + fq] = e1[reg] + b4r1;
    }
  }
}

extern "C" void kernel_launch(void* const* d_in, const int* in_sizes, int n_in,
                              void* d_out, int out_size, void* d_ws, size_t ws_size,
                              hipStream_t stream) {
  const float* x      = (const float*)d_in[0];
  const float* ew     = (const float*)d_in[1];
  const int*   src    = (const int*)d_in[2];
  const int*   dst    = (const int*)d_in[3];
  const float* ln1_g  = (const float*)d_in[4];
  const float* ln1_b  = (const float*)d_in[5];
  const float* w1     = (const float*)d_in[6];
  const float* b1     = (const float*)d_in[7];
  const float* ln_g   = (const float*)d_in[8];
  const float* ln_b   = (const float*)d_in[9];
  const float* conv_w = (const float*)d_in[10];
  const float* conv_b = (const float*)d_in[11];
  const float* ln2_g  = (const float*)d_in[12];
  const float* ln2_b  = (const float*)d_in[13];
  const float* w3     = (const float*)d_in[14];
  const float* b3     = (const float*)d_in[15];
  const float* w4     = (const float*)d_in[16];
  const float* b4     = (const float*)d_in[17];
  float* out = (float*)d_out;

  char* ws = (char*)d_ws;
  u16*   hAbf  = (u16*)ws;                           // 8 MB
  u16*   hBbf  = hAbf + (size_t)NN * HD;             // 8 MB
  int*   ecnt  = (int*)(hBbf + (size_t)NN * HD);     // 256 KB (+pad)
  u32*   edgep = (u32*)(ecnt + NN + 64);             // NN*CAP*4B = 12.6 MB
  int*   pcnt  = (int*)(edgep + (size_t)NN * CAP);   // NP ints (+pad)
  uint2* tmp   = (uint2*)(pcnt + NP + 64);           // NP*PCAP*8B = 10.5 MB

  zero_k<<<1, NP, 0, stream>>>(pcnt);
  passA_k<<<NE / 4096, 1024, 0, stream>>>(src, dst, ew, pcnt, tmp);
  passB_k<<<NP, 256, 0, stream>>>(tmp, pcnt, edgep, ecnt);

  fc_first_k<<<NN / 64, 256, 0, stream>>>(x, ln1_g, ln1_b, w1, b1, ln_g, ln_b,
                                          hAbf);
  conv_k<<<NN / 32, 512, 0, stream>>>(hAbf, hBbf, ecnt, edgep,
                                      conv_w,        conv_b,       ln_g, ln_b);
  conv_k<<<NN / 32, 512, 0, stream>>>(hBbf, hAbf, ecnt, edgep,
                                      conv_w + 4096, conv_b + 64,  ln_g, ln_b);
  conv_k<<<NN / 32, 512, 0, stream>>>(hAbf, hBbf, ecnt, edgep,
                                      conv_w + 8192, conv_b + 128, ln_g, ln_b);
  fc_final_k<<<NN / 64, 256, 0, stream>>>(hBbf, ln2_g, ln2_b, w3, b3, w4, b4, out);
}

// Round 24
// 142.784 us; speedup vs baseline: 1.6097x; 1.0334x over previous
//
#include <hip/hip_runtime.h>

#define NN   65536
#define NE   1048576
#define CAP  48        // per-node edge capacity (Poisson(16): P(deg>=48)~5e-6)
#define NP   512       // partitions (128 nodes each), bin = dst >> 7
#define NODP 128       // nodes per partition
#define PCAP 2560      // partition capacity: mean 2048 + ~11 sd
#define FIN  128
#define HD   64
#define NOUT 32
#define EPSV 1e-5f

typedef unsigned short u16;
typedef unsigned int u32;
typedef __attribute__((ext_vector_type(8))) short short8v;   // 8 bf16
typedef __attribute__((ext_vector_type(4))) float f32x4;

__device__ __forceinline__ u16 f2bf(float f) {
  u32 x = __float_as_uint(f);
  u32 r = x + 0x7FFFu + ((x >> 16) & 1u);   // round-to-nearest-even
  return (u16)(r >> 16);
}
__device__ __forceinline__ float bf2f(u16 u) {
  return __uint_as_float((u32)u << 16);
}

__device__ __forceinline__ void fma4bf(float4& acc, uint2 g, float w) {
  acc.x += __uint_as_float(g.x << 16) * w;
  acc.y += __uint_as_float(g.x & 0xFFFF0000u) * w;
  acc.z += __uint_as_float(g.y << 16) * w;
  acc.w += __uint_as_float(g.y & 0xFFFF0000u) * w;
}

// ---------------- zero pcnt ----------------
__global__ __launch_bounds__(512) void zero_k(int* __restrict__ pcnt) {
  pcnt[threadIdx.x] = 0;
}

// ---------------- pass A: partition edges into 512 coarse bins --------
__global__ __launch_bounds__(1024) void passA_k(
    const int* __restrict__ src, const int* __restrict__ dst,
    const float* __restrict__ ew, int* __restrict__ pcnt,
    uint2* __restrict__ tmp) {
  __shared__ int hist[NP];
  __shared__ int base[NP];
  int t = threadIdx.x;
  if (t < NP) hist[t] = 0;
  __syncthreads();

  int d[4], s[4];
  float w[4];
  size_t e0 = (size_t)blockIdx.x * 4096;
#pragma unroll
  for (int r = 0; r < 4; ++r) {
    int i = e0 + r * 1024 + t;
    d[r] = dst[i]; s[r] = src[i]; w[r] = ew[i];
    atomicAdd(&hist[d[r] >> 7], 1);
  }
  __syncthreads();
  if (t < NP) {
    int c = hist[t];
    base[t] = c ? atomicAdd(&pcnt[t], c) : 0;
    hist[t] = 0;                 // reuse as cursor
  }
  __syncthreads();
#pragma unroll
  for (int r = 0; r < 4; ++r) {
    int bin = d[r] >> 7;
    int pos = base[bin] + atomicAdd(&hist[bin], 1);
    if (pos < PCAP)
      tmp[(size_t)bin * PCAP + pos] =
          make_uint2(((u32)d[r] << 16) | (u32)s[r], __float_as_uint(w[r]));
  }
}

// ---------------- pass B: per-partition CSR build + pad-to-4 --------
__global__ __launch_bounds__(256) void passB_k(
    const uint2* __restrict__ tmp, const int* __restrict__ pcnt,
    u32* __restrict__ edgep, int* __restrict__ ecnt) {
  __shared__ int cur[NODP];
  int p = blockIdx.x, t = threadIdx.x;
  if (t < NODP) cur[t] = 0;
  __syncthreads();
  int cntp = min(pcnt[p], PCAP);
  const uint2* tp = tmp + (size_t)p * PCAP;
  for (int i = t; i < cntp; i += 256) {
    uint2 e = tp[i];
    int dd = e.x >> 16;
    int pos = atomicAdd(&cur[dd & (NODP - 1)], 1);
    if (pos < CAP)
      edgep[(size_t)dd * CAP + pos] =
          (e.x & 0xFFFFu) | ((u32)f2bf(__uint_as_float(e.y)) << 16);
  }
  __syncthreads();
  if (t < NODP) {
    int node = p * NODP + t;
    int c = min(cur[t], CAP);
    int padded = min((c + 3) & ~3, CAP);
    for (int s = c; s < padded; ++s)
      edgep[(size_t)node * CAP + s] = 0u;   // src 0, bf16 weight 0
    ecnt[node] = padded;
  }
}

// ---------------- fc_first: LN(128) -> MFMA [128x64] -> ELU -> LN(64) ----------------
__global__ __launch_bounds__(256, 4) void fc_first_k(
    const float* __restrict__ x, const float* __restrict__ ln1_g,
    const float* __restrict__ ln1_b, const float* __restrict__ w1,
    const float* __restrict__ b1, const float* __restrict__ ln_g,
    const float* __restrict__ ln_b, u16* __restrict__ hAbf) {
  __shared__ __align__(16) u16 sXn[64 * 136];   // [node][k] bf16, pad 136
  __shared__ __align__(16) u16 sWb[64 * 136];   // [j][k] bf16 (W^T), pad 136
  __shared__ __align__(16) float sG[FIN], sB[FIN];
  int tid = threadIdx.x;
  for (int i = tid; i < FIN * HD; i += 256) {
    int k = i >> 6, j = i & 63;          // w1[k][j]
    sWb[j * 136 + k] = f2bf(w1[i]);
  }
  if (tid < FIN) { sG[tid] = ln1_g[tid]; sB[tid] = ln1_b[tid]; }
  __syncthreads();

  // ---- phase 1: LN(128), 4 lanes/node, x read once ----
  {
    int jq = tid & 3;                  // k-slice jq*32..jq*32+31
    int nl = tid >> 2;                 // local node 0..63
    int node = blockIdx.x * 64 + nl;
    const float4* xp = (const float4*)(x + (size_t)node * FIN + jq * 32);
    float xv[32];
    float s = 0.f, s2 = 0.f;
#pragma unroll
    for (int i = 0; i < 8; ++i) {
      float4 v = xp[i];
      xv[i * 4 + 0] = v.x; xv[i * 4 + 1] = v.y;
      xv[i * 4 + 2] = v.z; xv[i * 4 + 3] = v.w;
      s += v.x + v.y + v.z + v.w;
      s2 += v.x * v.x + v.y * v.y + v.z * v.z + v.w * v.w;
    }
    s += __shfl_xor(s, 1, 64);  s += __shfl_xor(s, 2, 64);
    s2 += __shfl_xor(s2, 1, 64); s2 += __shfl_xor(s2, 2, 64);
    float mean = s * (1.f / FIN);
    float var = s2 * (1.f / FIN) - mean * mean;
    float r = rsqrtf(var + EPSV);
    u32* dp = (u32*)&sXn[nl * 136 + jq * 32];
#pragma unroll
    for (int i = 0; i < 16; ++i) {
      int k = jq * 32 + i * 2;
      float a0 = (xv[i * 2 + 0] - mean) * r * sG[k + 0] + sB[k + 0];
      float a1 = (xv[i * 2 + 1] - mean) * r * sG[k + 1] + sB[k + 1];
      dp[i] = (u32)f2bf(a0) | ((u32)f2bf(a1) << 16);
    }
  }
  __syncthreads();

  // ---- phase 2: MFMA. wave wl -> nodes wl*16..+15; 4 j-tiles ----
  int wl = tid >> 6, lane = tid & 63;
  int q = lane >> 4, fq = lane & 15;
  f32x4 d0 = {0.f, 0.f, 0.f, 0.f}, d1 = d0, d2 = d0, d3 = d0;
#pragma unroll
  for (int st = 0; st < 4; ++st) {
    short8v av = *(const short8v*)&sXn[(wl * 16 + fq) * 136 + st * 32 + q * 8];
    short8v b0 = *(const short8v*)&sWb[(0 * 16 + fq) * 136 + st * 32 + q * 8];
    short8v b1v = *(const short8v*)&sWb[(1 * 16 + fq) * 136 + st * 32 + q * 8];
    short8v b2 = *(const short8v*)&sWb[(2 * 16 + fq) * 136 + st * 32 + q * 8];
    short8v b3v = *(const short8v*)&sWb[(3 * 16 + fq) * 136 + st * 32 + q * 8];
    d0 = __builtin_amdgcn_mfma_f32_16x16x32_bf16(av, b0, d0, 0, 0, 0);
    d1 = __builtin_amdgcn_mfma_f32_16x16x32_bf16(av, b1v, d1, 0, 0, 0);
    d2 = __builtin_amdgcn_mfma_f32_16x16x32_bf16(av, b2, d2, 0, 0, 0);
    d3 = __builtin_amdgcn_mfma_f32_16x16x32_bf16(av, b3v, d3, 0, 0, 0);
  }

  // ---- phase 3: bias+ELU (in regs), LN(64) via 16-lane butterflies, store ----
  float b1r[4], lgr[4], lbr[4];
#pragma unroll
  for (int t = 0; t < 4; ++t) {
    b1r[t] = b1[t * 16 + fq];
    lgr[t] = ln_g[t * 16 + fq];
    lbr[t] = ln_b[t * 16 + fq];
  }
  float y0[4], y1[4], y2[4], y3[4];
  float ps[4], ps2[4];
#pragma unroll
  for (int reg = 0; reg < 4; ++reg) {
    float v0 = d0[reg] + b1r[0]; v0 = (v0 > 0.f) ? v0 : expm1f(v0);
    float v1 = d1[reg] + b1r[1]; v1 = (v1 > 0.f) ? v1 : expm1f(v1);
    float v2 = d2[reg] + b1r[2]; v2 = (v2 > 0.f) ? v2 : expm1f(v2);
    float v3 = d3[reg] + b1r[3]; v3 = (v3 > 0.f) ? v3 : expm1f(v3);
    y0[reg] = v0; y1[reg] = v1; y2[reg] = v2; y3[reg] = v3;
    ps[reg] = v0 + v1 + v2 + v3;
    ps2[reg] = v0 * v0 + v1 * v1 + v2 * v2 + v3 * v3;
  }
#pragma unroll
  for (int o = 1; o <= 8; o <<= 1) {
#pragma unroll
    for (int reg = 0; reg < 4; ++reg) {
      ps[reg] += __shfl_xor(ps[reg], o, 64);
      ps2[reg] += __shfl_xor(ps2[reg], o, 64);
    }
  }
#pragma unroll
  for (int reg = 0; reg < 4; ++reg) {
    int n = blockIdx.x * 64 + wl * 16 + q * 4 + reg;   // D: row=(lane>>4)*4+reg
    float m2 = ps[reg] * (1.f / HD);
    float vv = ps2[reg] * (1.f / HD) - m2 * m2;
    float r2 = rsqrtf(vv + EPSV);
    hAbf[(size_t)n * HD + 0 * 16 + fq] = f2bf((y0[reg] - m2) * r2 * lgr[0] + lbr[0]);
    hAbf[(size_t)n * HD + 1 * 16 + fq] = f2bf((y1[reg] - m2) * r2 * lgr[1] + lbr[1]);
    hAbf[(size_t)n * HD + 2 * 16 + fq] = f2bf((y2[reg] - m2) * r2 * lgr[2] + lbr[2]);
    hAbf[(size_t)n * HD + 3 * 16 + fq] = f2bf((y3[reg] - m2) * r2 * lgr[3] + lbr[3]);
  }
}

// ---------------- conv: pair-interleaved gather -> MFMA GEMM -> LN -> residual -------
__global__ __launch_bounds__(512, 8) void conv_k(
    const u16* __restrict__ hbf_in, u16* __restrict__ hbf_out,
    const int* __restrict__ ecnt, const u32* __restrict__ edgep,
    const float* __restrict__ W, const float* __restrict__ B,
    const float* __restrict__ ln_g, const float* __restrict__ ln_b) {
  __shared__ __align__(16) u16 sWt[HD * 72];      // [j][k] bf16, row pad 72
  __shared__ __align__(16) u16 sAgg[32 * 72];     // [node][k] bf16, row pad 72
  __shared__ __align__(16) float sOut[32 * 68];   // [node][j] f32, row pad 68
  int tid = threadIdx.x;
  for (int i = tid; i < HD * HD; i += 512) {
    int k = i >> 6, j = i & 63;          // W[k][j]
    sWt[j * 72 + k] = f2bf(W[i]);
  }

  int wl = tid >> 6, lane = tid & 63;
  int q = lane >> 4;
  int fq = lane & 15;
  int nbase = blockIdx.x * 32;

  int cntR[4];
  u32 HR[4];
#pragma unroll
  for (int rp = 0; rp < 4; ++rp) {
    int n = nbase + wl * 4 + rp;
    cntR[rp] = ecnt[n];
    HR[rp] = edgep[(size_t)n * CAP + min(lane, 31)];
  }

  // ---- gather: 2 node-pairs, interleaved dependency chains ----
#pragma unroll
  for (int pr = 0; pr < 2; ++pr) {
    int nA = nbase + wl * 4 + pr * 2;
    int nB = nA + 1;
    int cA = cntR[pr * 2], cB = cntR[pr * 2 + 1];
    u32 HA = HR[pr * 2], HB = HR[pr * 2 + 1];

    float4 accA = make_float4(0.f, 0.f, 0.f, 0.f);
    float4 accB = make_float4(0.f, 0.f, 0.f, 0.f);
    int ngsA = min(cA >> 2, 8), ngsB = min(cB >> 2, 8);
    int ngm = max(ngsA, ngsB);
    int g = 0;
    for (; g + 2 <= ngm; g += 2) {     // 4 gathers in flight, 2 chains
      int j0 = (g + 0) * 4 + q, j1 = (g + 1) * 4 + q;
      u32 a0 = __shfl(HA, j0, 64), a1 = __shfl(HA, j1, 64);
      u32 b0 = __shfl(HB, j0, 64), b1 = __shfl(HB, j1, 64);
      uint2 ga0 = ((const uint2*)(hbf_in + ((size_t)(a0 & 0xFFFFu) << 6)))[fq];
      uint2 ga1 = ((const uint2*)(hbf_in + ((size_t)(a1 & 0xFFFFu) << 6)))[fq];
      uint2 gb0 = ((const uint2*)(hbf_in + ((size_t)(b0 & 0xFFFFu) << 6)))[fq];
      uint2 gb1 = ((const uint2*)(hbf_in + ((size_t)(b1 & 0xFFFFu) << 6)))[fq];
      float wa0 = (j0 < cA) ? __uint_as_float(a0 & 0xFFFF0000u) : 0.f;
      float wa1 = (j1 < cA) ? __uint_as_float(a1 & 0xFFFF0000u) : 0.f;
      float wb0 = (j0 < cB) ? __uint_as_float(b0 & 0xFFFF0000u) : 0.f;
      float wb1 = (j1 < cB) ? __uint_as_float(b1 & 0xFFFF0000u) : 0.f;
      fma4bf(accA, ga0, wa0); fma4bf(accA, ga1, wa1);
      fma4bf(accB, gb0, wb0); fma4bf(accB, gb1, wb1);
    }
    for (; g < ngm; ++g) {             // odd tail group (both nodes, predicated)
      int j = g * 4 + q;
      u32 ha = __shfl(HA, j, 64), hb = __shfl(HB, j, 64);
      uint2 ga = ((const uint2*)(hbf_in + ((size_t)(ha & 0xFFFFu) << 6)))[fq];
      uint2 gb = ((const uint2*)(hbf_in + ((size_t)(hb & 0xFFFFu) << 6)))[fq];
      float wa = (j < cA) ? __uint_as_float(ha & 0xFFFF0000u) : 0.f;
      float wb = (j < cB) ? __uint_as_float(hb & 0xFFFF0000u) : 0.f;
      fma4bf(accA, ga, wa);
      fma4bf(accB, gb, wb);
    }
    // rare deg>32 tails: direct header loads
    for (int gg = 8; gg < (cA >> 2); ++gg) {
      u32 hj = edgep[(size_t)nA * CAP + gg * 4 + q];
      uint2 gx = ((const uint2*)(hbf_in + ((size_t)(hj & 0xFFFFu) << 6)))[fq];
      fma4bf(accA, gx, __uint_as_float(hj & 0xFFFF0000u));
    }
    for (int gg = 8; gg < (cB >> 2); ++gg) {
      u32 hj = edgep[(size_t)nB * CAP + gg * 4 + q];
      uint2 gx = ((const uint2*)(hbf_in + ((size_t)(hj & 0xFFFFu) << 6)))[fq];
      fma4bf(accB, gx, __uint_as_float(hj & 0xFFFF0000u));
    }
#pragma unroll
    for (int off = 16; off < 64; off <<= 1) {
      accA.x += __shfl_xor(accA.x, off, 64);
      accA.y += __shfl_xor(accA.y, off, 64);
      accA.z += __shfl_xor(accA.z, off, 64);
      accA.w += __shfl_xor(accA.w, off, 64);
      accB.x += __shfl_xor(accB.x, off, 64);
      accB.y += __shfl_xor(accB.y, off, 64);
      accB.z += __shfl_xor(accB.z, off, 64);
      accB.w += __shfl_xor(accB.w, off, 64);
    }
    if (lane < 16) {
      u32 a0 = (u32)f2bf(accA.x) | ((u32)f2bf(accA.y) << 16);
      u32 a1 = (u32)f2bf(accA.z) | ((u32)f2bf(accA.w) << 16);
      u32 b0 = (u32)f2bf(accB.x) | ((u32)f2bf(accB.y) << 16);
      u32 b1 = (u32)f2bf(accB.z) | ((u32)f2bf(accB.w) << 16);
      u32* dpA = (u32*)&sAgg[(wl * 4 + pr * 2 + 0) * 72 + fq * 4];
      u32* dpB = (u32*)&sAgg[(wl * 4 + pr * 2 + 1) * 72 + fq * 4];
      dpA[0] = a0; dpA[1] = a1;
      dpB[0] = b0; dpB[1] = b1;
    }
  }
  __syncthreads();

  {
    int g = wl >> 2, t = wl & 3;
    f32x4 d = {0.f, 0.f, 0.f, 0.f};
#pragma unroll
    for (int s = 0; s < 2; ++s) {
      short8v av = *(const short8v*)&sAgg[(g * 16 + fq) * 72 + s * 32 + q * 8];
      short8v bv = *(const short8v*)&sWt[(t * 16 + fq) * 72 + s * 32 + q * 8];
      d = __builtin_amdgcn_mfma_f32_16x16x32_bf16(av, bv, d, 0, 0, 0);
    }
#pragma unroll
    for (int reg = 0; reg < 4; ++reg) {
      int row = q * 4 + reg;
      sOut[(g * 16 + row) * 68 + t * 16 + fq] = d[reg];
    }
  }
  __syncthreads();

  float bias = B[lane], lg = ln_g[lane], lb = ln_b[lane];
#pragma unroll
  for (int rp = 0; rp < 4; ++rp) {
    int nl = wl * 4 + rp;
    int n = nbase + nl;
    float y = sOut[nl * 68 + lane] + bias;
    float a = y, b2 = y * y;
#pragma unroll
    for (int o = 32; o > 0; o >>= 1) {
      a += __shfl_xor(a, o, 64);
      b2 += __shfl_xor(b2, o, 64);
    }
    float m = a * (1.f / HD);
    float v = b2 * (1.f / HD) - m * m;
    float ln = (y - m) * rsqrtf(v + EPSV) * lg + lb;
    float hv = bf2f(hbf_in[(size_t)n * HD + lane]) + ln;
    hbf_out[(size_t)n * HD + lane] = f2bf(hv);
  }
}

// ---------------- fc_final: LN(64) -> MFMA [64x64] -> ELU -> MFMA [64x32] ------------
__global__ __launch_bounds__(256, 4) void fc_final_k(
    const u16* __restrict__ hbf, const float* __restrict__ ln2_g,
    const float* __restrict__ ln2_b, const float* __restrict__ w3,
    const float* __restrict__ b3, const float* __restrict__ w4,
    const float* __restrict__ b4, float* __restrict__ out) {
  __shared__ __align__(16) u16 sHn[64 * 72];    // [node][k] LN(h) bf16
  __shared__ __align__(16) u16 sW3b[64 * 72];   // [j][k] W3^T bf16
  __shared__ __align__(16) u16 sW4b[32 * 72];   // [j][k] W4^T bf16
  __shared__ __align__(16) u16 sZ[64 * 72];     // [node][k] z bf16
  int tid = threadIdx.x;
  for (int i = tid; i < HD * HD; i += 256) {
    int k = i >> 6, j = i & 63;          // w3[k][j]
    sW3b[j * 72 + k] = f2bf(w3[i]);
  }
  for (int i = tid; i < HD * NOUT; i += 256) {
    int k = i >> 5, j = i & 31;          // w4[k][j]
    sW4b[j * 72 + k] = f2bf(w4[i]);
  }

  // ---- phase 1: LN(64), 4 lanes/node ----
  {
    int jq = tid & 3;                  // k-slice jq*16..jq*16+15
    int nl = tid >> 2;
    int node = blockIdx.x * 64 + nl;
    const uint4* hp = (const uint4*)(hbf + (size_t)node * HD + jq * 16);
    float hv[16];
    float s = 0.f, s2 = 0.f;
#pragma unroll
    for (int i = 0; i < 2; ++i) {
      uint4 v = hp[i];
      float f0 = __uint_as_float(v.x << 16), f1 = __uint_as_float(v.x & 0xFFFF0000u);
      float f2 = __uint_as_float(v.y << 16), f3 = __uint_as_float(v.y & 0xFFFF0000u);
      float f4 = __uint_as_float(v.z << 16), f5 = __uint_as_float(v.z & 0xFFFF0000u);
      float f6 = __uint_as_float(v.w << 16), f7 = __uint_as_float(v.w & 0xFFFF0000u);
      hv[i * 8 + 0] = f0; hv[i * 8 + 1] = f1; hv[i * 8 + 2] = f2; hv[i * 8 + 3] = f3;
      hv[i * 8 + 4] = f4; hv[i * 8 + 5] = f5; hv[i * 8 + 6] = f6; hv[i * 8 + 7] = f7;
      s += f0 + f1 + f2 + f3 + f4 + f5 + f6 + f7;
      s2 += f0 * f0 + f1 * f1 + f2 * f2 + f3 * f3
          + f4 * f4 + f5 * f5 + f6 * f6 + f7 * f7;
    }
    s += __shfl_xor(s, 1, 64);  s += __shfl_xor(s, 2, 64);
    s2 += __shfl_xor(s2, 1, 64); s2 += __shfl_xor(s2, 2, 64);
    float mean = s * (1.f / HD);
    float var = s2 * (1.f / HD) - mean * mean;
    float r = rsqrtf(var + EPSV);
    u32* dp = (u32*)&sHn[nl * 72 + jq * 16];
#pragma unroll
    for (int i = 0; i < 8; ++i) {
      int k = jq * 16 + i * 2;
      float a0 = (hv[i * 2 + 0] - mean) * r * ln2_g[k + 0] + ln2_b[k + 0];
      float a1 = (hv[i * 2 + 1] - mean) * r * ln2_g[k + 1] + ln2_b[k + 1];
      dp[i] = (u32)f2bf(a0) | ((u32)f2bf(a1) << 16);
    }
  }
  __syncthreads();   // W3/W4 staged + sHn complete

  // ---- phase 2: GEMM1 MFMA, wave wl -> nodes wl*16..+15, 4 j-tiles ----
  int wl = tid >> 6, lane = tid & 63;
  int q = lane >> 4, fq = lane & 15;
  f32x4 d0 = {0.f, 0.f, 0.f, 0.f}, d1 = d0, d2 = d0, d3 = d0;
#pragma unroll
  for (int st = 0; st < 2; ++st) {
    short8v av = *(const short8v*)&sHn[(wl * 16 + fq) * 72 + st * 32 + q * 8];
    short8v b0 = *(const short8v*)&sW3b[(0 * 16 + fq) * 72 + st * 32 + q * 8];
    short8v b1v = *(const short8v*)&sW3b[(1 * 16 + fq) * 72 + st * 32 + q * 8];
    short8v b2 = *(const short8v*)&sW3b[(2 * 16 + fq) * 72 + st * 32 + q * 8];
    short8v b3v = *(const short8v*)&sW3b[(3 * 16 + fq) * 72 + st * 32 + q * 8];
    d0 = __builtin_amdgcn_mfma_f32_16x16x32_bf16(av, b0, d0, 0, 0, 0);
    d1 = __builtin_amdgcn_mfma_f32_16x16x32_bf16(av, b1v, d1, 0, 0, 0);
    d2 = __builtin_amdgcn_mfma_f32_16x16x32_bf16(av, b2, d2, 0, 0, 0);
    d3 = __builtin_amdgcn_mfma_f32_16x16x32_bf16(av, b3v, d3, 0, 0, 0);
  }
  // bias + ELU, z -> bf16 LDS (same-wave rows: no barrier needed)
  {
    float b3r[4];
#pragma unroll
    for (int t = 0; t < 4; ++t) b3r[t] = b3[t * 16 + fq];
#pragma unroll
    for (int reg = 0; reg < 4; ++reg) {
      int row = wl * 16 + q * 4 + reg;
      float v0 = d0[reg] + b3r[0]; v0 = (v0 > 0.f) ? v0 : expm1f(v0);
      float v1 = d1[reg] + b3r[1]; v1 = (v1 > 0.f) ? v1 : expm1f(v1);
      float v2 = d2[reg] + b3r[2]; v2 = (v2 > 0.f) ? v2 : expm1f(v2);
      float v3 = d3[reg] + b3r[3]; v3 = (v3 > 0.f) ? v3 : expm1f(v3);
      sZ[row * 72 + 0 * 16 + fq] = f2bf(v0);
      sZ[row * 72 + 1 * 16 + fq] = f2bf(v1);
      sZ[row * 72 + 2 * 16 + fq] = f2bf(v2);
      sZ[row * 72 + 3 * 16 + fq] = f2bf(v3);
    }
  }

  // ---- phase 3: GEMM2 MFMA (64 -> 32), 2 j-tiles, direct f32 store ----
  {
    f32x4 e0 = {0.f, 0.f, 0.f, 0.f}, e1 = e0;
#pragma unroll
    for (int st = 0; st < 2; ++st) {
      short8v av = *(const short8v*)&sZ[(wl * 16 + fq) * 72 + st * 32 + q * 8];
      short8v b0 = *(const short8v*)&sW4b[(0 * 16 + fq) * 72 + st * 32 + q * 8];
      short8v b1v = *(const short8v*)&sW4b[(1 * 16 + fq) * 72 + st * 32 + q * 8];
      e0 = __builtin_amdgcn_mfma_f32_16x16x32_bf16(av, b0, e0, 0, 0, 0);
      e1 = __builtin_amdgcn_mfma_f32_16x16x32_bf16(av, b1v, e1, 0, 0, 0);
    }
    float b4r0 = b4[0 * 16 + fq], b4r1 = b4[1 * 16 + fq];
#pragma unroll
    for (int reg = 0; reg < 4; ++reg) {
      int n = blockIdx.x * 64 + wl * 16 + q * 4 + reg;
      out[(size_t)n * NOUT + 0 * 16 + fq] = e0[reg] + b4r0;
      out[(size_t)n * NOUT + 1 * 16 + fq] = e1[reg] + b4r1;
    }
  }
}

extern "C" void kernel_launch(void* const* d_in, const int* in_sizes, int n_in,
                              void* d_out, int out_size, void* d_ws, size_t ws_size,
                              hipStream_t stream) {
  const float* x      = (const float*)d_in[0];
  const float* ew     = (const float*)d_in[1];
  const int*   src    = (const int*)d_in[2];
  const int*   dst    = (const int*)d_in[3];
  const float* ln1_g  = (const float*)d_in[4];
  const float* ln1_b  = (const float*)d_in[5];
  const float* w1     = (const float*)d_in[6];
  const float* b1     = (const float*)d_in[7];
  const float* ln_g   = (const float*)d_in[8];
  const float* ln_b   = (const float*)d_in[9];
  const float* conv_w = (const float*)d_in[10];
  const float* conv_b = (const float*)d_in[11];
  const float* ln2_g  = (const float*)d_in[12];
  const float* ln2_b  = (const float*)d_in[13];
  const float* w3     = (const float*)d_in[14];
  const float* b3     = (const float*)d_in[15];
  const float* w4     = (const float*)d_in[16];
  const float* b4     = (const float*)d_in[17];
  float* out = (float*)d_out;

  char* ws = (char*)d_ws;
  u16*   hAbf  = (u16*)ws;                           // 8 MB
  u16*   hBbf  = hAbf + (size_t)NN * HD;             // 8 MB
  int*   ecnt  = (int*)(hBbf + (size_t)NN * HD);     // 256 KB (+pad)
  u32*   edgep = (u32*)(ecnt + NN + 64);             // NN*CAP*4B = 12.6 MB
  int*   pcnt  = (int*)(edgep + (size_t)NN * CAP);   // NP ints (+pad)
  uint2* tmp   = (uint2*)(pcnt + NP + 64);           // NP*PCAP*8B = 10.5 MB

  zero_k<<<1, NP, 0, stream>>>(pcnt);
  passA_k<<<NE / 4096, 1024, 0, stream>>>(src, dst, ew, pcnt, tmp);
  passB_k<<<NP, 256, 0, stream>>>(tmp, pcnt, edgep, ecnt);

  fc_first_k<<<NN / 64, 256, 0, stream>>>(x, ln1_g, ln1_b, w1, b1, ln_g, ln_b,
                                          hAbf);
  conv_k<<<NN / 32, 512, 0, stream>>>(hAbf, hBbf, ecnt, edgep,
                                      conv_w,        conv_b,       ln_g, ln_b);
  conv_k<<<NN / 32, 512, 0, stream>>>(hBbf, hAbf, ecnt, edgep,
                                      conv_w + 4096, conv_b + 64,  ln_g, ln_b);
  conv_k<<<NN / 32, 512, 0, stream>>>(hAbf, hBbf, ecnt, edgep,
                                      conv_w + 8192, conv_b + 128, ln_g, ln_b);
  fc_final_k<<<NN / 64, 256, 0, stream>>>(hBbf, ln2_g, ln2_b, w3, b3, w4, b4, out);
}